// Round 7
// baseline (11388.442 us; speedup 1.0000x reference)
//
#include <hip/hip_runtime.h>
#include <math.h>

#define NN 2000
#define BB 32
#define TT 24
#define T_OUT 12
#define HH 64
#define DD 10
#define NP 2048   // padded node dim
#define BC 2048   // B*H columns (j = b*64 + c)

typedef unsigned short ushort_t;
typedef __bf16 bf16x8 __attribute__((ext_vector_type(8)));
typedef float f32x4 __attribute__((ext_vector_type(4)));

__device__ __forceinline__ float sigmoidf_(float x) { return 1.f / (1.f + expf(-x)); }

__device__ __forceinline__ ushort_t f2bf(float f) {
    unsigned int u = __float_as_uint(f);
    unsigned int r = (u + 0x7FFFu + ((u >> 16) & 1u)) >> 16;
    return (ushort_t)r;
}
__device__ __forceinline__ float bf2f(ushort_t s) {
    return __uint_as_float(((unsigned int)s) << 16);
}

__device__ __forceinline__ void glld16(const ushort_t* g, ushort_t* lds) {
    __builtin_amdgcn_global_load_lds(
        (const __attribute__((address_space(1))) char*)g,
        (__attribute__((address_space(3))) char*)lds, 16, 0, 0);
}

// ---------------- workspace layout (bytes), high-water 122,896,384 ----------------
constexpr size_t SZ_NPNP2 = (size_t)NP * NP * 2;   // 8,388,608
constexpr size_t SZ_ST4   = (size_t)NN * BC * 4;   // 16,384,000
constexpr size_t SZ_ST2   = (size_t)NN * BC * 2;   // 8,192,000

constexpr size_t ABF_OFF  = 0;
constexpr size_t H1T_OFF  = ABF_OFF + SZ_NPNP2;
constexpr size_t TMPT_OFF = H1T_OFF + SZ_NPNP2;
constexpr size_t H0F_OFF  = TMPT_OFF + SZ_NPNP2;
constexpr size_t H1F_OFF  = H0F_OFF + SZ_ST4;
constexpr size_t ZF_OFF   = H1F_OFF + SZ_ST4;       // f32; overlaid with A_f32 in setup
constexpr size_t H0B_OFF  = ZF_OFF + SZ_ST4;
constexpr size_t H1B_OFF  = H0B_OFF + SZ_ST2;
constexpr size_t RHB_OFF  = H1B_OFF + SZ_ST2;
constexpr size_t AH0_OFF  = RHB_OFF + SZ_ST2;
constexpr size_t AHX_OFF  = AH0_OFF + SZ_ST2;       // shared: Arh0 / Ah1 / Arh1
constexpr size_t AXF_OFF  = AHX_OFF + SZ_ST2;       // [B][T][N] f32
constexpr size_t BTG0_OFF = AXF_OFF + (size_t)BB * TT * NN * 4;
constexpr size_t BTC0_OFF = BTG0_OFF + (size_t)DD * 128 * 128 * 2;  // 327,680
constexpr size_t BTG1_OFF = BTC0_OFF + (size_t)DD * 64 * 128 * 2;   // 163,840
constexpr size_t BTC1_OFF = BTG1_OFF + (size_t)DD * 128 * 256 * 2;  // 655,360
constexpr size_t WS_TOP   = BTC1_OFF + (size_t)DD * 64 * 256 * 2;   // 122,896,384

// ---------------- A_f32 = row_softmax(relu(E E^T)) ----------------
__global__ __launch_bounds__(256) void compute_A_kernel(const float* __restrict__ E,
                                                        float* __restrict__ A) {
    const int row = blockIdx.x;
    const int tid = threadIdx.x;
    float er[DD];
#pragma unroll
    for (int d = 0; d < DD; ++d) er[d] = E[row * DD + d];
    __shared__ float red[8];

    float lmax = -1e30f;
    for (int c = tid; c < NN; c += 256) {
        float s = 0.f;
#pragma unroll
        for (int d = 0; d < DD; ++d) s += er[d] * E[c * DD + d];
        s = fmaxf(s, 0.f);
        A[(size_t)row * NN + c] = s;
        lmax = fmaxf(lmax, s);
    }
#pragma unroll
    for (int o = 32; o > 0; o >>= 1) lmax = fmaxf(lmax, __shfl_down(lmax, o, 64));
    if ((tid & 63) == 0) red[tid >> 6] = lmax;
    __syncthreads();
    const float rmax = fmaxf(fmaxf(red[0], red[1]), fmaxf(red[2], red[3]));
    __syncthreads();

    float lsum = 0.f;
    for (int c = tid; c < NN; c += 256) {
        float v = expf(A[(size_t)row * NN + c] - rmax);
        A[(size_t)row * NN + c] = v;
        lsum += v;
    }
#pragma unroll
    for (int o = 32; o > 0; o >>= 1) lsum += __shfl_down(lsum, o, 64);
    if ((tid & 63) == 0) red[4 + (tid >> 6)] = lsum;
    __syncthreads();
    const float inv = 1.f / (red[4] + red[5] + red[6] + red[7]);
    for (int c = tid; c < NN; c += 256) A[(size_t)row * NN + c] *= inv;
}

// ---------------- A_f32 -> A_bf [2048][2048] with zero pad ----------------
__global__ __launch_bounds__(256) void convert_A(const float* __restrict__ Af,
                                                 ushort_t* __restrict__ Ab) {
    size_t idx = (size_t)blockIdx.x * 256 + threadIdx.x;
    int r = (int)(idx >> 11), c = (int)(idx & 2047);
    float v = (r < NN && c < NN) ? Af[(size_t)r * NN + c] : 0.f;
    Ab[idx] = f2bf(v);
}

// ---------------- Ax[b,t,n] = sum_m A[n,m] x[b,t,m]  (f32, one-time) ----------------
__global__ __launch_bounds__(256) void ax_kernel(const float* __restrict__ A,
                                                 const float* __restrict__ x,
                                                 float* __restrict__ Ax) {
    __shared__ float As[64][65];
    __shared__ float xs[64][25];
    const int n0 = blockIdx.x * 64;
    const int b = blockIdx.y;
    const int tid = threadIdx.x;
    float acc[6] = {0, 0, 0, 0, 0, 0};
    for (int m0 = 0; m0 < NN; m0 += 64) {
#pragma unroll
        for (int l = 0; l < 16; ++l) {
            int idx = tid + l * 256;
            int r = idx >> 6, c = idx & 63;
            int n = n0 + r, m = m0 + c;
            As[r][c] = (n < NN && m < NN) ? A[(size_t)n * NN + m] : 0.f;
        }
        for (int idx = tid; idx < 64 * TT; idx += 256) {
            int c = idx >> 6, r = idx & 63;
            int m = m0 + r;
            xs[r][c] = (m < NN) ? x[((size_t)b * TT + c) * NN + m] : 0.f;
        }
        __syncthreads();
#pragma unroll 4
        for (int mm = 0; mm < 64; ++mm) {
#pragma unroll
            for (int j = 0; j < 6; ++j) {
                int oi = tid + j * 256;
                int r = oi / TT, c = oi % TT;
                acc[j] += As[r][mm] * xs[mm][c];
            }
        }
        __syncthreads();
    }
#pragma unroll
    for (int j = 0; j < 6; ++j) {
        int oi = tid + j * 256;
        int r = oi / TT, c = oi % TT;
        int n = n0 + r;
        if (n < NN) Ax[((size_t)b * TT + c) * NN + n] = acc[j];
    }
}

// ---------------- transpose bf16 [n][j] -> [j][n], zero-fill n>=NN ----------------
__global__ __launch_bounds__(256) void transpose_bf(const ushort_t* __restrict__ src,
                                                    ushort_t* __restrict__ dst) {
    __shared__ ushort_t tile[64][65];
    const int jb = blockIdx.x * 64, nb = blockIdx.y * 64;
    const int tid = threadIdx.x;
#pragma unroll
    for (int l = 0; l < 16; ++l) {
        int idx = tid + l * 256;
        int r = idx >> 6, c = idx & 63;  // r: n-local, c: j-local
        int n = nb + r;
        tile[r][c] = (n < NN) ? src[(size_t)n * BC + jb + c] : (ushort_t)0;
    }
    __syncthreads();
#pragma unroll
    for (int l = 0; l < 16; ++l) {
        int idx = tid + l * 256;
        int r = idx >> 6, c = idx & 63;  // r: j-local, c: n-local
        dst[(size_t)(jb + r) * NP + nb + c] = tile[c][r];
    }
}

// ---------------- MFMA GEMM: Y[n][j] = sum_m A[n][m] * XT[j][m], bf16 ----------------
// 64x128 tile, BK=32, 4 waves (col-split), 512 blocks.
// T3-minimum 2-phase: double-buffered LDS; issue next K-step's global_load_lds
// BEFORE current step's ds_read+MFMA; ONE barrier per K-step (compiler drains
// vmcnt+lgkmcnt at the barrier, so next-tile data is ready after it).
__global__ __launch_bounds__(256) void gemm_mfma(const ushort_t* __restrict__ Ab,
                                                 const ushort_t* __restrict__ XT,
                                                 ushort_t* __restrict__ Y) {
    __shared__ __align__(16) ushort_t As[2][64 * 32];
    __shared__ __align__(16) ushort_t Bs[2][128 * 32];
    const int tid = threadIdx.x;
    const int w = tid >> 6, l = tid & 63, lr = l & 15, lg = l >> 4;
    const int n0 = blockIdx.x * 64, j0 = blockIdx.y * 128;
    f32x4 acc[4][2] = {};

    // per-lane staging coords (constant across iterations)
    const int arow = tid >> 2, ac16 = tid & 3;
    const size_t asrc = (size_t)(n0 + arow) * NP + ((ac16 ^ (arow & 3)) << 3);

    // prologue: stage k-step 0 into buf 0
    glld16(Ab + asrc + 0, (ushort_t*)((char*)As[0] + tid * 16));
#pragma unroll
    for (int p = 0; p < 2; ++p) {
        const int idx = p * 256 + tid;
        const int row = idx >> 2, c16 = idx & 3;
        glld16(XT + (size_t)(j0 + row) * NP + 0 + ((c16 ^ (row & 3)) << 3),
               (ushort_t*)((char*)Bs[0] + idx * 16));
    }
    __syncthreads();

    for (int ks = 0; ks < NP / 32; ++ks) {
        const int cur = ks & 1;
        // phase 1: issue next K-step's staging into the other buffer
        if (ks + 1 < NP / 32) {
            const int k1 = (ks + 1) * 32;
            glld16(Ab + asrc + k1, (ushort_t*)((char*)As[cur ^ 1] + tid * 16));
#pragma unroll
            for (int p = 0; p < 2; ++p) {
                const int idx = p * 256 + tid;
                const int row = idx >> 2, c16 = idx & 3;
                glld16(XT + (size_t)(j0 + row) * NP + k1 + ((c16 ^ (row & 3)) << 3),
                       (ushort_t*)((char*)Bs[cur ^ 1] + idx * 16));
            }
        }
        // phase 2: compute current buffer (overlaps with in-flight loads)
        bf16x8 av[4], bv[2];
#pragma unroll
        for (int m = 0; m < 4; ++m) {
            const int rr = m * 16 + lr;
            av[m] = *(const bf16x8*)&As[cur][rr * 32 + ((lg * 8) ^ ((rr & 3) << 3))];
        }
#pragma unroll
        for (int nt = 0; nt < 2; ++nt) {
            const int br = w * 32 + nt * 16 + lr;
            bv[nt] = *(const bf16x8*)&Bs[cur][br * 32 + ((lg * 8) ^ ((br & 3) << 3))];
        }
#pragma unroll
        for (int m = 0; m < 4; ++m)
#pragma unroll
            for (int nt = 0; nt < 2; ++nt)
                acc[m][nt] = __builtin_amdgcn_mfma_f32_16x16x32_bf16(av[m], bv[nt], acc[m][nt], 0, 0, 0);
        __syncthreads();  // drains vmcnt (next tile ready) + lgkm (reads done)
    }

#pragma unroll
    for (int m = 0; m < 4; ++m)
#pragma unroll
        for (int r = 0; r < 4; ++r) {
            const int n = n0 + m * 16 + lg * 4 + r;
            if (n < NN) {
#pragma unroll
                for (int nt = 0; nt < 2; ++nt)
                    Y[(size_t)n * BC + j0 + w * 32 + nt * 16 + lr] = f2bf(acc[m][nt][r]);
            }
        }
}

// ---------------- prep: Bt[d][o][K] bf16 from pool (B^T form for MFMA) ----------------
// L0: K=128, k -> (kk=k>>6, i=1+(k&63)).  L1: K=256, s=k>>6 -> (kk=s&1, i=(s>>1)*64+(k&63)).
template <int CI, int CO, bool L0>
__global__ __launch_bounds__(256) void prepW(const float* __restrict__ Wp,
                                             ushort_t* __restrict__ Bt) {
    constexpr int K = L0 ? 128 : 256;
    const int idx = blockIdx.x * 256 + threadIdx.x;
    if (idx >= DD * CO * K) return;
    const int d = idx / (CO * K);
    const int rem = idx - d * CO * K;
    const int o = rem / K;
    const int k = rem - o * K;
    const int s = k >> 6, c = k & 63;
    const int kk = L0 ? s : (s & 1);
    const int i = L0 ? (1 + c) : ((s >> 1) * 64 + c);
    Bt[idx] = f2bf(Wp[((size_t)(d * 2 + kk) * CI + i) * CO + o]);
}

// ---------------- factored-MFMA NAPL gconv (round-5 proven LDS-staged form) ----------------
// Block = 64 output rows j (= 2 nodes x 32 batches). out[j,o] = sum_d e[n,d]*(in @ Wp[d])[j,o].
// Input segs staged once in LDS (XOR-swizzled); B-frags stream from tiny Bt pools (L2).
// GATE (CO=128): o<64 -> z=sigma -> zf ; o>=64 -> rh = sigma*hf -> outb.
// CAND (CO=64): h_new = z*hf + (1-z)*tanh(val) -> outf (f32) + outb (bf16).
template <int NSEGS, int CO, bool GATE, bool HASX>
__global__ __launch_bounds__(256) void napl2(
    const ushort_t* __restrict__ Bt, const float* __restrict__ bp,
    const float* __restrict__ emb, const float* __restrict__ WxPool,
    const ushort_t* __restrict__ s0p, const ushort_t* __restrict__ s1p,
    const ushort_t* __restrict__ s2p, const ushort_t* __restrict__ s3p,
    const float* __restrict__ xv, const float* __restrict__ axv,
    const float* hf, float* __restrict__ zf,
    ushort_t* __restrict__ outb, float* outf, int t) {
    constexpr int K = NSEGS * 64;
    constexpr int NT = (CO == 128) ? 2 : 1;
    __shared__ __align__(16) ushort_t As[NSEGS * 64 * 64];
    const int tid = threadIdx.x;
    const int w = tid >> 6, l = tid & 63, lr = l & 15, lg = l >> 4;
    const int n0 = blockIdx.x * 2;
    const int ob = w * (16 * NT);
    const ushort_t* segs[4] = {s0p, s1p, s2p, s3p};

    // stage A: seg-major [s][64 rows][64 cols], source pre-swizzled by ((row&7)<<3) els
#pragma unroll
    for (int s = 0; s < NSEGS; ++s) {
        const ushort_t* sp = segs[s];
#pragma unroll
        for (int p = 0; p < 2; ++p) {
            const int idx = p * 256 + tid;
            const int row = idx >> 3, c16 = idx & 7;
            glld16(sp + (size_t)(n0 + (row >> 5)) * BC + (row & 31) * 64 +
                       ((c16 ^ (row & 7)) << 3),
                   (ushort_t*)((char*)As + s * 8192 + idx * 16));
        }
    }
    __syncthreads();

    f32x4 OUT[4][NT] = {};
#pragma unroll 1
    for (int d = 0; d < DD; ++d) {
        const ushort_t* btd = Bt + (size_t)d * CO * K;
        const float ea = emb[n0 * DD + d];
        const float eb = emb[(n0 + 1) * DD + d];
        f32x4 P[4][NT] = {};
#pragma unroll
        for (int s = 0; s < NSEGS; ++s)
#pragma unroll
            for (int h2 = 0; h2 < 2; ++h2) {
                const int kin = h2 * 32 + lg * 8;
                const int kg = s * 64 + kin;
                bf16x8 bv[NT];
#pragma unroll
                for (int nt = 0; nt < NT; ++nt)
                    bv[nt] = *(const bf16x8*)&btd[(size_t)(ob + nt * 16 + lr) * K + kg];
                bf16x8 av[4];
#pragma unroll
                for (int m = 0; m < 4; ++m) {
                    const int rr = m * 16 + lr;
                    av[m] = *(const bf16x8*)&As[s * 4096 + rr * 64 + (kin ^ ((rr & 7) << 3))];
                }
#pragma unroll
                for (int m = 0; m < 4; ++m)
#pragma unroll
                    for (int nt = 0; nt < NT; ++nt)
                        P[m][nt] = __builtin_amdgcn_mfma_f32_16x16x32_bf16(av[m], bv[nt], P[m][nt], 0, 0, 0);
            }
#pragma unroll
        for (int m = 0; m < 4; ++m) {
            const float e = (m < 2) ? ea : eb;
#pragma unroll
            for (int nt = 0; nt < NT; ++nt)
#pragma unroll
                for (int r = 0; r < 4; ++r)
                    OUT[m][nt][r] += e * P[m][nt][r];
        }
    }

    // per-node bias and (optional) x rank-2 weights
    float bias[2][NT];
#pragma unroll
    for (int nd = 0; nd < 2; ++nd)
#pragma unroll
        for (int nt = 0; nt < NT; ++nt) {
            float s_ = 0.f;
#pragma unroll
            for (int d = 0; d < DD; ++d)
                s_ += emb[(n0 + nd) * DD + d] * bp[d * CO + ob + nt * 16 + lr];
            bias[nd][nt] = s_;
        }
    float wx[2][2][NT] = {};
    if (HASX) {
#pragma unroll
        for (int kk = 0; kk < 2; ++kk)
#pragma unroll
            for (int nd = 0; nd < 2; ++nd)
#pragma unroll
                for (int nt = 0; nt < NT; ++nt) {
                    float s_ = 0.f;
#pragma unroll
                    for (int d = 0; d < DD; ++d)
                        s_ += emb[(n0 + nd) * DD + d] *
                              WxPool[(size_t)(d * 2 + kk) * 65 * CO + ob + nt * 16 + lr];
                    wx[kk][nd][nt] = s_;
                }
    }

#pragma unroll
    for (int m = 0; m < 4; ++m) {
        const int nd = m >> 1;
        const int n = n0 + nd;
#pragma unroll
        for (int r = 0; r < 4; ++r) {
            const int row = m * 16 + lg * 4 + r;
            const int b = row & 31;
            const size_t nb = (size_t)n * BC + b * 64;
            float xt = 0.f, axt = 0.f;
            if (HASX) {
                xt = xv[((size_t)b * TT + t) * NN + n];
                axt = axv[((size_t)b * TT + t) * NN + n];
            }
#pragma unroll
            for (int nt = 0; nt < NT; ++nt) {
                const int o = ob + nt * 16 + lr;
                float val = OUT[m][nt][r] + bias[nd][nt];
                if (HASX) val += xt * wx[0][nd][nt] + axt * wx[1][nd][nt];
                if (GATE) {
                    const float sg = sigmoidf_(val);
                    if (ob < 64) {
                        zf[nb + o] = sg;
                    } else {
                        outb[nb + (o - 64)] = f2bf(sg * hf[nb + (o - 64)]);
                    }
                } else {
                    const float hc = tanhf(val);
                    const float z = zf[nb + o];
                    const float hn = z * hf[nb + o] + (1.f - z) * hc;
                    outf[nb + o] = hn;
                    outb[nb + o] = f2bf(hn);
                }
            }
        }
    }
}

// ---------------- head: y[b,ot,n] = hb[ot] + sum_h h1[n][b*64+h]*hw[ot,h] ----------------
__global__ __launch_bounds__(256) void head_kernel(const float* __restrict__ h1,
                                                   const float* __restrict__ hw,
                                                   const float* __restrict__ hb,
                                                   float* __restrict__ y) {
    __shared__ float wl[T_OUT * HH];
    const int tid = threadIdx.x;
    for (int idx = tid; idx < T_OUT * HH; idx += 256) wl[idx] = hw[idx];
    __syncthreads();
    const int gi = blockIdx.x * 256 + tid;
    if (gi >= BB * NN) return;
    const int b = gi / NN, n = gi % NN;
    float acc[T_OUT];
#pragma unroll
    for (int ot = 0; ot < T_OUT; ++ot) acc[ot] = hb[ot];
    for (int h = 0; h < HH; ++h) {
        float v = h1[(size_t)n * BC + b * 64 + h];
#pragma unroll
        for (int ot = 0; ot < T_OUT; ++ot) acc[ot] += v * wl[ot * HH + h];
    }
#pragma unroll
    for (int ot = 0; ot < T_OUT; ++ot)
        y[((size_t)b * T_OUT + ot) * NN + n] = acc[ot];
}

extern "C" void kernel_launch(void* const* d_in, const int* in_sizes, int n_in,
                              void* d_out, int out_size, void* d_ws, size_t ws_size,
                              hipStream_t stream) {
    const float* x = (const float*)d_in[0];
    const float* node_emb = (const float*)d_in[1];
    const float* adapt_emb = (const float*)d_in[2];
    const float* Wg0 = (const float*)d_in[3];
    const float* bg0 = (const float*)d_in[4];
    const float* Wc0 = (const float*)d_in[5];
    const float* bc0 = (const float*)d_in[6];
    const float* Wg1 = (const float*)d_in[7];
    const float* bg1 = (const float*)d_in[8];
    const float* Wc1 = (const float*)d_in[9];
    const float* bc1 = (const float*)d_in[10];
    const float* head_w = (const float*)d_in[11];
    const float* head_b = (const float*)d_in[12];
    float* y = (float*)d_out;

    char* ws = (char*)d_ws;
    ushort_t* Abf  = (ushort_t*)(ws + ABF_OFF);
    ushort_t* h1T  = (ushort_t*)(ws + H1T_OFF);
    ushort_t* tmpT = (ushort_t*)(ws + TMPT_OFF);
    float* h0f = (float*)(ws + H0F_OFF);
    float* h1f = (float*)(ws + H1F_OFF);
    float* zf  = (float*)(ws + ZF_OFF);
    ushort_t* h0b = (ushort_t*)(ws + H0B_OFF);
    ushort_t* h1b = (ushort_t*)(ws + H1B_OFF);
    ushort_t* rhb = (ushort_t*)(ws + RHB_OFF);
    ushort_t* Ah0 = (ushort_t*)(ws + AH0_OFF);
    ushort_t* AhX = (ushort_t*)(ws + AHX_OFF);
    float* Axf = (float*)(ws + AXF_OFF);
    ushort_t* Btg0 = (ushort_t*)(ws + BTG0_OFF);
    ushort_t* Btc0 = (ushort_t*)(ws + BTC0_OFF);
    ushort_t* Btg1 = (ushort_t*)(ws + BTG1_OFF);
    ushort_t* Btc1 = (ushort_t*)(ws + BTC1_OFF);
    float* Af32 = zf;  // overlay: consumed before first gate writes z

    hipMemsetAsync(h0f, 0, SZ_ST4, stream);
    hipMemsetAsync(h1f, 0, SZ_ST4, stream);
    hipMemsetAsync(h0b, 0, SZ_ST2, stream);
    hipMemsetAsync(h1b, 0, SZ_ST2, stream);
    hipMemsetAsync(Ah0, 0, SZ_ST2, stream);
    hipMemsetAsync(h1T, 0, SZ_NPNP2, stream);

    // one-time setup
    compute_A_kernel<<<NN, 256, 0, stream>>>(adapt_emb, Af32);
    ax_kernel<<<dim3((NN + 63) / 64, BB), 256, 0, stream>>>(Af32, x, Axf);
    convert_A<<<(NP * NP) / 256, 256, 0, stream>>>(Af32, Abf);
    prepW<65, 128, true><<<(DD * 128 * 128 + 255) / 256, 256, 0, stream>>>(Wg0, Btg0);
    prepW<65, 64, true><<<(DD * 64 * 128 + 255) / 256, 256, 0, stream>>>(Wc0, Btc0);
    prepW<128, 128, false><<<(DD * 128 * 256 + 255) / 256, 256, 0, stream>>>(Wg1, Btg1);
    prepW<128, 64, false><<<(DD * 64 * 256 + 255) / 256, 256, 0, stream>>>(Wc1, Btc1);

    const dim3 gG(NP / 64, NP / 128);  // 32 x 16 = 512 blocks
    const dim3 gT(NP / 64, NP / 64);   // 32 x 32
    const int gN = NN * BB / 64;       // 1000 blocks

    for (int t = 0; t < TT; ++t) {
        // layer0 gate: segs [h0 | A h0] (+x rank-2) -> zf, rhb
        napl2<2, 128, true, true><<<gN, 256, 0, stream>>>(
            Btg0, bg0, node_emb, Wg0, h0b, Ah0, h0b, h0b, x, Axf, h0f, zf, rhb, nullptr, t);
        transpose_bf<<<gT, 256, 0, stream>>>(rhb, tmpT);
        gemm_mfma<<<gG, 256, 0, stream>>>(Abf, tmpT, AhX);  // Arh0
        // layer0 cand: segs [rh | A rh] (+x) -> h0f, h0b
        napl2<2, 64, false, true><<<gN, 256, 0, stream>>>(
            Btc0, bc0, node_emb, Wc0, rhb, AhX, rhb, rhb, x, Axf, h0f, zf, h0b, h0f, t);
        transpose_bf<<<gT, 256, 0, stream>>>(h0b, tmpT);
        gemm_mfma<<<gG, 256, 0, stream>>>(Abf, tmpT, Ah0);  // A h0_new (also next step's gate0)
        gemm_mfma<<<gG, 256, 0, stream>>>(Abf, h1T, AhX);   // A h1_prev
        // layer1 gate: segs [h0new | A h0new | h1 | A h1] -> zf, rhb
        napl2<4, 128, true, false><<<gN, 256, 0, stream>>>(
            Btg1, bg1, node_emb, nullptr, h0b, Ah0, h1b, AhX, nullptr, nullptr, h1f, zf, rhb, nullptr, t);
        transpose_bf<<<gT, 256, 0, stream>>>(rhb, tmpT);
        gemm_mfma<<<gG, 256, 0, stream>>>(Abf, tmpT, AhX);  // Arh1
        // layer1 cand: segs [h0new | A h0new | rh1 | A rh1] -> h1f, h1b
        napl2<4, 64, false, false><<<gN, 256, 0, stream>>>(
            Btc1, bc1, node_emb, nullptr, h0b, Ah0, rhb, AhX, nullptr, nullptr, h1f, zf, h1b, h1f, t);
        transpose_bf<<<gT, 256, 0, stream>>>(h1b, h1T);
    }

    head_kernel<<<(BB * NN + 255) / 256, 256, 0, stream>>>(h1f, head_w, head_b, y);
}

// Round 8
// 9787.597 us; speedup vs baseline: 1.1636x; 1.1636x over previous
//
#include <hip/hip_runtime.h>
#include <math.h>

#define NN 2000
#define BB 32
#define TT 24
#define T_OUT 12
#define HH 64
#define DD 10
#define NP 2048   // padded node dim
#define BC 2048   // B*H columns (j = b*64 + c)

typedef unsigned short ushort_t;
typedef __bf16 bf16x8 __attribute__((ext_vector_type(8)));
typedef float f32x4 __attribute__((ext_vector_type(4)));

__device__ __forceinline__ float sigmoidf_(float x) { return 1.f / (1.f + expf(-x)); }

__device__ __forceinline__ ushort_t f2bf(float f) {
    unsigned int u = __float_as_uint(f);
    unsigned int r = (u + 0x7FFFu + ((u >> 16) & 1u)) >> 16;
    return (ushort_t)r;
}
__device__ __forceinline__ float bf2f(ushort_t s) {
    return __uint_as_float(((unsigned int)s) << 16);
}

__device__ __forceinline__ void glld16(const ushort_t* g, ushort_t* lds) {
    __builtin_amdgcn_global_load_lds(
        (const __attribute__((address_space(1))) char*)g,
        (__attribute__((address_space(3))) char*)lds, 16, 0, 0);
}

__device__ __forceinline__ unsigned lds_off(const void* p) {
    return (unsigned)(size_t)(__attribute__((address_space(3))) const char*)p;
}

// ---------------- workspace layout (bytes), high-water 107,102,208 ----------------
constexpr size_t SZ_NPNP2 = (size_t)NP * NP * 2;   // 8,388,608
constexpr size_t SZ_ST4   = (size_t)NN * BC * 4;   // 16,384,000
constexpr size_t SZ_NPB2  = (size_t)NP * BC * 2;   // 8,388,608 (padded bf16 state)

constexpr size_t ABF_OFF  = 0;
constexpr size_t H0F_OFF  = ABF_OFF + SZ_NPNP2;
constexpr size_t H1F_OFF  = H0F_OFF + SZ_ST4;
constexpr size_t ZF_OFF   = H1F_OFF + SZ_ST4;       // f32; overlaid with A_f32 in setup
constexpr size_t H0B_OFF  = ZF_OFF + SZ_ST4;
constexpr size_t H1B_OFF  = H0B_OFF + SZ_NPB2;
constexpr size_t RHB_OFF  = H1B_OFF + SZ_NPB2;
constexpr size_t AH0_OFF  = RHB_OFF + SZ_NPB2;
constexpr size_t AHX_OFF  = AH0_OFF + SZ_NPB2;      // shared: Arh0 / Ah1 / Arh1
constexpr size_t AXF_OFF  = AHX_OFF + SZ_NPB2;      // [B][T][N] f32
constexpr size_t BTG0_OFF = AXF_OFF + (size_t)BB * TT * NN * 4;
constexpr size_t BTC0_OFF = BTG0_OFF + (size_t)DD * 128 * 128 * 2;  // 327,680
constexpr size_t BTG1_OFF = BTC0_OFF + (size_t)DD * 64 * 128 * 2;   // 163,840
constexpr size_t BTC1_OFF = BTG1_OFF + (size_t)DD * 128 * 256 * 2;  // 655,360
constexpr size_t WS_TOP   = BTC1_OFF + (size_t)DD * 64 * 256 * 2;   // 107,102,208

// ---------------- A_f32 = row_softmax(relu(E E^T)) ----------------
__global__ __launch_bounds__(256) void compute_A_kernel(const float* __restrict__ E,
                                                        float* __restrict__ A) {
    const int row = blockIdx.x;
    const int tid = threadIdx.x;
    float er[DD];
#pragma unroll
    for (int d = 0; d < DD; ++d) er[d] = E[row * DD + d];
    __shared__ float red[8];

    float lmax = -1e30f;
    for (int c = tid; c < NN; c += 256) {
        float s = 0.f;
#pragma unroll
        for (int d = 0; d < DD; ++d) s += er[d] * E[c * DD + d];
        s = fmaxf(s, 0.f);
        A[(size_t)row * NN + c] = s;
        lmax = fmaxf(lmax, s);
    }
#pragma unroll
    for (int o = 32; o > 0; o >>= 1) lmax = fmaxf(lmax, __shfl_down(lmax, o, 64));
    if ((tid & 63) == 0) red[tid >> 6] = lmax;
    __syncthreads();
    const float rmax = fmaxf(fmaxf(red[0], red[1]), fmaxf(red[2], red[3]));
    __syncthreads();

    float lsum = 0.f;
    for (int c = tid; c < NN; c += 256) {
        float v = expf(A[(size_t)row * NN + c] - rmax);
        A[(size_t)row * NN + c] = v;
        lsum += v;
    }
#pragma unroll
    for (int o = 32; o > 0; o >>= 1) lsum += __shfl_down(lsum, o, 64);
    if ((tid & 63) == 0) red[4 + (tid >> 6)] = lsum;
    __syncthreads();
    const float inv = 1.f / (red[4] + red[5] + red[6] + red[7]);
    for (int c = tid; c < NN; c += 256) A[(size_t)row * NN + c] *= inv;
}

// ---------------- A_f32 -> A_bf [2048][2048] with zero pad ----------------
__global__ __launch_bounds__(256) void convert_A(const float* __restrict__ Af,
                                                 ushort_t* __restrict__ Ab) {
    size_t idx = (size_t)blockIdx.x * 256 + threadIdx.x;
    int r = (int)(idx >> 11), c = (int)(idx & 2047);
    float v = (r < NN && c < NN) ? Af[(size_t)r * NN + c] : 0.f;
    Ab[idx] = f2bf(v);
}

// ---------------- Ax[b,t,n] = sum_m A[n,m] x[b,t,m]  (f32, one-time) ----------------
__global__ __launch_bounds__(256) void ax_kernel(const float* __restrict__ A,
                                                 const float* __restrict__ x,
                                                 float* __restrict__ Ax) {
    __shared__ float As[64][65];
    __shared__ float xs[64][25];
    const int n0 = blockIdx.x * 64;
    const int b = blockIdx.y;
    const int tid = threadIdx.x;
    float acc[6] = {0, 0, 0, 0, 0, 0};
    for (int m0 = 0; m0 < NN; m0 += 64) {
#pragma unroll
        for (int l = 0; l < 16; ++l) {
            int idx = tid + l * 256;
            int r = idx >> 6, c = idx & 63;
            int n = n0 + r, m = m0 + c;
            As[r][c] = (n < NN && m < NN) ? A[(size_t)n * NN + m] : 0.f;
        }
        for (int idx = tid; idx < 64 * TT; idx += 256) {
            int c = idx >> 6, r = idx & 63;
            int m = m0 + r;
            xs[r][c] = (m < NN) ? x[((size_t)b * TT + c) * NN + m] : 0.f;
        }
        __syncthreads();
#pragma unroll 4
        for (int mm = 0; mm < 64; ++mm) {
#pragma unroll
            for (int j = 0; j < 6; ++j) {
                int oi = tid + j * 256;
                int r = oi / TT, c = oi % TT;
                acc[j] += As[r][mm] * xs[mm][c];
            }
        }
        __syncthreads();
    }
#pragma unroll
    for (int j = 0; j < 6; ++j) {
        int oi = tid + j * 256;
        int r = oi / TT, c = oi % TT;
        int n = n0 + r;
        if (n < NN) Ax[((size_t)b * TT + c) * NN + n] = acc[j];
    }
}

// ---------------- MFMA GEMM with tr-read B: Y[n][j] = sum_m A[n][m] * H[m][j] ----------------
// 64x128 tile, BK=32 (m), 4 waves (col-split), round-5 2-barrier structure.
// A-tile staged XOR-swizzled (round-5 proven). B-tile H[32 m][128 j] staged in 4x16
// subtile order; B-frags read via ds_read_b64_tr_b16 (hardware transpose) -> no
// separate transpose kernels, states consumed in native [n][j] layout.
// blockIdx.z selects (H0->Y0) or (H1->Y1) for fused dual-GEMM dispatches.
__global__ __launch_bounds__(256) void gemm_trb(const ushort_t* __restrict__ Ab,
                                                const ushort_t* __restrict__ H0,
                                                ushort_t* __restrict__ Y0,
                                                const ushort_t* __restrict__ H1,
                                                ushort_t* __restrict__ Y1) {
    __shared__ __align__(16) ushort_t As[64 * 32];
    __shared__ __align__(16) ushort_t Bs[32 * 128];
    const ushort_t* __restrict__ H = (blockIdx.z == 0) ? H0 : H1;
    ushort_t* __restrict__ Y = (blockIdx.z == 0) ? Y0 : Y1;
    const int tid = threadIdx.x;
    const int w = tid >> 6, l = tid & 63, lr = l & 15, lg = l >> 4;
    const int n0 = blockIdx.x * 64, j0 = blockIdx.y * 128;
    f32x4 acc[4][2] = {};

    // A staging coords (round-5 exact)
    const int arow = tid >> 2, ac16 = tid & 3;
    const size_t asrc = (size_t)(n0 + arow) * NP + ((ac16 ^ (arow & 3)) << 3);
    // B staging coords: idx -> subtile layout el L = idx*8:
    //   jc0=8*(idx&1), jj=(idx>>1)&3, s=(idx>>3)&7, jb=idx>>6
    // B tr-read per-lane byte addrs (within Bs): el = (w*2+nt)*512 + lg*128 + lr
    const unsigned bs0 = lds_off(Bs);
    const unsigned btr0 = bs0 + 2u * ((unsigned)(w * 2 + 0) * 512 + (unsigned)lg * 128 + (unsigned)lr);
    const unsigned btr1 = bs0 + 2u * ((unsigned)(w * 2 + 1) * 512 + (unsigned)lg * 128 + (unsigned)lr);

    for (int ks = 0; ks < NP / 32; ++ks) {
        const int m0 = ks * 32;
        glld16(Ab + asrc + m0, (ushort_t*)((char*)As + tid * 16));
#pragma unroll
        for (int p = 0; p < 2; ++p) {
            const int idx = p * 256 + tid;
            const int row = m0 + ((idx >> 3) & 7) * 4 + ((idx >> 1) & 3);
            const int col = j0 + (idx >> 6) * 16 + (idx & 1) * 8;
            glld16(H + (size_t)row * BC + col, (ushort_t*)((char*)Bs + idx * 16));
        }
        __syncthreads();

        bf16x8 av[4];
#pragma unroll
        for (int m = 0; m < 4; ++m) {
            const int rr = m * 16 + lr;
            av[m] = *(const bf16x8*)&As[rr * 32 + ((lg * 8) ^ ((rr & 3) << 3))];
        }
        unsigned long long bq0a, bq0b, bq1a, bq1b;
        asm volatile(
            "ds_read_b64_tr_b16 %0, %4 offset:0\n\t"
            "ds_read_b64_tr_b16 %1, %4 offset:128\n\t"
            "ds_read_b64_tr_b16 %2, %5 offset:0\n\t"
            "ds_read_b64_tr_b16 %3, %5 offset:128"
            : "=v"(bq0a), "=v"(bq0b), "=v"(bq1a), "=v"(bq1b)
            : "v"(btr0), "v"(btr1));
        asm volatile("s_waitcnt lgkmcnt(0)" ::: "memory");
        __builtin_amdgcn_sched_barrier(0);
        union { unsigned long long q[2]; bf16x8 f; } u0, u1;
        u0.q[0] = bq0a; u0.q[1] = bq0b;
        u1.q[0] = bq1a; u1.q[1] = bq1b;
        bf16x8 bv[2] = {u0.f, u1.f};

#pragma unroll
        for (int m = 0; m < 4; ++m)
#pragma unroll
            for (int nt = 0; nt < 2; ++nt)
                acc[m][nt] = __builtin_amdgcn_mfma_f32_16x16x32_bf16(av[m], bv[nt], acc[m][nt], 0, 0, 0);
        __syncthreads();
    }

#pragma unroll
    for (int m = 0; m < 4; ++m)
#pragma unroll
        for (int r = 0; r < 4; ++r) {
            const int n = n0 + m * 16 + lg * 4 + r;
            if (n < NN) {
#pragma unroll
                for (int nt = 0; nt < 2; ++nt)
                    Y[(size_t)n * BC + j0 + w * 32 + nt * 16 + lr] = f2bf(acc[m][nt][r]);
            }
        }
}

// ---------------- prep: Bt[d][o][K] bf16 from pool (B^T form for MFMA) ----------------
// L0: K=128, k -> (kk=k>>6, i=1+(k&63)).  L1: K=256, s=k>>6 -> (kk=s&1, i=(s>>1)*64+(k&63)).
template <int CI, int CO, bool L0>
__global__ __launch_bounds__(256) void prepW(const float* __restrict__ Wp,
                                             ushort_t* __restrict__ Bt) {
    constexpr int K = L0 ? 128 : 256;
    const int idx = blockIdx.x * 256 + threadIdx.x;
    if (idx >= DD * CO * K) return;
    const int d = idx / (CO * K);
    const int rem = idx - d * CO * K;
    const int o = rem / K;
    const int k = rem - o * K;
    const int s = k >> 6, c = k & 63;
    const int kk = L0 ? s : (s & 1);
    const int i = L0 ? (1 + c) : ((s >> 1) * 64 + c);
    Bt[idx] = f2bf(Wp[((size_t)(d * 2 + kk) * CI + i) * CO + o]);
}

// ---------------- factored-MFMA NAPL gconv (round-5 proven LDS-staged form) ----------------
template <int NSEGS, int CO, bool GATE, bool HASX>
__global__ __launch_bounds__(256) void napl2(
    const ushort_t* __restrict__ Bt, const float* __restrict__ bp,
    const float* __restrict__ emb, const float* __restrict__ WxPool,
    const ushort_t* __restrict__ s0p, const ushort_t* __restrict__ s1p,
    const ushort_t* __restrict__ s2p, const ushort_t* __restrict__ s3p,
    const float* __restrict__ xv, const float* __restrict__ axv,
    const float* hf, float* __restrict__ zf,
    ushort_t* __restrict__ outb, float* outf, int t) {
    constexpr int K = NSEGS * 64;
    constexpr int NT = (CO == 128) ? 2 : 1;
    __shared__ __align__(16) ushort_t As[NSEGS * 64 * 64];
    const int tid = threadIdx.x;
    const int w = tid >> 6, l = tid & 63, lr = l & 15, lg = l >> 4;
    const int n0 = blockIdx.x * 2;
    const int ob = w * (16 * NT);
    const ushort_t* segs[4] = {s0p, s1p, s2p, s3p};

    // stage A: seg-major [s][64 rows][64 cols], source pre-swizzled by ((row&7)<<3) els
#pragma unroll
    for (int s = 0; s < NSEGS; ++s) {
        const ushort_t* sp = segs[s];
#pragma unroll
        for (int p = 0; p < 2; ++p) {
            const int idx = p * 256 + tid;
            const int row = idx >> 3, c16 = idx & 7;
            glld16(sp + (size_t)(n0 + (row >> 5)) * BC + (row & 31) * 64 +
                       ((c16 ^ (row & 7)) << 3),
                   (ushort_t*)((char*)As + s * 8192 + idx * 16));
        }
    }
    __syncthreads();

    f32x4 OUT[4][NT] = {};
#pragma unroll 1
    for (int d = 0; d < DD; ++d) {
        const ushort_t* btd = Bt + (size_t)d * CO * K;
        const float ea = emb[n0 * DD + d];
        const float eb = emb[(n0 + 1) * DD + d];
        f32x4 P[4][NT] = {};
#pragma unroll
        for (int s = 0; s < NSEGS; ++s)
#pragma unroll
            for (int h2 = 0; h2 < 2; ++h2) {
                const int kin = h2 * 32 + lg * 8;
                const int kg = s * 64 + kin;
                bf16x8 bv[NT];
#pragma unroll
                for (int nt = 0; nt < NT; ++nt)
                    bv[nt] = *(const bf16x8*)&btd[(size_t)(ob + nt * 16 + lr) * K + kg];
                bf16x8 av[4];
#pragma unroll
                for (int m = 0; m < 4; ++m) {
                    const int rr = m * 16 + lr;
                    av[m] = *(const bf16x8*)&As[s * 4096 + rr * 64 + (kin ^ ((rr & 7) << 3))];
                }
#pragma unroll
                for (int m = 0; m < 4; ++m)
#pragma unroll
                    for (int nt = 0; nt < NT; ++nt)
                        P[m][nt] = __builtin_amdgcn_mfma_f32_16x16x32_bf16(av[m], bv[nt], P[m][nt], 0, 0, 0);
            }
#pragma unroll
        for (int m = 0; m < 4; ++m) {
            const float e = (m < 2) ? ea : eb;
#pragma unroll
            for (int nt = 0; nt < NT; ++nt)
#pragma unroll
                for (int r = 0; r < 4; ++r)
                    OUT[m][nt][r] += e * P[m][nt][r];
        }
    }

    // per-node bias and (optional) x rank-2 weights
    float bias[2][NT];
#pragma unroll
    for (int nd = 0; nd < 2; ++nd)
#pragma unroll
        for (int nt = 0; nt < NT; ++nt) {
            float s_ = 0.f;
#pragma unroll
            for (int d = 0; d < DD; ++d)
                s_ += emb[(n0 + nd) * DD + d] * bp[d * CO + ob + nt * 16 + lr];
            bias[nd][nt] = s_;
        }
    float wx[2][2][NT] = {};
    if (HASX) {
#pragma unroll
        for (int kk = 0; kk < 2; ++kk)
#pragma unroll
            for (int nd = 0; nd < 2; ++nd)
#pragma unroll
                for (int nt = 0; nt < NT; ++nt) {
                    float s_ = 0.f;
#pragma unroll
                    for (int d = 0; d < DD; ++d)
                        s_ += emb[(n0 + nd) * DD + d] *
                              WxPool[(size_t)(d * 2 + kk) * 65 * CO + ob + nt * 16 + lr];
                    wx[kk][nd][nt] = s_;
                }
    }

#pragma unroll
    for (int m = 0; m < 4; ++m) {
        const int nd = m >> 1;
        const int n = n0 + nd;
#pragma unroll
        for (int r = 0; r < 4; ++r) {
            const int row = m * 16 + lg * 4 + r;
            const int b = row & 31;
            const size_t nb = (size_t)n * BC + b * 64;
            float xt = 0.f, axt = 0.f;
            if (HASX) {
                xt = xv[((size_t)b * TT + t) * NN + n];
                axt = axv[((size_t)b * TT + t) * NN + n];
            }
#pragma unroll
            for (int nt = 0; nt < NT; ++nt) {
                const int o = ob + nt * 16 + lr;
                float val = OUT[m][nt][r] + bias[nd][nt];
                if (HASX) val += xt * wx[0][nd][nt] + axt * wx[1][nd][nt];
                if (GATE) {
                    const float sg = sigmoidf_(val);
                    if (ob < 64) {
                        zf[nb + o] = sg;
                    } else {
                        outb[nb + (o - 64)] = f2bf(sg * hf[nb + (o - 64)]);
                    }
                } else {
                    const float hc = tanhf(val);
                    const float z = zf[nb + o];
                    const float hn = z * hf[nb + o] + (1.f - z) * hc;
                    outf[nb + o] = hn;
                    outb[nb + o] = f2bf(hn);
                }
            }
        }
    }
}

// ---------------- head: y[b,ot,n] = hb[ot] + sum_h h1[n][b*64+h]*hw[ot,h] ----------------
__global__ __launch_bounds__(256) void head_kernel(const float* __restrict__ h1,
                                                   const float* __restrict__ hw,
                                                   const float* __restrict__ hb,
                                                   float* __restrict__ y) {
    __shared__ float wl[T_OUT * HH];
    const int tid = threadIdx.x;
    for (int idx = tid; idx < T_OUT * HH; idx += 256) wl[idx] = hw[idx];
    __syncthreads();
    const int gi = blockIdx.x * 256 + tid;
    if (gi >= BB * NN) return;
    const int b = gi / NN, n = gi % NN;
    float acc[T_OUT];
#pragma unroll
    for (int ot = 0; ot < T_OUT; ++ot) acc[ot] = hb[ot];
    for (int h = 0; h < HH; ++h) {
        float v = h1[(size_t)n * BC + b * 64 + h];
#pragma unroll
        for (int ot = 0; ot < T_OUT; ++ot) acc[ot] += v * wl[ot * HH + h];
    }
#pragma unroll
    for (int ot = 0; ot < T_OUT; ++ot)
        y[((size_t)b * T_OUT + ot) * NN + n] = acc[ot];
}

extern "C" void kernel_launch(void* const* d_in, const int* in_sizes, int n_in,
                              void* d_out, int out_size, void* d_ws, size_t ws_size,
                              hipStream_t stream) {
    const float* x = (const float*)d_in[0];
    const float* node_emb = (const float*)d_in[1];
    const float* adapt_emb = (const float*)d_in[2];
    const float* Wg0 = (const float*)d_in[3];
    const float* bg0 = (const float*)d_in[4];
    const float* Wc0 = (const float*)d_in[5];
    const float* bc0 = (const float*)d_in[6];
    const float* Wg1 = (const float*)d_in[7];
    const float* bg1 = (const float*)d_in[8];
    const float* Wc1 = (const float*)d_in[9];
    const float* bc1 = (const float*)d_in[10];
    const float* head_w = (const float*)d_in[11];
    const float* head_b = (const float*)d_in[12];
    float* y = (float*)d_out;

    char* ws = (char*)d_ws;
    ushort_t* Abf  = (ushort_t*)(ws + ABF_OFF);
    float* h0f = (float*)(ws + H0F_OFF);
    float* h1f = (float*)(ws + H1F_OFF);
    float* zf  = (float*)(ws + ZF_OFF);
    ushort_t* h0b = (ushort_t*)(ws + H0B_OFF);
    ushort_t* h1b = (ushort_t*)(ws + H1B_OFF);
    ushort_t* rhb = (ushort_t*)(ws + RHB_OFF);
    ushort_t* Ah0 = (ushort_t*)(ws + AH0_OFF);
    ushort_t* AhX = (ushort_t*)(ws + AHX_OFF);
    float* Axf = (float*)(ws + AXF_OFF);
    ushort_t* Btg0 = (ushort_t*)(ws + BTG0_OFF);
    ushort_t* Btc0 = (ushort_t*)(ws + BTC0_OFF);
    ushort_t* Btg1 = (ushort_t*)(ws + BTG1_OFF);
    ushort_t* Btc1 = (ushort_t*)(ws + BTC1_OFF);
    float* Af32 = zf;  // overlay: consumed before first gate writes z

    hipMemsetAsync(h0f, 0, SZ_ST4, stream);
    hipMemsetAsync(h1f, 0, SZ_ST4, stream);
    hipMemsetAsync(h0b, 0, SZ_NPB2, stream);
    hipMemsetAsync(h1b, 0, SZ_NPB2, stream);
    hipMemsetAsync(rhb, 0, SZ_NPB2, stream);
    hipMemsetAsync(Ah0, 0, SZ_NPB2, stream);
    hipMemsetAsync(AhX, 0, SZ_NPB2, stream);

    // one-time setup
    compute_A_kernel<<<NN, 256, 0, stream>>>(adapt_emb, Af32);
    ax_kernel<<<dim3((NN + 63) / 64, BB), 256, 0, stream>>>(Af32, x, Axf);
    convert_A<<<(NP * NP) / 256, 256, 0, stream>>>(Af32, Abf);
    prepW<65, 128, true><<<(DD * 128 * 128 + 255) / 256, 256, 0, stream>>>(Wg0, Btg0);
    prepW<65, 64, true><<<(DD * 64 * 128 + 255) / 256, 256, 0, stream>>>(Wc0, Btc0);
    prepW<128, 128, false><<<(DD * 128 * 256 + 255) / 256, 256, 0, stream>>>(Wg1, Btg1);
    prepW<128, 64, false><<<(DD * 64 * 256 + 255) / 256, 256, 0, stream>>>(Wc1, Btc1);

    const dim3 gG1(NP / 64, NP / 128, 1);  // 512 blocks
    const dim3 gG2(NP / 64, NP / 128, 2);  // fused dual GEMM
    const int gN = NN * BB / 64;           // 1000 blocks

    for (int t = 0; t < TT; ++t) {
        // layer0 gate: segs [h0 | A h0] (+x rank-2) -> zf, rhb
        napl2<2, 128, true, true><<<gN, 256, 0, stream>>>(
            Btg0, bg0, node_emb, Wg0, h0b, Ah0, h0b, h0b, x, Axf, h0f, zf, rhb, nullptr, t);
        gemm_trb<<<gG1, 256, 0, stream>>>(Abf, rhb, AhX, rhb, AhX);  // Arh0
        // layer0 cand: segs [rh | A rh] (+x) -> h0f, h0b
        napl2<2, 64, false, true><<<gN, 256, 0, stream>>>(
            Btc0, bc0, node_emb, Wc0, rhb, AhX, rhb, rhb, x, Axf, h0f, zf, h0b, h0f, t);
        // fused: A @ h0_new -> Ah0 ; A @ h1_prev -> AhX
        gemm_trb<<<gG2, 256, 0, stream>>>(Abf, h0b, Ah0, h1b, AhX);
        // layer1 gate: segs [h0new | A h0new | h1 | A h1] -> zf, rhb
        napl2<4, 128, true, false><<<gN, 256, 0, stream>>>(
            Btg1, bg1, node_emb, nullptr, h0b, Ah0, h1b, AhX, nullptr, nullptr, h1f, zf, rhb, nullptr, t);
        gemm_trb<<<gG1, 256, 0, stream>>>(Abf, rhb, AhX, rhb, AhX);  // Arh1
        // layer1 cand: segs [h0new | A h0new | rh1 | A rh1] -> h1f, h1b
        napl2<4, 64, false, false><<<gN, 256, 0, stream>>>(
            Btc1, bc1, node_emb, nullptr, h0b, Ah0, rhb, AhX, nullptr, nullptr, h1f, zf, h1b, h1f, t);
    }

    head_kernel<<<(BB * NN + 255) / 256, 256, 0, stream>>>(h1f, head_w, head_b, y);
}

// Round 9
// 9729.356 us; speedup vs baseline: 1.1705x; 1.0060x over previous
//
#include <hip/hip_runtime.h>
#include <math.h>

#define NN 2000
#define BB 32
#define TT 24
#define T_OUT 12
#define HH 64
#define DD 10
#define NP 2048   // padded node dim
#define BC 2048   // B*H columns (j = b*64 + c)

typedef unsigned short ushort_t;
typedef __bf16 bf16x8 __attribute__((ext_vector_type(8)));
typedef float f32x4 __attribute__((ext_vector_type(4)));

__device__ __forceinline__ float sigmoidf_(float x) { return 1.f / (1.f + expf(-x)); }

__device__ __forceinline__ ushort_t f2bf(float f) {
    unsigned int u = __float_as_uint(f);
    unsigned int r = (u + 0x7FFFu + ((u >> 16) & 1u)) >> 16;
    return (ushort_t)r;
}
__device__ __forceinline__ float bf2f(ushort_t s) {
    return __uint_as_float(((unsigned int)s) << 16);
}

__device__ __forceinline__ void glld16(const ushort_t* g, ushort_t* lds) {
    __builtin_amdgcn_global_load_lds(
        (const __attribute__((address_space(1))) char*)g,
        (__attribute__((address_space(3))) char*)lds, 16, 0, 0);
}

__device__ __forceinline__ unsigned lds_off(const void* p) {
    return (unsigned)(size_t)(__attribute__((address_space(3))) const char*)p;
}

// ---------------- workspace layout (bytes), high-water 107,102,208 ----------------
constexpr size_t SZ_NPNP2 = (size_t)NP * NP * 2;   // 8,388,608
constexpr size_t SZ_ST4   = (size_t)NN * BC * 4;   // 16,384,000
constexpr size_t SZ_NPB2  = (size_t)NP * BC * 2;   // 8,388,608 (padded bf16 state)

constexpr size_t ABF_OFF  = 0;
constexpr size_t H0F_OFF  = ABF_OFF + SZ_NPNP2;
constexpr size_t H1F_OFF  = H0F_OFF + SZ_ST4;
constexpr size_t ZF_OFF   = H1F_OFF + SZ_ST4;       // f32; overlaid with A_f32 in setup
constexpr size_t H0B_OFF  = ZF_OFF + SZ_ST4;
constexpr size_t H1B_OFF  = H0B_OFF + SZ_NPB2;
constexpr size_t RHB_OFF  = H1B_OFF + SZ_NPB2;
constexpr size_t AH0_OFF  = RHB_OFF + SZ_NPB2;
constexpr size_t AHX_OFF  = AH0_OFF + SZ_NPB2;      // shared: Arh0 / Ah1 / Arh1
constexpr size_t AXF_OFF  = AHX_OFF + SZ_NPB2;      // [B][T][N] f32
constexpr size_t BTG0_OFF = AXF_OFF + (size_t)BB * TT * NN * 4;
constexpr size_t BTC0_OFF = BTG0_OFF + (size_t)DD * 128 * 128 * 2;  // 327,680
constexpr size_t BTG1_OFF = BTC0_OFF + (size_t)DD * 64 * 128 * 2;   // 163,840
constexpr size_t BTC1_OFF = BTG1_OFF + (size_t)DD * 128 * 256 * 2;  // 655,360
constexpr size_t WS_TOP   = BTC1_OFF + (size_t)DD * 64 * 256 * 2;   // 107,102,208

// ---------------- A_f32 = row_softmax(relu(E E^T)) ----------------
__global__ __launch_bounds__(256) void compute_A_kernel(const float* __restrict__ E,
                                                        float* __restrict__ A) {
    const int row = blockIdx.x;
    const int tid = threadIdx.x;
    float er[DD];
#pragma unroll
    for (int d = 0; d < DD; ++d) er[d] = E[row * DD + d];
    __shared__ float red[8];

    float lmax = -1e30f;
    for (int c = tid; c < NN; c += 256) {
        float s = 0.f;
#pragma unroll
        for (int d = 0; d < DD; ++d) s += er[d] * E[c * DD + d];
        s = fmaxf(s, 0.f);
        A[(size_t)row * NN + c] = s;
        lmax = fmaxf(lmax, s);
    }
#pragma unroll
    for (int o = 32; o > 0; o >>= 1) lmax = fmaxf(lmax, __shfl_down(lmax, o, 64));
    if ((tid & 63) == 0) red[tid >> 6] = lmax;
    __syncthreads();
    const float rmax = fmaxf(fmaxf(red[0], red[1]), fmaxf(red[2], red[3]));
    __syncthreads();

    float lsum = 0.f;
    for (int c = tid; c < NN; c += 256) {
        float v = expf(A[(size_t)row * NN + c] - rmax);
        A[(size_t)row * NN + c] = v;
        lsum += v;
    }
#pragma unroll
    for (int o = 32; o > 0; o >>= 1) lsum += __shfl_down(lsum, o, 64);
    if ((tid & 63) == 0) red[4 + (tid >> 6)] = lsum;
    __syncthreads();
    const float inv = 1.f / (red[4] + red[5] + red[6] + red[7]);
    for (int c = tid; c < NN; c += 256) A[(size_t)row * NN + c] *= inv;
}

// ---------------- A_f32 -> A_bf [2048][2048] with zero pad ----------------
__global__ __launch_bounds__(256) void convert_A(const float* __restrict__ Af,
                                                 ushort_t* __restrict__ Ab) {
    size_t idx = (size_t)blockIdx.x * 256 + threadIdx.x;
    int r = (int)(idx >> 11), c = (int)(idx & 2047);
    float v = (r < NN && c < NN) ? Af[(size_t)r * NN + c] : 0.f;
    Ab[idx] = f2bf(v);
}

// ---------------- Ax[b,t,n] = sum_m A[n,m] x[b,t,m]  (f32, one-time) ----------------
// v2: register-tiled outer product. Block = 64 n-rows x 96 cols (4 b x 24 t);
// thread (tr,tc) owns 4x6. As staged TRANSPOSED [mm][r] -> a-side is one aligned
// ds_read_b128; x-side 3x float2. Same summation order as v1 (bit-identical Ax).
__global__ __launch_bounds__(256) void ax2_kernel(const float* __restrict__ A,
                                                  const float* __restrict__ x,
                                                  float* __restrict__ Ax) {
    __shared__ float As[64][68];  // [mm][r], stride 68 (16B-aligned rows)
    __shared__ float xs[64][98];  // [mm][col], col = bl*24 + t
    const int n0 = blockIdx.x * 64;
    const int b0 = blockIdx.y * 4;
    const int tid = threadIdx.x;
    const int tr = tid >> 4, tc = tid & 15;
    float acc[4][6] = {};

    for (int m0 = 0; m0 < NN; m0 += 64) {
#pragma unroll
        for (int l = 0; l < 16; ++l) {
            int idx = tid + l * 256;
            int mm = idx & 63, r = idx >> 6;  // mm fast -> coalesced over A cols
            int n = n0 + r, m = m0 + mm;
            As[mm][r] = (n < NN && m < NN) ? A[(size_t)n * NN + m] : 0.f;
        }
#pragma unroll
        for (int l = 0; l < 24; ++l) {
            int idx = tid + l * 256;
            int mm = idx & 63, col = idx >> 6;  // mm fast -> coalesced over x cols
            int m = m0 + mm;
            int bl = col / 24, t = col - bl * 24;
            xs[mm][col] = (m < NN) ? x[((size_t)(b0 + bl) * TT + t) * NN + m] : 0.f;
        }
        __syncthreads();
#pragma unroll 4
        for (int mm = 0; mm < 64; ++mm) {
            float4 a4 = *(const float4*)&As[mm][tr * 4];
            float xv[6];
            *(float2*)&xv[0] = *(const float2*)&xs[mm][tc * 6];
            *(float2*)&xv[2] = *(const float2*)&xs[mm][tc * 6 + 2];
            *(float2*)&xv[4] = *(const float2*)&xs[mm][tc * 6 + 4];
            float av[4] = {a4.x, a4.y, a4.z, a4.w};
#pragma unroll
            for (int i = 0; i < 4; ++i)
#pragma unroll
                for (int j = 0; j < 6; ++j) acc[i][j] += av[i] * xv[j];
        }
        __syncthreads();
    }
#pragma unroll
    for (int i = 0; i < 4; ++i) {
        const int n = n0 + tr * 4 + i;
        if (n < NN) {
#pragma unroll
            for (int j = 0; j < 6; ++j) {
                int col = tc * 6 + j;
                int bl = col / 24, t = col - bl * 24;
                Ax[((size_t)(b0 + bl) * TT + t) * NN + n] = acc[i][j];
            }
        }
    }
}

// ---------------- MFMA GEMM with tr-read B: Y[n][j] = sum_m A[n][m] * H[m][j] ----------------
// 64x128 tile, BK=32 (m), 4 waves (col-split), round-5 2-barrier structure.
// A-tile staged XOR-swizzled. B-tile H[32 m][128 j] staged in 4x16 subtile order;
// B-frags read via ds_read_b64_tr_b16. blockIdx.z selects (H0->Y0) or (H1->Y1).
__global__ __launch_bounds__(256) void gemm_trb(const ushort_t* __restrict__ Ab,
                                                const ushort_t* __restrict__ H0,
                                                ushort_t* __restrict__ Y0,
                                                const ushort_t* __restrict__ H1,
                                                ushort_t* __restrict__ Y1) {
    __shared__ __align__(16) ushort_t As[64 * 32];
    __shared__ __align__(16) ushort_t Bs[32 * 128];
    const ushort_t* __restrict__ H = (blockIdx.z == 0) ? H0 : H1;
    ushort_t* __restrict__ Y = (blockIdx.z == 0) ? Y0 : Y1;
    const int tid = threadIdx.x;
    const int w = tid >> 6, l = tid & 63, lr = l & 15, lg = l >> 4;
    const int n0 = blockIdx.x * 64, j0 = blockIdx.y * 128;
    f32x4 acc[4][2] = {};

    const int arow = tid >> 2, ac16 = tid & 3;
    const size_t asrc = (size_t)(n0 + arow) * NP + ((ac16 ^ (arow & 3)) << 3);
    const unsigned bs0 = lds_off(Bs);
    const unsigned btr0 = bs0 + 2u * ((unsigned)(w * 2 + 0) * 512 + (unsigned)lg * 128 + (unsigned)lr);
    const unsigned btr1 = bs0 + 2u * ((unsigned)(w * 2 + 1) * 512 + (unsigned)lg * 128 + (unsigned)lr);

    for (int ks = 0; ks < NP / 32; ++ks) {
        const int m0 = ks * 32;
        glld16(Ab + asrc + m0, (ushort_t*)((char*)As + tid * 16));
#pragma unroll
        for (int p = 0; p < 2; ++p) {
            const int idx = p * 256 + tid;
            const int row = m0 + ((idx >> 3) & 7) * 4 + ((idx >> 1) & 3);
            const int col = j0 + (idx >> 6) * 16 + (idx & 1) * 8;
            glld16(H + (size_t)row * BC + col, (ushort_t*)((char*)Bs + idx * 16));
        }
        __syncthreads();

        bf16x8 av[4];
#pragma unroll
        for (int m = 0; m < 4; ++m) {
            const int rr = m * 16 + lr;
            av[m] = *(const bf16x8*)&As[rr * 32 + ((lg * 8) ^ ((rr & 3) << 3))];
        }
        unsigned long long bq0a, bq0b, bq1a, bq1b;
        asm volatile(
            "ds_read_b64_tr_b16 %0, %4 offset:0\n\t"
            "ds_read_b64_tr_b16 %1, %4 offset:128\n\t"
            "ds_read_b64_tr_b16 %2, %5 offset:0\n\t"
            "ds_read_b64_tr_b16 %3, %5 offset:128"
            : "=v"(bq0a), "=v"(bq0b), "=v"(bq1a), "=v"(bq1b)
            : "v"(btr0), "v"(btr1));
        asm volatile("s_waitcnt lgkmcnt(0)" ::: "memory");
        __builtin_amdgcn_sched_barrier(0);
        union { unsigned long long q[2]; bf16x8 f; } u0, u1;
        u0.q[0] = bq0a; u0.q[1] = bq0b;
        u1.q[0] = bq1a; u1.q[1] = bq1b;
        bf16x8 bv[2] = {u0.f, u1.f};

#pragma unroll
        for (int m = 0; m < 4; ++m)
#pragma unroll
            for (int nt = 0; nt < 2; ++nt)
                acc[m][nt] = __builtin_amdgcn_mfma_f32_16x16x32_bf16(av[m], bv[nt], acc[m][nt], 0, 0, 0);
        __syncthreads();
    }

#pragma unroll
    for (int m = 0; m < 4; ++m)
#pragma unroll
        for (int r = 0; r < 4; ++r) {
            const int n = n0 + m * 16 + lg * 4 + r;
            if (n < NN) {
#pragma unroll
                for (int nt = 0; nt < 2; ++nt)
                    Y[(size_t)n * BC + j0 + w * 32 + nt * 16 + lr] = f2bf(acc[m][nt][r]);
            }
        }
}

// ---------------- prep: Bt[d][o][K] bf16 from pool (B^T form for MFMA) ----------------
// L0: K=128, k -> (kk=k>>6, i=1+(k&63)).  L1: K=256, s=k>>6 -> (kk=s&1, i=(s>>1)*64+(k&63)).
template <int CI, int CO, bool L0>
__global__ __launch_bounds__(256) void prepW(const float* __restrict__ Wp,
                                             ushort_t* __restrict__ Bt) {
    constexpr int K = L0 ? 128 : 256;
    const int idx = blockIdx.x * 256 + threadIdx.x;
    if (idx >= DD * CO * K) return;
    const int d = idx / (CO * K);
    const int rem = idx - d * CO * K;
    const int o = rem / K;
    const int k = rem - o * K;
    const int s = k >> 6, c = k & 63;
    const int kk = L0 ? s : (s & 1);
    const int i = L0 ? (1 + c) : ((s >> 1) * 64 + c);
    Bt[idx] = f2bf(Wp[((size_t)(d * 2 + kk) * CI + i) * CO + o]);
}

// ---------------- factored-MFMA NAPL gconv (round-5 proven LDS-staged form) ----------------
template <int NSEGS, int CO, bool GATE, bool HASX>
__global__ __launch_bounds__(256) void napl2(
    const ushort_t* __restrict__ Bt, const float* __restrict__ bp,
    const float* __restrict__ emb, const float* __restrict__ WxPool,
    const ushort_t* __restrict__ s0p, const ushort_t* __restrict__ s1p,
    const ushort_t* __restrict__ s2p, const ushort_t* __restrict__ s3p,
    const float* __restrict__ xv, const float* __restrict__ axv,
    const float* hf, float* __restrict__ zf,
    ushort_t* __restrict__ outb, float* outf, int t) {
    constexpr int K = NSEGS * 64;
    constexpr int NT = (CO == 128) ? 2 : 1;
    __shared__ __align__(16) ushort_t As[NSEGS * 64 * 64];
    const int tid = threadIdx.x;
    const int w = tid >> 6, l = tid & 63, lr = l & 15, lg = l >> 4;
    const int n0 = blockIdx.x * 2;
    const int ob = w * (16 * NT);
    const ushort_t* segs[4] = {s0p, s1p, s2p, s3p};

    // stage A: seg-major [s][64 rows][64 cols], source pre-swizzled by ((row&7)<<3) els
#pragma unroll
    for (int s = 0; s < NSEGS; ++s) {
        const ushort_t* sp = segs[s];
#pragma unroll
        for (int p = 0; p < 2; ++p) {
            const int idx = p * 256 + tid;
            const int row = idx >> 3, c16 = idx & 7;
            glld16(sp + (size_t)(n0 + (row >> 5)) * BC + (row & 31) * 64 +
                       ((c16 ^ (row & 7)) << 3),
                   (ushort_t*)((char*)As + s * 8192 + idx * 16));
        }
    }
    __syncthreads();

    f32x4 OUT[4][NT] = {};
#pragma unroll 1
    for (int d = 0; d < DD; ++d) {
        const ushort_t* btd = Bt + (size_t)d * CO * K;
        const float ea = emb[n0 * DD + d];
        const float eb = emb[(n0 + 1) * DD + d];
        f32x4 P[4][NT] = {};
#pragma unroll
        for (int s = 0; s < NSEGS; ++s)
#pragma unroll
            for (int h2 = 0; h2 < 2; ++h2) {
                const int kin = h2 * 32 + lg * 8;
                const int kg = s * 64 + kin;
                bf16x8 bv[NT];
#pragma unroll
                for (int nt = 0; nt < NT; ++nt)
                    bv[nt] = *(const bf16x8*)&btd[(size_t)(ob + nt * 16 + lr) * K + kg];
                bf16x8 av[4];
#pragma unroll
                for (int m = 0; m < 4; ++m) {
                    const int rr = m * 16 + lr;
                    av[m] = *(const bf16x8*)&As[s * 4096 + rr * 64 + (kin ^ ((rr & 7) << 3))];
                }
#pragma unroll
                for (int m = 0; m < 4; ++m)
#pragma unroll
                    for (int nt = 0; nt < NT; ++nt)
                        P[m][nt] = __builtin_amdgcn_mfma_f32_16x16x32_bf16(av[m], bv[nt], P[m][nt], 0, 0, 0);
            }
#pragma unroll
        for (int m = 0; m < 4; ++m) {
            const float e = (m < 2) ? ea : eb;
#pragma unroll
            for (int nt = 0; nt < NT; ++nt)
#pragma unroll
                for (int r = 0; r < 4; ++r)
                    OUT[m][nt][r] += e * P[m][nt][r];
        }
    }

    // per-node bias and (optional) x rank-2 weights
    float bias[2][NT];
#pragma unroll
    for (int nd = 0; nd < 2; ++nd)
#pragma unroll
        for (int nt = 0; nt < NT; ++nt) {
            float s_ = 0.f;
#pragma unroll
            for (int d = 0; d < DD; ++d)
                s_ += emb[(n0 + nd) * DD + d] * bp[d * CO + ob + nt * 16 + lr];
            bias[nd][nt] = s_;
        }
    float wx[2][2][NT] = {};
    if (HASX) {
#pragma unroll
        for (int kk = 0; kk < 2; ++kk)
#pragma unroll
            for (int nd = 0; nd < 2; ++nd)
#pragma unroll
                for (int nt = 0; nt < NT; ++nt) {
                    float s_ = 0.f;
#pragma unroll
                    for (int d = 0; d < DD; ++d)
                        s_ += emb[(n0 + nd) * DD + d] *
                              WxPool[(size_t)(d * 2 + kk) * 65 * CO + ob + nt * 16 + lr];
                    wx[kk][nd][nt] = s_;
                }
    }

#pragma unroll
    for (int m = 0; m < 4; ++m) {
        const int nd = m >> 1;
        const int n = n0 + nd;
#pragma unroll
        for (int r = 0; r < 4; ++r) {
            const int row = m * 16 + lg * 4 + r;
            const int b = row & 31;
            const size_t nb = (size_t)n * BC + b * 64;
            float xt = 0.f, axt = 0.f;
            if (HASX) {
                xt = xv[((size_t)b * TT + t) * NN + n];
                axt = axv[((size_t)b * TT + t) * NN + n];
            }
#pragma unroll
            for (int nt = 0; nt < NT; ++nt) {
                const int o = ob + nt * 16 + lr;
                float val = OUT[m][nt][r] + bias[nd][nt];
                if (HASX) val += xt * wx[0][nd][nt] + axt * wx[1][nd][nt];
                if (GATE) {
                    const float sg = sigmoidf_(val);
                    if (ob < 64) {
                        zf[nb + o] = sg;
                    } else {
                        outb[nb + (o - 64)] = f2bf(sg * hf[nb + (o - 64)]);
                    }
                } else {
                    const float hc = tanhf(val);
                    const float z = zf[nb + o];
                    const float hn = z * hf[nb + o] + (1.f - z) * hc;
                    outf[nb + o] = hn;
                    outb[nb + o] = f2bf(hn);
                }
            }
        }
    }
}

// ---------------- head: y[b,ot,n] = hb[ot] + sum_h h1[n][b*64+h]*hw[ot,h] ----------------
__global__ __launch_bounds__(256) void head_kernel(const float* __restrict__ h1,
                                                   const float* __restrict__ hw,
                                                   const float* __restrict__ hb,
                                                   float* __restrict__ y) {
    __shared__ float wl[T_OUT * HH];
    const int tid = threadIdx.x;
    for (int idx = tid; idx < T_OUT * HH; idx += 256) wl[idx] = hw[idx];
    __syncthreads();
    const int gi = blockIdx.x * 256 + tid;
    if (gi >= BB * NN) return;
    const int b = gi / NN, n = gi % NN;
    float acc[T_OUT];
#pragma unroll
    for (int ot = 0; ot < T_OUT; ++ot) acc[ot] = hb[ot];
    for (int h = 0; h < HH; ++h) {
        float v = h1[(size_t)n * BC + b * 64 + h];
#pragma unroll
        for (int ot = 0; ot < T_OUT; ++ot) acc[ot] += v * wl[ot * HH + h];
    }
#pragma unroll
    for (int ot = 0; ot < T_OUT; ++ot)
        y[((size_t)b * T_OUT + ot) * NN + n] = acc[ot];
}

extern "C" void kernel_launch(void* const* d_in, const int* in_sizes, int n_in,
                              void* d_out, int out_size, void* d_ws, size_t ws_size,
                              hipStream_t stream) {
    const float* x = (const float*)d_in[0];
    const float* node_emb = (const float*)d_in[1];
    const float* adapt_emb = (const float*)d_in[2];
    const float* Wg0 = (const float*)d_in[3];
    const float* bg0 = (const float*)d_in[4];
    const float* Wc0 = (const float*)d_in[5];
    const float* bc0 = (const float*)d_in[6];
    const float* Wg1 = (const float*)d_in[7];
    const float* bg1 = (const float*)d_in[8];
    const float* Wc1 = (const float*)d_in[9];
    const float* bc1 = (const float*)d_in[10];
    const float* head_w = (const float*)d_in[11];
    const float* head_b = (const float*)d_in[12];
    float* y = (float*)d_out;

    char* ws = (char*)d_ws;
    ushort_t* Abf  = (ushort_t*)(ws + ABF_OFF);
    float* h0f = (float*)(ws + H0F_OFF);
    float* h1f = (float*)(ws + H1F_OFF);
    float* zf  = (float*)(ws + ZF_OFF);
    ushort_t* h0b = (ushort_t*)(ws + H0B_OFF);
    ushort_t* h1b = (ushort_t*)(ws + H1B_OFF);
    ushort_t* rhb = (ushort_t*)(ws + RHB_OFF);
    ushort_t* Ah0 = (ushort_t*)(ws + AH0_OFF);
    ushort_t* AhX = (ushort_t*)(ws + AHX_OFF);
    float* Axf = (float*)(ws + AXF_OFF);
    ushort_t* Btg0 = (ushort_t*)(ws + BTG0_OFF);
    ushort_t* Btc0 = (ushort_t*)(ws + BTC0_OFF);
    ushort_t* Btg1 = (ushort_t*)(ws + BTG1_OFF);
    ushort_t* Btc1 = (ushort_t*)(ws + BTC1_OFF);
    float* Af32 = zf;  // overlay: consumed before first gate writes z

    hipMemsetAsync(h0f, 0, SZ_ST4, stream);
    hipMemsetAsync(h1f, 0, SZ_ST4, stream);
    hipMemsetAsync(h0b, 0, SZ_NPB2, stream);
    hipMemsetAsync(h1b, 0, SZ_NPB2, stream);
    hipMemsetAsync(rhb, 0, SZ_NPB2, stream);
    hipMemsetAsync(Ah0, 0, SZ_NPB2, stream);
    hipMemsetAsync(AhX, 0, SZ_NPB2, stream);

    // one-time setup
    compute_A_kernel<<<NN, 256, 0, stream>>>(adapt_emb, Af32);
    ax2_kernel<<<dim3(32, 8), 256, 0, stream>>>(Af32, x, Axf);
    convert_A<<<(NP * NP) / 256, 256, 0, stream>>>(Af32, Abf);
    prepW<65, 128, true><<<(DD * 128 * 128 + 255) / 256, 256, 0, stream>>>(Wg0, Btg0);
    prepW<65, 64, true><<<(DD * 64 * 128 + 255) / 256, 256, 0, stream>>>(Wc0, Btc0);
    prepW<128, 128, false><<<(DD * 128 * 256 + 255) / 256, 256, 0, stream>>>(Wg1, Btg1);
    prepW<128, 64, false><<<(DD * 64 * 256 + 255) / 256, 256, 0, stream>>>(Wc1, Btc1);

    const dim3 gG1(NP / 64, NP / 128, 1);  // 512 blocks
    const dim3 gG2(NP / 64, NP / 128, 2);  // fused dual GEMM
    const int gN = NN * BB / 64;           // 1000 blocks

    for (int t = 0; t < TT; ++t) {
        // layer0 gate: segs [h0 | A h0] (+x rank-2) -> zf, rhb
        napl2<2, 128, true, true><<<gN, 256, 0, stream>>>(
            Btg0, bg0, node_emb, Wg0, h0b, Ah0, h0b, h0b, x, Axf, h0f, zf, rhb, nullptr, t);
        gemm_trb<<<gG1, 256, 0, stream>>>(Abf, rhb, AhX, rhb, AhX);  // Arh0
        // layer0 cand: segs [rh | A rh] (+x) -> h0f, h0b
        napl2<2, 64, false, true><<<gN, 256, 0, stream>>>(
            Btc0, bc0, node_emb, Wc0, rhb, AhX, rhb, rhb, x, Axf, h0f, zf, h0b, h0f, t);
        // fused: A @ h0_new -> Ah0 ; A @ h1_prev -> AhX
        gemm_trb<<<gG2, 256, 0, stream>>>(Abf, h0b, Ah0, h1b, AhX);
        // layer1 gate: segs [h0new | A h0new | h1 | A h1] -> zf, rhb
        napl2<4, 128, true, false><<<gN, 256, 0, stream>>>(
            Btg1, bg1, node_emb, nullptr, h0b, Ah0, h1b, AhX, nullptr, nullptr, h1f, zf, rhb, nullptr, t);
        gemm_trb<<<gG1, 256, 0, stream>>>(Abf, rhb, AhX, rhb, AhX);  // Arh1
        // layer1 cand: segs [h0new | A h0new | rh1 | A rh1] -> h1f, h1b
        napl2<4, 64, false, false><<<gN, 256, 0, stream>>>(
            Btc1, bc1, node_emb, nullptr, h0b, Ah0, rhb, AhX, nullptr, nullptr, h1f, zf, h1b, h1f, t);
    }

    head_kernel<<<(BB * NN + 255) / 256, 256, 0, stream>>>(h1f, head_w, head_b, y);
}

// Round 10
// 9645.600 us; speedup vs baseline: 1.1807x; 1.0087x over previous
//
#include <hip/hip_runtime.h>
#include <math.h>

#define NN 2000
#define BB 32
#define TT 24
#define T_OUT 12
#define HH 64
#define DD 10
#define NP 2048   // padded node dim
#define BC 2048   // B*H columns (j = b*64 + c)

typedef unsigned short ushort_t;
typedef __bf16 bf16x8 __attribute__((ext_vector_type(8)));
typedef float f32x4 __attribute__((ext_vector_type(4)));

__device__ __forceinline__ float sigmoidf_(float x) { return 1.f / (1.f + expf(-x)); }

__device__ __forceinline__ ushort_t f2bf(float f) {
    unsigned int u = __float_as_uint(f);
    unsigned int r = (u + 0x7FFFu + ((u >> 16) & 1u)) >> 16;
    return (ushort_t)r;
}
__device__ __forceinline__ float bf2f(ushort_t s) {
    return __uint_as_float(((unsigned int)s) << 16);
}

__device__ __forceinline__ void glld16(const ushort_t* g, ushort_t* lds) {
    __builtin_amdgcn_global_load_lds(
        (const __attribute__((address_space(1))) char*)g,
        (__attribute__((address_space(3))) char*)lds, 16, 0, 0);
}

__device__ __forceinline__ unsigned lds_off(const void* p) {
    return (unsigned)(size_t)(__attribute__((address_space(3))) const char*)p;
}

// ---------------- workspace layout (bytes), high-water 107,102,208 ----------------
constexpr size_t SZ_NPNP2 = (size_t)NP * NP * 2;   // 8,388,608
constexpr size_t SZ_ST4   = (size_t)NN * BC * 4;   // 16,384,000
constexpr size_t SZ_NPB2  = (size_t)NP * BC * 2;   // 8,388,608 (padded bf16 state)

constexpr size_t ABF_OFF  = 0;
constexpr size_t H0F_OFF  = ABF_OFF + SZ_NPNP2;
constexpr size_t H1F_OFF  = H0F_OFF + SZ_ST4;
constexpr size_t ZF_OFF   = H1F_OFF + SZ_ST4;       // f32; overlaid with A_f32 in setup
constexpr size_t H0B_OFF  = ZF_OFF + SZ_ST4;
constexpr size_t H1B_OFF  = H0B_OFF + SZ_NPB2;
constexpr size_t RHB_OFF  = H1B_OFF + SZ_NPB2;
constexpr size_t AH0_OFF  = RHB_OFF + SZ_NPB2;
constexpr size_t AHX_OFF  = AH0_OFF + SZ_NPB2;      // shared: Arh0 / Ah1 / Arh1
constexpr size_t AXF_OFF  = AHX_OFF + SZ_NPB2;      // [B][T][N] f32
constexpr size_t BTG0_OFF = AXF_OFF + (size_t)BB * TT * NN * 4;
constexpr size_t BTC0_OFF = BTG0_OFF + (size_t)DD * 128 * 128 * 2;  // 327,680
constexpr size_t BTG1_OFF = BTC0_OFF + (size_t)DD * 64 * 128 * 2;   // 163,840
constexpr size_t BTC1_OFF = BTG1_OFF + (size_t)DD * 128 * 256 * 2;  // 655,360
constexpr size_t WS_TOP   = BTC1_OFF + (size_t)DD * 64 * 256 * 2;   // 107,102,208

// ---------------- A_f32 = row_softmax(relu(E E^T)) ----------------
__global__ __launch_bounds__(256) void compute_A_kernel(const float* __restrict__ E,
                                                        float* __restrict__ A) {
    const int row = blockIdx.x;
    const int tid = threadIdx.x;
    float er[DD];
#pragma unroll
    for (int d = 0; d < DD; ++d) er[d] = E[row * DD + d];
    __shared__ float red[8];

    float lmax = -1e30f;
    for (int c = tid; c < NN; c += 256) {
        float s = 0.f;
#pragma unroll
        for (int d = 0; d < DD; ++d) s += er[d] * E[c * DD + d];
        s = fmaxf(s, 0.f);
        A[(size_t)row * NN + c] = s;
        lmax = fmaxf(lmax, s);
    }
#pragma unroll
    for (int o = 32; o > 0; o >>= 1) lmax = fmaxf(lmax, __shfl_down(lmax, o, 64));
    if ((tid & 63) == 0) red[tid >> 6] = lmax;
    __syncthreads();
    const float rmax = fmaxf(fmaxf(red[0], red[1]), fmaxf(red[2], red[3]));
    __syncthreads();

    float lsum = 0.f;
    for (int c = tid; c < NN; c += 256) {
        float v = expf(A[(size_t)row * NN + c] - rmax);
        A[(size_t)row * NN + c] = v;
        lsum += v;
    }
#pragma unroll
    for (int o = 32; o > 0; o >>= 1) lsum += __shfl_down(lsum, o, 64);
    if ((tid & 63) == 0) red[4 + (tid >> 6)] = lsum;
    __syncthreads();
    const float inv = 1.f / (red[4] + red[5] + red[6] + red[7]);
    for (int c = tid; c < NN; c += 256) A[(size_t)row * NN + c] *= inv;
}

// ---------------- A_f32 -> A_bf [2048][2048] with zero pad ----------------
__global__ __launch_bounds__(256) void convert_A(const float* __restrict__ Af,
                                                 ushort_t* __restrict__ Ab) {
    size_t idx = (size_t)blockIdx.x * 256 + threadIdx.x;
    int r = (int)(idx >> 11), c = (int)(idx & 2047);
    float v = (r < NN && c < NN) ? Af[(size_t)r * NN + c] : 0.f;
    Ab[idx] = f2bf(v);
}

// ---------------- Ax[b,t,n] = sum_m A[n,m] x[b,t,m]  (f32, one-time) ----------------
// v3: as v2 but As stride 66 (66%32=2 -> 2-way write aliasing, free) and 8B-aligned
// float2 reads. Same summation order as v1/v2 (bit-identical Ax).
__global__ __launch_bounds__(256) void ax2_kernel(const float* __restrict__ A,
                                                  const float* __restrict__ x,
                                                  float* __restrict__ Ax) {
    __shared__ float As[64][66];  // [mm][r]
    __shared__ float xs[64][98];  // [mm][col], col = bl*24 + t
    const int n0 = blockIdx.x * 64;
    const int b0 = blockIdx.y * 4;
    const int tid = threadIdx.x;
    const int tr = tid >> 4, tc = tid & 15;
    float acc[4][6] = {};

    for (int m0 = 0; m0 < NN; m0 += 64) {
#pragma unroll
        for (int l = 0; l < 16; ++l) {
            int idx = tid + l * 256;
            int mm = idx & 63, r = idx >> 6;  // mm fast -> coalesced over A cols
            int n = n0 + r, m = m0 + mm;
            As[mm][r] = (n < NN && m < NN) ? A[(size_t)n * NN + m] : 0.f;
        }
#pragma unroll
        for (int l = 0; l < 24; ++l) {
            int idx = tid + l * 256;
            int mm = idx & 63, col = idx >> 6;  // mm fast -> coalesced over x cols
            int m = m0 + mm;
            int bl = col / 24, t = col - bl * 24;
            xs[mm][col] = (m < NN) ? x[((size_t)(b0 + bl) * TT + t) * NN + m] : 0.f;
        }
        __syncthreads();
#pragma unroll 4
        for (int mm = 0; mm < 64; ++mm) {
            float2 a01 = *(const float2*)&As[mm][tr * 4];
            float2 a23 = *(const float2*)&As[mm][tr * 4 + 2];
            float xv[6];
            *(float2*)&xv[0] = *(const float2*)&xs[mm][tc * 6];
            *(float2*)&xv[2] = *(const float2*)&xs[mm][tc * 6 + 2];
            *(float2*)&xv[4] = *(const float2*)&xs[mm][tc * 6 + 4];
            float av[4] = {a01.x, a01.y, a23.x, a23.y};
#pragma unroll
            for (int i = 0; i < 4; ++i)
#pragma unroll
                for (int j = 0; j < 6; ++j) acc[i][j] += av[i] * xv[j];
        }
        __syncthreads();
    }
#pragma unroll
    for (int i = 0; i < 4; ++i) {
        const int n = n0 + tr * 4 + i;
        if (n < NN) {
#pragma unroll
            for (int j = 0; j < 6; ++j) {
                int col = tc * 6 + j;
                int bl = col / 24, t = col - bl * 24;
                Ax[((size_t)(b0 + bl) * TT + t) * NN + n] = acc[i][j];
            }
        }
    }
}

// ---------------- MFMA GEMM with tr-read B: Y[n][j] = sum_m A[n][m] * H[m][j] ----------------
// 64x128 tile, BK=32 (m), 4 waves (col-split), round-5 2-barrier structure.
// A-tile staged XOR-swizzled. B-tile H[32 m][128 j] staged in 4x16 subtile order;
// B-frags read via ds_read_b64_tr_b16. blockIdx.z selects (H0->Y0) or (H1->Y1).
__global__ __launch_bounds__(256) void gemm_trb(const ushort_t* __restrict__ Ab,
                                                const ushort_t* __restrict__ H0,
                                                ushort_t* __restrict__ Y0,
                                                const ushort_t* __restrict__ H1,
                                                ushort_t* __restrict__ Y1) {
    __shared__ __align__(16) ushort_t As[64 * 32];
    __shared__ __align__(16) ushort_t Bs[32 * 128];
    const ushort_t* __restrict__ H = (blockIdx.z == 0) ? H0 : H1;
    ushort_t* __restrict__ Y = (blockIdx.z == 0) ? Y0 : Y1;
    const int tid = threadIdx.x;
    const int w = tid >> 6, l = tid & 63, lr = l & 15, lg = l >> 4;
    const int n0 = blockIdx.x * 64, j0 = blockIdx.y * 128;
    f32x4 acc[4][2] = {};

    const int arow = tid >> 2, ac16 = tid & 3;
    const size_t asrc = (size_t)(n0 + arow) * NP + ((ac16 ^ (arow & 3)) << 3);
    const unsigned bs0 = lds_off(Bs);
    const unsigned btr0 = bs0 + 2u * ((unsigned)(w * 2 + 0) * 512 + (unsigned)lg * 128 + (unsigned)lr);
    const unsigned btr1 = bs0 + 2u * ((unsigned)(w * 2 + 1) * 512 + (unsigned)lg * 128 + (unsigned)lr);

    for (int ks = 0; ks < NP / 32; ++ks) {
        const int m0 = ks * 32;
        glld16(Ab + asrc + m0, (ushort_t*)((char*)As + tid * 16));
#pragma unroll
        for (int p = 0; p < 2; ++p) {
            const int idx = p * 256 + tid;
            const int row = m0 + ((idx >> 3) & 7) * 4 + ((idx >> 1) & 3);
            const int col = j0 + (idx >> 6) * 16 + (idx & 1) * 8;
            glld16(H + (size_t)row * BC + col, (ushort_t*)((char*)Bs + idx * 16));
        }
        __syncthreads();

        bf16x8 av[4];
#pragma unroll
        for (int m = 0; m < 4; ++m) {
            const int rr = m * 16 + lr;
            av[m] = *(const bf16x8*)&As[rr * 32 + ((lg * 8) ^ ((rr & 3) << 3))];
        }
        unsigned long long bq0a, bq0b, bq1a, bq1b;
        asm volatile(
            "ds_read_b64_tr_b16 %0, %4 offset:0\n\t"
            "ds_read_b64_tr_b16 %1, %4 offset:128\n\t"
            "ds_read_b64_tr_b16 %2, %5 offset:0\n\t"
            "ds_read_b64_tr_b16 %3, %5 offset:128"
            : "=v"(bq0a), "=v"(bq0b), "=v"(bq1a), "=v"(bq1b)
            : "v"(btr0), "v"(btr1));
        asm volatile("s_waitcnt lgkmcnt(0)" ::: "memory");
        __builtin_amdgcn_sched_barrier(0);
        union { unsigned long long q[2]; bf16x8 f; } u0, u1;
        u0.q[0] = bq0a; u0.q[1] = bq0b;
        u1.q[0] = bq1a; u1.q[1] = bq1b;
        bf16x8 bv[2] = {u0.f, u1.f};

#pragma unroll
        for (int m = 0; m < 4; ++m)
#pragma unroll
            for (int nt = 0; nt < 2; ++nt)
                acc[m][nt] = __builtin_amdgcn_mfma_f32_16x16x32_bf16(av[m], bv[nt], acc[m][nt], 0, 0, 0);
        __syncthreads();
    }

#pragma unroll
    for (int m = 0; m < 4; ++m)
#pragma unroll
        for (int r = 0; r < 4; ++r) {
            const int n = n0 + m * 16 + lg * 4 + r;
            if (n < NN) {
#pragma unroll
                for (int nt = 0; nt < 2; ++nt)
                    Y[(size_t)n * BC + j0 + w * 32 + nt * 16 + lr] = f2bf(acc[m][nt][r]);
            }
        }
}

// ---------------- prep: Bt[d][o][K] bf16 from pool (B^T form for MFMA) ----------------
// L0: K=128, k -> (kk=k>>6, i=1+(k&63)).  L1: K=256, s=k>>6 -> (kk=s&1, i=(s>>1)*64+(k&63)).
template <int CI, int CO, bool L0>
__global__ __launch_bounds__(256) void prepW(const float* __restrict__ Wp,
                                             ushort_t* __restrict__ Bt) {
    constexpr int K = L0 ? 128 : 256;
    const int idx = blockIdx.x * 256 + threadIdx.x;
    if (idx >= DD * CO * K) return;
    const int d = idx / (CO * K);
    const int rem = idx - d * CO * K;
    const int o = rem / K;
    const int k = rem - o * K;
    const int s = k >> 6, c = k & 63;
    const int kk = L0 ? s : (s & 1);
    const int i = L0 ? (1 + c) : ((s >> 1) * 64 + c);
    Bt[idx] = f2bf(Wp[((size_t)(d * 2 + kk) * CI + i) * CO + o]);
}

// ---------------- factored-MFMA NAPL gconv, v4: LDS-staged + av-hoist over d ----------------
// Block = 64 output rows j (= 2 nodes x 32 batches). out[j,o] = sum_d e[n,d]*(in @ Wp[d])[j,o].
// Staging identical to round-5 (proven). Per K-half (2 segs = 128 k), hoist the 16 A-frags
// into VGPRs ONCE and reuse across the 10-d loop (cuts ds_read traffic 10x -> MFMA-bound).
// GATE (CO=128): o<64 -> z=sigma -> zf ; o>=64 -> rh = sigma*hf -> outb.
// CAND (CO=64): h_new = z*hf + (1-z)*tanh(val) -> outf (f32) + outb (bf16).
template <int NSEGS, int CO, bool GATE, bool HASX>
__global__ __launch_bounds__(256) void napl2(
    const ushort_t* __restrict__ Bt, const float* __restrict__ bp,
    const float* __restrict__ emb, const float* __restrict__ WxPool,
    const ushort_t* __restrict__ s0p, const ushort_t* __restrict__ s1p,
    const ushort_t* __restrict__ s2p, const ushort_t* __restrict__ s3p,
    const float* __restrict__ xv, const float* __restrict__ axv,
    const float* hf, float* __restrict__ zf,
    ushort_t* __restrict__ outb, float* outf, int t) {
    constexpr int K = NSEGS * 64;
    constexpr int NT = (CO == 128) ? 2 : 1;
    constexpr int NHALF = NSEGS / 2;
    __shared__ __align__(16) ushort_t As[NSEGS * 64 * 64];
    const int tid = threadIdx.x;
    const int w = tid >> 6, l = tid & 63, lr = l & 15, lg = l >> 4;
    const int n0 = blockIdx.x * 2;
    const int ob = w * (16 * NT);
    const ushort_t* segs[4] = {s0p, s1p, s2p, s3p};

    // stage A: seg-major [s][64 rows][64 cols], source pre-swizzled by ((row&7)<<3) els
#pragma unroll
    for (int s = 0; s < NSEGS; ++s) {
        const ushort_t* sp = segs[s];
#pragma unroll
        for (int p = 0; p < 2; ++p) {
            const int idx = p * 256 + tid;
            const int row = idx >> 3, c16 = idx & 7;
            glld16(sp + (size_t)(n0 + (row >> 5)) * BC + (row & 31) * 64 +
                       ((c16 ^ (row & 7)) << 3),
                   (ushort_t*)((char*)As + s * 8192 + idx * 16));
        }
    }
    __syncthreads();

    f32x4 OUT[4][NT] = {};
#pragma unroll 1
    for (int hf2 = 0; hf2 < NHALF; ++hf2) {
        // hoist this half's 16 A-frags (read once, reuse across all 10 d's)
        bf16x8 av[4][4];  // [c][m], c = s_local*2 + h2
#pragma unroll
        for (int c = 0; c < 4; ++c) {
            const int s = hf2 * 2 + (c >> 1);
            const int kin = (c & 1) * 32 + lg * 8;
#pragma unroll
            for (int m = 0; m < 4; ++m) {
                const int rr = m * 16 + lr;
                av[c][m] = *(const bf16x8*)&As[s * 4096 + rr * 64 + (kin ^ ((rr & 7) << 3))];
            }
        }
#pragma unroll 1
        for (int d = 0; d < DD; ++d) {
            const ushort_t* btd = Bt + (size_t)d * CO * K;
            const float ea = emb[n0 * DD + d];
            const float eb = emb[(n0 + 1) * DD + d];
            f32x4 P[4][NT] = {};
#pragma unroll
            for (int c = 0; c < 4; ++c) {
                const int kg = (hf2 * 2 + (c >> 1)) * 64 + (c & 1) * 32 + lg * 8;
                bf16x8 bv[NT];
#pragma unroll
                for (int nt = 0; nt < NT; ++nt)
                    bv[nt] = *(const bf16x8*)&btd[(size_t)(ob + nt * 16 + lr) * K + kg];
#pragma unroll
                for (int m = 0; m < 4; ++m)
#pragma unroll
                    for (int nt = 0; nt < NT; ++nt)
                        P[m][nt] = __builtin_amdgcn_mfma_f32_16x16x32_bf16(av[c][m], bv[nt], P[m][nt], 0, 0, 0);
            }
#pragma unroll
            for (int m = 0; m < 4; ++m) {
                const float e = (m < 2) ? ea : eb;
#pragma unroll
                for (int nt = 0; nt < NT; ++nt)
#pragma unroll
                    for (int r = 0; r < 4; ++r)
                        OUT[m][nt][r] += e * P[m][nt][r];
            }
        }
    }

    // per-node bias and (optional) x rank-2 weights
    float bias[2][NT];
#pragma unroll
    for (int nd = 0; nd < 2; ++nd)
#pragma unroll
        for (int nt = 0; nt < NT; ++nt) {
            float s_ = 0.f;
#pragma unroll
            for (int d = 0; d < DD; ++d)
                s_ += emb[(n0 + nd) * DD + d] * bp[d * CO + ob + nt * 16 + lr];
            bias[nd][nt] = s_;
        }
    float wx[2][2][NT] = {};
    if (HASX) {
#pragma unroll
        for (int kk = 0; kk < 2; ++kk)
#pragma unroll
            for (int nd = 0; nd < 2; ++nd)
#pragma unroll
                for (int nt = 0; nt < NT; ++nt) {
                    float s_ = 0.f;
#pragma unroll
                    for (int d = 0; d < DD; ++d)
                        s_ += emb[(n0 + nd) * DD + d] *
                              WxPool[(size_t)(d * 2 + kk) * 65 * CO + ob + nt * 16 + lr];
                    wx[kk][nd][nt] = s_;
                }
    }

#pragma unroll
    for (int m = 0; m < 4; ++m) {
        const int nd = m >> 1;
        const int n = n0 + nd;
#pragma unroll
        for (int r = 0; r < 4; ++r) {
            const int row = m * 16 + lg * 4 + r;
            const int b = row & 31;
            const size_t nb = (size_t)n * BC + b * 64;
            float xt = 0.f, axt = 0.f;
            if (HASX) {
                xt = xv[((size_t)b * TT + t) * NN + n];
                axt = axv[((size_t)b * TT + t) * NN + n];
            }
#pragma unroll
            for (int nt = 0; nt < NT; ++nt) {
                const int o = ob + nt * 16 + lr;
                float val = OUT[m][nt][r] + bias[nd][nt];
                if (HASX) val += xt * wx[0][nd][nt] + axt * wx[1][nd][nt];
                if (GATE) {
                    const float sg = sigmoidf_(val);
                    if (ob < 64) {
                        zf[nb + o] = sg;
                    } else {
                        outb[nb + (o - 64)] = f2bf(sg * hf[nb + (o - 64)]);
                    }
                } else {
                    const float hc = tanhf(val);
                    const float z = zf[nb + o];
                    const float hn = z * hf[nb + o] + (1.f - z) * hc;
                    outf[nb + o] = hn;
                    outb[nb + o] = f2bf(hn);
                }
            }
        }
    }
}

// ---------------- head: y[b,ot,n] = hb[ot] + sum_h h1[n][b*64+h]*hw[ot,h] ----------------
__global__ __launch_bounds__(256) void head_kernel(const float* __restrict__ h1,
                                                   const float* __restrict__ hw,
                                                   const float* __restrict__ hb,
                                                   float* __restrict__ y) {
    __shared__ float wl[T_OUT * HH];
    const int tid = threadIdx.x;
    for (int idx = tid; idx < T_OUT * HH; idx += 256) wl[idx] = hw[idx];
    __syncthreads();
    const int gi = blockIdx.x * 256 + tid;
    if (gi >= BB * NN) return;
    const int b = gi / NN, n = gi % NN;
    float acc[T_OUT];
#pragma unroll
    for (int ot = 0; ot < T_OUT; ++ot) acc[ot] = hb[ot];
    for (int h = 0; h < HH; ++h) {
        float v = h1[(size_t)n * BC + b * 64 + h];
#pragma unroll
        for (int ot = 0; ot < T_OUT; ++ot) acc[ot] += v * wl[ot * HH + h];
    }
#pragma unroll
    for (int ot = 0; ot < T_OUT; ++ot)
        y[((size_t)b * T_OUT + ot) * NN + n] = acc[ot];
}

extern "C" void kernel_launch(void* const* d_in, const int* in_sizes, int n_in,
                              void* d_out, int out_size, void* d_ws, size_t ws_size,
                              hipStream_t stream) {
    const float* x = (const float*)d_in[0];
    const float* node_emb = (const float*)d_in[1];
    const float* adapt_emb = (const float*)d_in[2];
    const float* Wg0 = (const float*)d_in[3];
    const float* bg0 = (const float*)d_in[4];
    const float* Wc0 = (const float*)d_in[5];
    const float* bc0 = (const float*)d_in[6];
    const float* Wg1 = (const float*)d_in[7];
    const float* bg1 = (const float*)d_in[8];
    const float* Wc1 = (const float*)d_in[9];
    const float* bc1 = (const float*)d_in[10];
    const float* head_w = (const float*)d_in[11];
    const float* head_b = (const float*)d_in[12];
    float* y = (float*)d_out;

    char* ws = (char*)d_ws;
    ushort_t* Abf  = (ushort_t*)(ws + ABF_OFF);
    float* h0f = (float*)(ws + H0F_OFF);
    float* h1f = (float*)(ws + H1F_OFF);
    float* zf  = (float*)(ws + ZF_OFF);
    ushort_t* h0b = (ushort_t*)(ws + H0B_OFF);
    ushort_t* h1b = (ushort_t*)(ws + H1B_OFF);
    ushort_t* rhb = (ushort_t*)(ws + RHB_OFF);
    ushort_t* Ah0 = (ushort_t*)(ws + AH0_OFF);
    ushort_t* AhX = (ushort_t*)(ws + AHX_OFF);
    float* Axf = (float*)(ws + AXF_OFF);
    ushort_t* Btg0 = (ushort_t*)(ws + BTG0_OFF);
    ushort_t* Btc0 = (ushort_t*)(ws + BTC0_OFF);
    ushort_t* Btg1 = (ushort_t*)(ws + BTG1_OFF);
    ushort_t* Btc1 = (ushort_t*)(ws + BTC1_OFF);
    float* Af32 = zf;  // overlay: consumed before first gate writes z

    hipMemsetAsync(h0f, 0, SZ_ST4, stream);
    hipMemsetAsync(h1f, 0, SZ_ST4, stream);
    hipMemsetAsync(h0b, 0, SZ_NPB2, stream);
    hipMemsetAsync(h1b, 0, SZ_NPB2, stream);
    hipMemsetAsync(rhb, 0, SZ_NPB2, stream);
    hipMemsetAsync(Ah0, 0, SZ_NPB2, stream);
    hipMemsetAsync(AhX, 0, SZ_NPB2, stream);

    // one-time setup
    compute_A_kernel<<<NN, 256, 0, stream>>>(adapt_emb, Af32);
    ax2_kernel<<<dim3(32, 8), 256, 0, stream>>>(Af32, x, Axf);
    convert_A<<<(NP * NP) / 256, 256, 0, stream>>>(Af32, Abf);
    prepW<65, 128, true><<<(DD * 128 * 128 + 255) / 256, 256, 0, stream>>>(Wg0, Btg0);
    prepW<65, 64, true><<<(DD * 64 * 128 + 255) / 256, 256, 0, stream>>>(Wc0, Btc0);
    prepW<128, 128, false><<<(DD * 128 * 256 + 255) / 256, 256, 0, stream>>>(Wg1, Btg1);
    prepW<128, 64, false><<<(DD * 64 * 256 + 255) / 256, 256, 0, stream>>>(Wc1, Btc1);

    const dim3 gG1(NP / 64, NP / 128, 1);  // 512 blocks
    const dim3 gG2(NP / 64, NP / 128, 2);  // fused dual GEMM
    const int gN = NN * BB / 64;           // 1000 blocks

    for (int t = 0; t < TT; ++t) {
        // layer0 gate: segs [h0 | A h0] (+x rank-2) -> zf, rhb
        napl2<2, 128, true, true><<<gN, 256, 0, stream>>>(
            Btg0, bg0, node_emb, Wg0, h0b, Ah0, h0b, h0b, x, Axf, h0f, zf, rhb, nullptr, t);
        gemm_trb<<<gG1, 256, 0, stream>>>(Abf, rhb, AhX, rhb, AhX);  // Arh0
        // layer0 cand: segs [rh | A rh] (+x) -> h0f, h0b
        napl2<2, 64, false, true><<<gN, 256, 0, stream>>>(
            Btc0, bc0, node_emb, Wc0, rhb, AhX, rhb, rhb, x, Axf, h0f, zf, h0b, h0f, t);
        // fused: A @ h0_new -> Ah0 ; A @ h1_prev -> AhX
        gemm_trb<<<gG2, 256, 0, stream>>>(Abf, h0b, Ah0, h1b, AhX);
        // layer1 gate: segs [h0new | A h0new | h1 | A h1] -> zf, rhb
        napl2<4, 128, true, false><<<gN, 256, 0, stream>>>(
            Btg1, bg1, node_emb, nullptr, h0b, Ah0, h1b, AhX, nullptr, nullptr, h1f, zf, rhb, nullptr, t);
        gemm_trb<<<gG1, 256, 0, stream>>>(Abf, rhb, AhX, rhb, AhX);  // Arh1
        // layer1 cand: segs [h0new | A h0new | rh1 | A rh1] -> h1f, h1b
        napl2<4, 64, false, false><<<gN, 256, 0, stream>>>(
            Btc1, bc1, node_emb, nullptr, h0b, Ah0, rhb, AhX, nullptr, nullptr, h1f, zf, h1b, h1f, t);
    }

    head_kernel<<<(BB * NN + 255) / 256, 256, 0, stream>>>(h1f, head_w, head_b, y);
}

// Round 11
// 9025.548 us; speedup vs baseline: 1.2618x; 1.0687x over previous
//
#include <hip/hip_runtime.h>
#include <math.h>

#define NN 2000
#define BB 32
#define TT 24
#define T_OUT 12
#define HH 64
#define DD 10
#define NP 2048   // padded node dim
#define BC 2048   // B*H columns (j = b*64 + c)

typedef unsigned short ushort_t;
typedef __bf16 bf16x8 __attribute__((ext_vector_type(8)));
typedef float f32x4 __attribute__((ext_vector_type(4)));

__device__ __forceinline__ float sigmoidf_(float x) { return 1.f / (1.f + expf(-x)); }

__device__ __forceinline__ ushort_t f2bf(float f) {
    unsigned int u = __float_as_uint(f);
    unsigned int r = (u + 0x7FFFu + ((u >> 16) & 1u)) >> 16;
    return (ushort_t)r;
}
__device__ __forceinline__ float bf2f(ushort_t s) {
    return __uint_as_float(((unsigned int)s) << 16);
}

__device__ __forceinline__ void glld16(const ushort_t* g, ushort_t* lds) {
    __builtin_amdgcn_global_load_lds(
        (const __attribute__((address_space(1))) char*)g,
        (__attribute__((address_space(3))) char*)lds, 16, 0, 0);
}

__device__ __forceinline__ unsigned lds_off(const void* p) {
    return (unsigned)(size_t)(__attribute__((address_space(3))) const char*)p;
}

// ---------------- workspace layout (bytes), high-water 107,102,208 ----------------
constexpr size_t SZ_NPNP2 = (size_t)NP * NP * 2;   // 8,388,608
constexpr size_t SZ_ST4   = (size_t)NN * BC * 4;   // 16,384,000
constexpr size_t SZ_NPB2  = (size_t)NP * BC * 2;   // 8,388,608 (padded bf16 state)

constexpr size_t ABF_OFF  = 0;
constexpr size_t H0F_OFF  = ABF_OFF + SZ_NPNP2;
constexpr size_t H1F_OFF  = H0F_OFF + SZ_ST4;
constexpr size_t ZF_OFF   = H1F_OFF + SZ_ST4;       // f32; overlaid with A_f32 in setup
constexpr size_t H0B_OFF  = ZF_OFF + SZ_ST4;
constexpr size_t H1B_OFF  = H0B_OFF + SZ_NPB2;
constexpr size_t RHB_OFF  = H1B_OFF + SZ_NPB2;
constexpr size_t AH0_OFF  = RHB_OFF + SZ_NPB2;
constexpr size_t AHX_OFF  = AH0_OFF + SZ_NPB2;      // shared: Arh0 / Ah1 / Arh1
constexpr size_t AXF_OFF  = AHX_OFF + SZ_NPB2;      // [B][T][N] f32
constexpr size_t BTG0_OFF = AXF_OFF + (size_t)BB * TT * NN * 4;
constexpr size_t BTC0_OFF = BTG0_OFF + (size_t)DD * 128 * 128 * 2;  // 327,680
constexpr size_t BTG1_OFF = BTC0_OFF + (size_t)DD * 64 * 128 * 2;   // 163,840
constexpr size_t BTC1_OFF = BTG1_OFF + (size_t)DD * 128 * 256 * 2;  // 655,360
constexpr size_t WS_TOP   = BTC1_OFF + (size_t)DD * 64 * 256 * 2;   // 107,102,208

// ---------------- A_f32 = row_softmax(relu(E E^T)) ----------------
__global__ __launch_bounds__(256) void compute_A_kernel(const float* __restrict__ E,
                                                        float* __restrict__ A) {
    const int row = blockIdx.x;
    const int tid = threadIdx.x;
    float er[DD];
#pragma unroll
    for (int d = 0; d < DD; ++d) er[d] = E[row * DD + d];
    __shared__ float red[8];

    float lmax = -1e30f;
    for (int c = tid; c < NN; c += 256) {
        float s = 0.f;
#pragma unroll
        for (int d = 0; d < DD; ++d) s += er[d] * E[c * DD + d];
        s = fmaxf(s, 0.f);
        A[(size_t)row * NN + c] = s;
        lmax = fmaxf(lmax, s);
    }
#pragma unroll
    for (int o = 32; o > 0; o >>= 1) lmax = fmaxf(lmax, __shfl_down(lmax, o, 64));
    if ((tid & 63) == 0) red[tid >> 6] = lmax;
    __syncthreads();
    const float rmax = fmaxf(fmaxf(red[0], red[1]), fmaxf(red[2], red[3]));
    __syncthreads();

    float lsum = 0.f;
    for (int c = tid; c < NN; c += 256) {
        float v = expf(A[(size_t)row * NN + c] - rmax);
        A[(size_t)row * NN + c] = v;
        lsum += v;
    }
#pragma unroll
    for (int o = 32; o > 0; o >>= 1) lsum += __shfl_down(lsum, o, 64);
    if ((tid & 63) == 0) red[4 + (tid >> 6)] = lsum;
    __syncthreads();
    const float inv = 1.f / (red[4] + red[5] + red[6] + red[7]);
    for (int c = tid; c < NN; c += 256) A[(size_t)row * NN + c] *= inv;
}

// ---------------- A_f32 -> A_bf [2048][2048] with zero pad ----------------
__global__ __launch_bounds__(256) void convert_A(const float* __restrict__ Af,
                                                 ushort_t* __restrict__ Ab) {
    size_t idx = (size_t)blockIdx.x * 256 + threadIdx.x;
    int r = (int)(idx >> 11), c = (int)(idx & 2047);
    float v = (r < NN && c < NN) ? Af[(size_t)r * NN + c] : 0.f;
    Ab[idx] = f2bf(v);
}

// ---------------- Ax[b,t,n] = sum_m A[n,m] x[b,t,m]  (f32, one-time) ----------------
__global__ __launch_bounds__(256) void ax2_kernel(const float* __restrict__ A,
                                                  const float* __restrict__ x,
                                                  float* __restrict__ Ax) {
    __shared__ float As[64][66];  // [mm][r]
    __shared__ float xs[64][98];  // [mm][col], col = bl*24 + t
    const int n0 = blockIdx.x * 64;
    const int b0 = blockIdx.y * 4;
    const int tid = threadIdx.x;
    const int tr = tid >> 4, tc = tid & 15;
    float acc[4][6] = {};

    for (int m0 = 0; m0 < NN; m0 += 64) {
#pragma unroll
        for (int l = 0; l < 16; ++l) {
            int idx = tid + l * 256;
            int mm = idx & 63, r = idx >> 6;
            int n = n0 + r, m = m0 + mm;
            As[mm][r] = (n < NN && m < NN) ? A[(size_t)n * NN + m] : 0.f;
        }
#pragma unroll
        for (int l = 0; l < 24; ++l) {
            int idx = tid + l * 256;
            int mm = idx & 63, col = idx >> 6;
            int m = m0 + mm;
            int bl = col / 24, t = col - bl * 24;
            xs[mm][col] = (m < NN) ? x[((size_t)(b0 + bl) * TT + t) * NN + m] : 0.f;
        }
        __syncthreads();
#pragma unroll 4
        for (int mm = 0; mm < 64; ++mm) {
            float2 a01 = *(const float2*)&As[mm][tr * 4];
            float2 a23 = *(const float2*)&As[mm][tr * 4 + 2];
            float xv[6];
            *(float2*)&xv[0] = *(const float2*)&xs[mm][tc * 6];
            *(float2*)&xv[2] = *(const float2*)&xs[mm][tc * 6 + 2];
            *(float2*)&xv[4] = *(const float2*)&xs[mm][tc * 6 + 4];
            float av[4] = {a01.x, a01.y, a23.x, a23.y};
#pragma unroll
            for (int i = 0; i < 4; ++i)
#pragma unroll
                for (int j = 0; j < 6; ++j) acc[i][j] += av[i] * xv[j];
        }
        __syncthreads();
    }
#pragma unroll
    for (int i = 0; i < 4; ++i) {
        const int n = n0 + tr * 4 + i;
        if (n < NN) {
#pragma unroll
            for (int j = 0; j < 6; ++j) {
                int col = tc * 6 + j;
                int bl = col / 24, t = col - bl * 24;
                Ax[((size_t)(b0 + bl) * TT + t) * NN + n] = acc[i][j];
            }
        }
    }
}

// ---------------- MFMA GEMM with tr-read B: Y[n][j] = sum_m A[n][m] * H[m][j] ----------------
// v2: BK=64 (m), single-buffered, 2-barrier loop -> 16 MFMA + 6 staging issues per
// barrier-pair, 32 iterations (half the drains of BK=32). A-tile 64x64 XOR-swizzled.
// B-tile = two 32-row halves, each in the proven 4x16 tr-read subtile layout; all 8
// tr-reads in one asm block. kk ascending => accumulation order == BK=32 (bit-identical).
// blockIdx.z selects (H0->Y0) or (H1->Y1).
__global__ __launch_bounds__(256) void gemm_trb(const ushort_t* __restrict__ Ab,
                                                const ushort_t* __restrict__ H0,
                                                ushort_t* __restrict__ Y0,
                                                const ushort_t* __restrict__ H1,
                                                ushort_t* __restrict__ Y1) {
    __shared__ __align__(16) ushort_t As[64 * 64];       // 8 KB
    __shared__ __align__(16) ushort_t Bs[2][32 * 128];   // 2 x 8 KB
    const ushort_t* __restrict__ H = (blockIdx.z == 0) ? H0 : H1;
    ushort_t* __restrict__ Y = (blockIdx.z == 0) ? Y0 : Y1;
    const int tid = threadIdx.x;
    const int w = tid >> 6, l = tid & 63, lr = l & 15, lg = l >> 4;
    const int n0 = blockIdx.x * 64, j0 = blockIdx.y * 128;
    f32x4 acc[4][2] = {};

    // A staging coords: 64 rows x 64 k, 2 issues; row gets 8x16B slots, XOR-swizzled
    const int arow = tid >> 3, asl = tid & 7;            // issue p adds 32 rows
    const unsigned bs0 = lds_off(Bs);
    const unsigned btr_b[2] = {
        bs0 + 2u * ((unsigned)(w * 2 + 0) * 512 + (unsigned)lg * 128 + (unsigned)lr),
        bs0 + 2u * ((unsigned)(w * 2 + 1) * 512 + (unsigned)lg * 128 + (unsigned)lr)};

    for (int ks = 0; ks < NP / 64; ++ks) {
        const int k0 = ks * 64;
#pragma unroll
        for (int p = 0; p < 2; ++p) {  // A: 64x64
            const int idx = p * 256 + tid;
            const int row = idx >> 3, sl = idx & 7;
            glld16(Ab + (size_t)(n0 + row) * NP + k0 + ((sl ^ (row & 7)) << 3),
                   (ushort_t*)((char*)As + idx * 16));
        }
#pragma unroll
        for (int p = 0; p < 4; ++p) {  // B: two 32-row halves in subtile order
            const int idx = p * 256 + tid;
            const int g = idx >> 9, li = idx & 511;
            const int row = k0 + g * 32 + ((li >> 3) & 7) * 4 + ((li >> 1) & 3);
            const int col = j0 + (li >> 6) * 16 + (li & 1) * 8;
            glld16(H + (size_t)row * BC + col,
                   (ushort_t*)((char*)Bs + g * 8192 + li * 16));
        }
        __syncthreads();

        bf16x8 av[2][4];
#pragma unroll
        for (int kk = 0; kk < 2; ++kk)
#pragma unroll
            for (int m = 0; m < 4; ++m) {
                const int rr = m * 16 + lr;
                av[kk][m] = *(const bf16x8*)&As[rr * 64 + (((kk * 4 + lg) ^ (rr & 7)) << 3)];
            }
        unsigned long long bq[2][2][2];  // [kk][nt][half]
        asm volatile(
            "ds_read_b64_tr_b16 %0, %8 offset:0\n\t"
            "ds_read_b64_tr_b16 %1, %8 offset:128\n\t"
            "ds_read_b64_tr_b16 %2, %9 offset:0\n\t"
            "ds_read_b64_tr_b16 %3, %9 offset:128\n\t"
            "ds_read_b64_tr_b16 %4, %8 offset:8192\n\t"
            "ds_read_b64_tr_b16 %5, %8 offset:8320\n\t"
            "ds_read_b64_tr_b16 %6, %9 offset:8192\n\t"
            "ds_read_b64_tr_b16 %7, %9 offset:8320"
            : "=v"(bq[0][0][0]), "=v"(bq[0][0][1]), "=v"(bq[0][1][0]), "=v"(bq[0][1][1]),
              "=v"(bq[1][0][0]), "=v"(bq[1][0][1]), "=v"(bq[1][1][0]), "=v"(bq[1][1][1])
            : "v"(btr_b[0]), "v"(btr_b[1]));
        asm volatile("s_waitcnt lgkmcnt(0)" ::: "memory");
        __builtin_amdgcn_sched_barrier(0);
        bf16x8 bv[2][2];
#pragma unroll
        for (int kk = 0; kk < 2; ++kk)
#pragma unroll
            for (int nt = 0; nt < 2; ++nt) {
                union { unsigned long long q[2]; bf16x8 f; } u;
                u.q[0] = bq[kk][nt][0];
                u.q[1] = bq[kk][nt][1];
                bv[kk][nt] = u.f;
            }

#pragma unroll
        for (int kk = 0; kk < 2; ++kk)
#pragma unroll
            for (int m = 0; m < 4; ++m)
#pragma unroll
                for (int nt = 0; nt < 2; ++nt)
                    acc[m][nt] = __builtin_amdgcn_mfma_f32_16x16x32_bf16(av[kk][m], bv[kk][nt], acc[m][nt], 0, 0, 0);
        __syncthreads();
    }

#pragma unroll
    for (int m = 0; m < 4; ++m)
#pragma unroll
        for (int r = 0; r < 4; ++r) {
            const int n = n0 + m * 16 + lg * 4 + r;
            if (n < NN) {
#pragma unroll
                for (int nt = 0; nt < 2; ++nt)
                    Y[(size_t)n * BC + j0 + w * 32 + nt * 16 + lr] = f2bf(acc[m][nt][r]);
            }
        }
}

// ---------------- prep: Bt[d][o][K] bf16 from pool (B^T form for MFMA) ----------------
// L0: K=128, k -> (kk=k>>6, i=1+(k&63)).  L1: K=256, s=k>>6 -> (kk=s&1, i=(s>>1)*64+(k&63)).
template <int CI, int CO, bool L0>
__global__ __launch_bounds__(256) void prepW(const float* __restrict__ Wp,
                                             ushort_t* __restrict__ Bt) {
    constexpr int K = L0 ? 128 : 256;
    const int idx = blockIdx.x * 256 + threadIdx.x;
    if (idx >= DD * CO * K) return;
    const int d = idx / (CO * K);
    const int rem = idx - d * CO * K;
    const int o = rem / K;
    const int k = rem - o * K;
    const int s = k >> 6, c = k & 63;
    const int kk = L0 ? s : (s & 1);
    const int i = L0 ? (1 + c) : ((s >> 1) * 64 + c);
    Bt[idx] = f2bf(Wp[((size_t)(d * 2 + kk) * CI + i) * CO + o]);
}

// ---------------- factored-MFMA NAPL gconv, v4: LDS-staged + av-hoist over d ----------------
template <int NSEGS, int CO, bool GATE, bool HASX>
__global__ __launch_bounds__(256) void napl2(
    const ushort_t* __restrict__ Bt, const float* __restrict__ bp,
    const float* __restrict__ emb, const float* __restrict__ WxPool,
    const ushort_t* __restrict__ s0p, const ushort_t* __restrict__ s1p,
    const ushort_t* __restrict__ s2p, const ushort_t* __restrict__ s3p,
    const float* __restrict__ xv, const float* __restrict__ axv,
    const float* hf, float* __restrict__ zf,
    ushort_t* __restrict__ outb, float* outf, int t) {
    constexpr int K = NSEGS * 64;
    constexpr int NT = (CO == 128) ? 2 : 1;
    constexpr int NHALF = NSEGS / 2;
    __shared__ __align__(16) ushort_t As[NSEGS * 64 * 64];
    const int tid = threadIdx.x;
    const int w = tid >> 6, l = tid & 63, lr = l & 15, lg = l >> 4;
    const int n0 = blockIdx.x * 2;
    const int ob = w * (16 * NT);
    const ushort_t* segs[4] = {s0p, s1p, s2p, s3p};

#pragma unroll
    for (int s = 0; s < NSEGS; ++s) {
        const ushort_t* sp = segs[s];
#pragma unroll
        for (int p = 0; p < 2; ++p) {
            const int idx = p * 256 + tid;
            const int row = idx >> 3, c16 = idx & 7;
            glld16(sp + (size_t)(n0 + (row >> 5)) * BC + (row & 31) * 64 +
                       ((c16 ^ (row & 7)) << 3),
                   (ushort_t*)((char*)As + s * 8192 + idx * 16));
        }
    }
    __syncthreads();

    f32x4 OUT[4][NT] = {};
#pragma unroll 1
    for (int hf2 = 0; hf2 < NHALF; ++hf2) {
        bf16x8 av[4][4];  // [c][m], c = s_local*2 + h2
#pragma unroll
        for (int c = 0; c < 4; ++c) {
            const int s = hf2 * 2 + (c >> 1);
            const int kin = (c & 1) * 32 + lg * 8;
#pragma unroll
            for (int m = 0; m < 4; ++m) {
                const int rr = m * 16 + lr;
                av[c][m] = *(const bf16x8*)&As[s * 4096 + rr * 64 + (kin ^ ((rr & 7) << 3))];
            }
        }
#pragma unroll 1
        for (int d = 0; d < DD; ++d) {
            const ushort_t* btd = Bt + (size_t)d * CO * K;
            const float ea = emb[n0 * DD + d];
            const float eb = emb[(n0 + 1) * DD + d];
            f32x4 P[4][NT] = {};
#pragma unroll
            for (int c = 0; c < 4; ++c) {
                const int kg = (hf2 * 2 + (c >> 1)) * 64 + (c & 1) * 32 + lg * 8;
                bf16x8 bv[NT];
#pragma unroll
                for (int nt = 0; nt < NT; ++nt)
                    bv[nt] = *(const bf16x8*)&btd[(size_t)(ob + nt * 16 + lr) * K + kg];
#pragma unroll
                for (int m = 0; m < 4; ++m)
#pragma unroll
                    for (int nt = 0; nt < NT; ++nt)
                        P[m][nt] = __builtin_amdgcn_mfma_f32_16x16x32_bf16(av[c][m], bv[nt], P[m][nt], 0, 0, 0);
            }
#pragma unroll
            for (int m = 0; m < 4; ++m) {
                const float e = (m < 2) ? ea : eb;
#pragma unroll
                for (int nt = 0; nt < NT; ++nt)
#pragma unroll
                    for (int r = 0; r < 4; ++r)
                        OUT[m][nt][r] += e * P[m][nt][r];
            }
        }
    }

    float bias[2][NT];
#pragma unroll
    for (int nd = 0; nd < 2; ++nd)
#pragma unroll
        for (int nt = 0; nt < NT; ++nt) {
            float s_ = 0.f;
#pragma unroll
            for (int d = 0; d < DD; ++d)
                s_ += emb[(n0 + nd) * DD + d] * bp[d * CO + ob + nt * 16 + lr];
            bias[nd][nt] = s_;
        }
    float wx[2][2][NT] = {};
    if (HASX) {
#pragma unroll
        for (int kk = 0; kk < 2; ++kk)
#pragma unroll
            for (int nd = 0; nd < 2; ++nd)
#pragma unroll
                for (int nt = 0; nt < NT; ++nt) {
                    float s_ = 0.f;
#pragma unroll
                    for (int d = 0; d < DD; ++d)
                        s_ += emb[(n0 + nd) * DD + d] *
                              WxPool[(size_t)(d * 2 + kk) * 65 * CO + ob + nt * 16 + lr];
                    wx[kk][nd][nt] = s_;
                }
    }

#pragma unroll
    for (int m = 0; m < 4; ++m) {
        const int nd = m >> 1;
        const int n = n0 + nd;
#pragma unroll
        for (int r = 0; r < 4; ++r) {
            const int row = m * 16 + lg * 4 + r;
            const int b = row & 31;
            const size_t nb = (size_t)n * BC + b * 64;
            float xt = 0.f, axt = 0.f;
            if (HASX) {
                xt = xv[((size_t)b * TT + t) * NN + n];
                axt = axv[((size_t)b * TT + t) * NN + n];
            }
#pragma unroll
            for (int nt = 0; nt < NT; ++nt) {
                const int o = ob + nt * 16 + lr;
                float val = OUT[m][nt][r] + bias[nd][nt];
                if (HASX) val += xt * wx[0][nd][nt] + axt * wx[1][nd][nt];
                if (GATE) {
                    const float sg = sigmoidf_(val);
                    if (ob < 64) {
                        zf[nb + o] = sg;
                    } else {
                        outb[nb + (o - 64)] = f2bf(sg * hf[nb + (o - 64)]);
                    }
                } else {
                    const float hc = tanhf(val);
                    const float z = zf[nb + o];
                    const float hn = z * hf[nb + o] + (1.f - z) * hc;
                    outf[nb + o] = hn;
                    outb[nb + o] = f2bf(hn);
                }
            }
        }
    }
}

// ---------------- head: y[b,ot,n] = hb[ot] + sum_h h1[n][b*64+h]*hw[ot,h] ----------------
__global__ __launch_bounds__(256) void head_kernel(const float* __restrict__ h1,
                                                   const float* __restrict__ hw,
                                                   const float* __restrict__ hb,
                                                   float* __restrict__ y) {
    __shared__ float wl[T_OUT * HH];
    const int tid = threadIdx.x;
    for (int idx = tid; idx < T_OUT * HH; idx += 256) wl[idx] = hw[idx];
    __syncthreads();
    const int gi = blockIdx.x * 256 + tid;
    if (gi >= BB * NN) return;
    const int b = gi / NN, n = gi % NN;
    float acc[T_OUT];
#pragma unroll
    for (int ot = 0; ot < T_OUT; ++ot) acc[ot] = hb[ot];
    for (int h = 0; h < HH; ++h) {
        float v = h1[(size_t)n * BC + b * 64 + h];
#pragma unroll
        for (int ot = 0; ot < T_OUT; ++ot) acc[ot] += v * wl[ot * HH + h];
    }
#pragma unroll
    for (int ot = 0; ot < T_OUT; ++ot)
        y[((size_t)b * T_OUT + ot) * NN + n] = acc[ot];
}

extern "C" void kernel_launch(void* const* d_in, const int* in_sizes, int n_in,
                              void* d_out, int out_size, void* d_ws, size_t ws_size,
                              hipStream_t stream) {
    const float* x = (const float*)d_in[0];
    const float* node_emb = (const float*)d_in[1];
    const float* adapt_emb = (const float*)d_in[2];
    const float* Wg0 = (const float*)d_in[3];
    const float* bg0 = (const float*)d_in[4];
    const float* Wc0 = (const float*)d_in[5];
    const float* bc0 = (const float*)d_in[6];
    const float* Wg1 = (const float*)d_in[7];
    const float* bg1 = (const float*)d_in[8];
    const float* Wc1 = (const float*)d_in[9];
    const float* bc1 = (const float*)d_in[10];
    const float* head_w = (const float*)d_in[11];
    const float* head_b = (const float*)d_in[12];
    float* y = (float*)d_out;

    char* ws = (char*)d_ws;
    ushort_t* Abf  = (ushort_t*)(ws + ABF_OFF);
    float* h0f = (float*)(ws + H0F_OFF);
    float* h1f = (float*)(ws + H1F_OFF);
    float* zf  = (float*)(ws + ZF_OFF);
    ushort_t* h0b = (ushort_t*)(ws + H0B_OFF);
    ushort_t* h1b = (ushort_t*)(ws + H1B_OFF);
    ushort_t* rhb = (ushort_t*)(ws + RHB_OFF);
    ushort_t* Ah0 = (ushort_t*)(ws + AH0_OFF);
    ushort_t* AhX = (ushort_t*)(ws + AHX_OFF);
    float* Axf = (float*)(ws + AXF_OFF);
    ushort_t* Btg0 = (ushort_t*)(ws + BTG0_OFF);
    ushort_t* Btc0 = (ushort_t*)(ws + BTC0_OFF);
    ushort_t* Btg1 = (ushort_t*)(ws + BTG1_OFF);
    ushort_t* Btc1 = (ushort_t*)(ws + BTC1_OFF);
    float* Af32 = zf;  // overlay: consumed before first gate writes z

    hipMemsetAsync(h0f, 0, SZ_ST4, stream);
    hipMemsetAsync(h1f, 0, SZ_ST4, stream);
    hipMemsetAsync(h0b, 0, SZ_NPB2, stream);
    hipMemsetAsync(h1b, 0, SZ_NPB2, stream);
    hipMemsetAsync(rhb, 0, SZ_NPB2, stream);
    hipMemsetAsync(Ah0, 0, SZ_NPB2, stream);
    hipMemsetAsync(AhX, 0, SZ_NPB2, stream);

    // one-time setup
    compute_A_kernel<<<NN, 256, 0, stream>>>(adapt_emb, Af32);
    ax2_kernel<<<dim3(32, 8), 256, 0, stream>>>(Af32, x, Axf);
    convert_A<<<(NP * NP) / 256, 256, 0, stream>>>(Af32, Abf);
    prepW<65, 128, true><<<(DD * 128 * 128 + 255) / 256, 256, 0, stream>>>(Wg0, Btg0);
    prepW<65, 64, true><<<(DD * 64 * 128 + 255) / 256, 256, 0, stream>>>(Wc0, Btc0);
    prepW<128, 128, false><<<(DD * 128 * 256 + 255) / 256, 256, 0, stream>>>(Wg1, Btg1);
    prepW<128, 64, false><<<(DD * 64 * 256 + 255) / 256, 256, 0, stream>>>(Wc1, Btc1);

    const dim3 gG1(NP / 64, NP / 128, 1);  // 512 blocks
    const dim3 gG2(NP / 64, NP / 128, 2);  // fused dual GEMM
    const int gN = NN * BB / 64;           // 1000 blocks

    for (int t = 0; t < TT; ++t) {
        // layer0 gate: segs [h0 | A h0] (+x rank-2) -> zf, rhb
        napl2<2, 128, true, true><<<gN, 256, 0, stream>>>(
            Btg0, bg0, node_emb, Wg0, h0b, Ah0, h0b, h0b, x, Axf, h0f, zf, rhb, nullptr, t);
        gemm_trb<<<gG1, 256, 0, stream>>>(Abf, rhb, AhX, rhb, AhX);  // Arh0
        // layer0 cand: segs [rh | A rh] (+x) -> h0f, h0b
        napl2<2, 64, false, true><<<gN, 256, 0, stream>>>(
            Btc0, bc0, node_emb, Wc0, rhb, AhX, rhb, rhb, x, Axf, h0f, zf, h0b, h0f, t);
        // fused: A @ h0_new -> Ah0 ; A @ h1_prev -> AhX
        gemm_trb<<<gG2, 256, 0, stream>>>(Abf, h0b, Ah0, h1b, AhX);
        // layer1 gate: segs [h0new | A h0new | h1 | A h1] -> zf, rhb
        napl2<4, 128, true, false><<<gN, 256, 0, stream>>>(
            Btg1, bg1, node_emb, nullptr, h0b, Ah0, h1b, AhX, nullptr, nullptr, h1f, zf, rhb, nullptr, t);
        gemm_trb<<<gG1, 256, 0, stream>>>(Abf, rhb, AhX, rhb, AhX);  // Arh1
        // layer1 cand: segs [h0new | A h0new | rh1 | A rh1] -> h1f, h1b
        napl2<4, 64, false, false><<<gN, 256, 0, stream>>>(
            Btc1, bc1, node_emb, nullptr, h0b, Ah0, rhb, AhX, nullptr, nullptr, h1f, zf, h1b, h1f, t);
    }

    head_kernel<<<(BB * NN + 255) / 256, 256, 0, stream>>>(h1f, head_w, head_b, y);
}

// Round 12
// 8802.545 us; speedup vs baseline: 1.2938x; 1.0253x over previous
//
#include <hip/hip_runtime.h>
#include <math.h>

#define NN 2000
#define BB 32
#define TT 24
#define T_OUT 12
#define HH 64
#define DD 10
#define NP 2048   // padded node dim
#define BC 2048   // B*H columns (j = b*64 + c)

typedef unsigned short ushort_t;
typedef __bf16 bf16x8 __attribute__((ext_vector_type(8)));
typedef float f32x4 __attribute__((ext_vector_type(4)));

__device__ __forceinline__ float sigmoidf_(float x) { return 1.f / (1.f + expf(-x)); }

__device__ __forceinline__ ushort_t f2bf(float f) {
    unsigned int u = __float_as_uint(f);
    unsigned int r = (u + 0x7FFFu + ((u >> 16) & 1u)) >> 16;
    return (ushort_t)r;
}
__device__ __forceinline__ float bf2f(ushort_t s) {
    return __uint_as_float(((unsigned int)s) << 16);
}

__device__ __forceinline__ void glld16(const ushort_t* g, ushort_t* lds) {
    __builtin_amdgcn_global_load_lds(
        (const __attribute__((address_space(1))) char*)g,
        (__attribute__((address_space(3))) char*)lds, 16, 0, 0);
}

__device__ __forceinline__ unsigned lds_off(const void* p) {
    return (unsigned)(size_t)(__attribute__((address_space(3))) const char*)p;
}

// ---------------- workspace layout (bytes) ----------------
constexpr size_t SZ_NPNP2 = (size_t)NP * NP * 2;   // 8,388,608
constexpr size_t SZ_ST4   = (size_t)NN * BC * 4;   // 16,384,000
constexpr size_t SZ_NPB2  = (size_t)NP * BC * 2;   // 8,388,608 (padded bf16 state)

constexpr size_t ABF_OFF  = 0;
constexpr size_t H0F_OFF  = ABF_OFF + SZ_NPNP2;
constexpr size_t H1F_OFF  = H0F_OFF + SZ_ST4;
constexpr size_t ZF_OFF   = H1F_OFF + SZ_ST4;       // f32; overlaid with A_f32 in setup
constexpr size_t H0B_OFF  = ZF_OFF + SZ_ST4;
constexpr size_t H1B_OFF  = H0B_OFF + SZ_NPB2;
constexpr size_t RHB_OFF  = H1B_OFF + SZ_NPB2;
constexpr size_t AH0_OFF  = RHB_OFF + SZ_NPB2;
constexpr size_t AHX_OFF  = AH0_OFF + SZ_NPB2;
constexpr size_t AXF_OFF  = AHX_OFF + SZ_NPB2;      // [B][T][N] f32
constexpr size_t BTG0_OFF = AXF_OFF + (size_t)BB * TT * NN * 4;
constexpr size_t BTC0_OFF = BTG0_OFF + (size_t)DD * 128 * 128 * 2;  // 327,680
constexpr size_t BTG1_OFF = BTC0_OFF + (size_t)DD * 64 * 128 * 2;   // 163,840
constexpr size_t BTC1_OFF = BTG1_OFF + (size_t)DD * 128 * 256 * 2;  // 655,360
constexpr size_t WS_TOP   = BTC1_OFF + (size_t)DD * 64 * 256 * 2;   // 107,102,208
// pipelined-path extension
constexpr size_t ZF1_OFF  = WS_TOP;                      // f32 16,384,000
constexpr size_t RHB1_OFF = ZF1_OFF + SZ_ST4;            // bf16 8,388,608
constexpr size_t AHY_OFF  = RHB1_OFF + SZ_NPB2;          // bf16 8,388,608
constexpr size_t TOP_PIPE = AHY_OFF + SZ_NPB2;           // 140,263,424

// ---------------- A_f32 = row_softmax(relu(E E^T)) ----------------
__global__ __launch_bounds__(256) void compute_A_kernel(const float* __restrict__ E,
                                                        float* __restrict__ A) {
    const int row = blockIdx.x;
    const int tid = threadIdx.x;
    float er[DD];
#pragma unroll
    for (int d = 0; d < DD; ++d) er[d] = E[row * DD + d];
    __shared__ float red[8];

    float lmax = -1e30f;
    for (int c = tid; c < NN; c += 256) {
        float s = 0.f;
#pragma unroll
        for (int d = 0; d < DD; ++d) s += er[d] * E[c * DD + d];
        s = fmaxf(s, 0.f);
        A[(size_t)row * NN + c] = s;
        lmax = fmaxf(lmax, s);
    }
#pragma unroll
    for (int o = 32; o > 0; o >>= 1) lmax = fmaxf(lmax, __shfl_down(lmax, o, 64));
    if ((tid & 63) == 0) red[tid >> 6] = lmax;
    __syncthreads();
    const float rmax = fmaxf(fmaxf(red[0], red[1]), fmaxf(red[2], red[3]));
    __syncthreads();

    float lsum = 0.f;
    for (int c = tid; c < NN; c += 256) {
        float v = expf(A[(size_t)row * NN + c] - rmax);
        A[(size_t)row * NN + c] = v;
        lsum += v;
    }
#pragma unroll
    for (int o = 32; o > 0; o >>= 1) lsum += __shfl_down(lsum, o, 64);
    if ((tid & 63) == 0) red[4 + (tid >> 6)] = lsum;
    __syncthreads();
    const float inv = 1.f / (red[4] + red[5] + red[6] + red[7]);
    for (int c = tid; c < NN; c += 256) A[(size_t)row * NN + c] *= inv;
}

// ---------------- A_f32 -> A_bf [2048][2048] with zero pad ----------------
__global__ __launch_bounds__(256) void convert_A(const float* __restrict__ Af,
                                                 ushort_t* __restrict__ Ab) {
    size_t idx = (size_t)blockIdx.x * 256 + threadIdx.x;
    int r = (int)(idx >> 11), c = (int)(idx & 2047);
    float v = (r < NN && c < NN) ? Af[(size_t)r * NN + c] : 0.f;
    Ab[idx] = f2bf(v);
}

// ---------------- Ax[b,t,n] = sum_m A[n,m] x[b,t,m]  (f32, one-time) ----------------
__global__ __launch_bounds__(256) void ax2_kernel(const float* __restrict__ A,
                                                  const float* __restrict__ x,
                                                  float* __restrict__ Ax) {
    __shared__ float As[64][66];  // [mm][r]
    __shared__ float xs[64][98];  // [mm][col], col = bl*24 + t
    const int n0 = blockIdx.x * 64;
    const int b0 = blockIdx.y * 4;
    const int tid = threadIdx.x;
    const int tr = tid >> 4, tc = tid & 15;
    float acc[4][6] = {};

    for (int m0 = 0; m0 < NN; m0 += 64) {
#pragma unroll
        for (int l = 0; l < 16; ++l) {
            int idx = tid + l * 256;
            int mm = idx & 63, r = idx >> 6;
            int n = n0 + r, m = m0 + mm;
            As[mm][r] = (n < NN && m < NN) ? A[(size_t)n * NN + m] : 0.f;
        }
#pragma unroll
        for (int l = 0; l < 24; ++l) {
            int idx = tid + l * 256;
            int mm = idx & 63, col = idx >> 6;
            int m = m0 + mm;
            int bl = col / 24, t = col - bl * 24;
            xs[mm][col] = (m < NN) ? x[((size_t)(b0 + bl) * TT + t) * NN + m] : 0.f;
        }
        __syncthreads();
#pragma unroll 4
        for (int mm = 0; mm < 64; ++mm) {
            float2 a01 = *(const float2*)&As[mm][tr * 4];
            float2 a23 = *(const float2*)&As[mm][tr * 4 + 2];
            float xv[6];
            *(float2*)&xv[0] = *(const float2*)&xs[mm][tc * 6];
            *(float2*)&xv[2] = *(const float2*)&xs[mm][tc * 6 + 2];
            *(float2*)&xv[4] = *(const float2*)&xs[mm][tc * 6 + 4];
            float av[4] = {a01.x, a01.y, a23.x, a23.y};
#pragma unroll
            for (int i = 0; i < 4; ++i)
#pragma unroll
                for (int j = 0; j < 6; ++j) acc[i][j] += av[i] * xv[j];
        }
        __syncthreads();
    }
#pragma unroll
    for (int i = 0; i < 4; ++i) {
        const int n = n0 + tr * 4 + i;
        if (n < NN) {
#pragma unroll
            for (int j = 0; j < 6; ++j) {
                int col = tc * 6 + j;
                int bl = col / 24, t = col - bl * 24;
                Ax[((size_t)(b0 + bl) * TT + t) * NN + n] = acc[i][j];
            }
        }
    }
}

// ================== device bodies (shared by standalone + merged kernels) ==================

// MFMA GEMM body: Y[n][j] = sum_m A[n][m] * H[m][j]; BK=64, 24 KB smem.
__device__ __forceinline__ void gemm_body(int bx, int by,
                                          const ushort_t* __restrict__ Ab,
                                          const ushort_t* __restrict__ H,
                                          ushort_t* __restrict__ Y, char* smem) {
    ushort_t* As = (ushort_t*)smem;            // 8 KB
    ushort_t* Bs = (ushort_t*)(smem + 8192);   // 16 KB (two 8 KB halves)
    const int tid = threadIdx.x;
    const int w = tid >> 6, l = tid & 63, lr = l & 15, lg = l >> 4;
    const int n0 = bx * 64, j0 = by * 128;
    f32x4 acc[4][2] = {};

    const unsigned bs0 = lds_off(Bs);
    const unsigned btr_b[2] = {
        bs0 + 2u * ((unsigned)(w * 2 + 0) * 512 + (unsigned)lg * 128 + (unsigned)lr),
        bs0 + 2u * ((unsigned)(w * 2 + 1) * 512 + (unsigned)lg * 128 + (unsigned)lr)};

    for (int ks = 0; ks < NP / 64; ++ks) {
        const int k0 = ks * 64;
#pragma unroll
        for (int p = 0; p < 2; ++p) {  // A: 64x64, XOR-swizzled
            const int idx = p * 256 + tid;
            const int row = idx >> 3, sl = idx & 7;
            glld16(Ab + (size_t)(n0 + row) * NP + k0 + ((sl ^ (row & 7)) << 3),
                   (ushort_t*)((char*)As + idx * 16));
        }
#pragma unroll
        for (int p = 0; p < 4; ++p) {  // B: two 32-row halves in tr-read subtile order
            const int idx = p * 256 + tid;
            const int g = idx >> 9, li = idx & 511;
            const int row = k0 + g * 32 + ((li >> 3) & 7) * 4 + ((li >> 1) & 3);
            const int col = j0 + (li >> 6) * 16 + (li & 1) * 8;
            glld16(H + (size_t)row * BC + col,
                   (ushort_t*)((char*)Bs + g * 8192 + li * 16));
        }
        __syncthreads();

        bf16x8 av[2][4];
#pragma unroll
        for (int kk = 0; kk < 2; ++kk)
#pragma unroll
            for (int m = 0; m < 4; ++m) {
                const int rr = m * 16 + lr;
                av[kk][m] = *(const bf16x8*)&As[rr * 64 + (((kk * 4 + lg) ^ (rr & 7)) << 3)];
            }
        unsigned long long bq[2][2][2];  // [kk][nt][half]
        asm volatile(
            "ds_read_b64_tr_b16 %0, %8 offset:0\n\t"
            "ds_read_b64_tr_b16 %1, %8 offset:128\n\t"
            "ds_read_b64_tr_b16 %2, %9 offset:0\n\t"
            "ds_read_b64_tr_b16 %3, %9 offset:128\n\t"
            "ds_read_b64_tr_b16 %4, %8 offset:8192\n\t"
            "ds_read_b64_tr_b16 %5, %8 offset:8320\n\t"
            "ds_read_b64_tr_b16 %6, %9 offset:8192\n\t"
            "ds_read_b64_tr_b16 %7, %9 offset:8320"
            : "=v"(bq[0][0][0]), "=v"(bq[0][0][1]), "=v"(bq[0][1][0]), "=v"(bq[0][1][1]),
              "=v"(bq[1][0][0]), "=v"(bq[1][0][1]), "=v"(bq[1][1][0]), "=v"(bq[1][1][1])
            : "v"(btr_b[0]), "v"(btr_b[1]));
        asm volatile("s_waitcnt lgkmcnt(0)" ::: "memory");
        __builtin_amdgcn_sched_barrier(0);
        bf16x8 bv[2][2];
#pragma unroll
        for (int kk = 0; kk < 2; ++kk)
#pragma unroll
            for (int nt = 0; nt < 2; ++nt) {
                union { unsigned long long q[2]; bf16x8 f; } u;
                u.q[0] = bq[kk][nt][0];
                u.q[1] = bq[kk][nt][1];
                bv[kk][nt] = u.f;
            }

#pragma unroll
        for (int kk = 0; kk < 2; ++kk)
#pragma unroll
            for (int m = 0; m < 4; ++m)
#pragma unroll
                for (int nt = 0; nt < 2; ++nt)
                    acc[m][nt] = __builtin_amdgcn_mfma_f32_16x16x32_bf16(av[kk][m], bv[kk][nt], acc[m][nt], 0, 0, 0);
        __syncthreads();
    }

#pragma unroll
    for (int m = 0; m < 4; ++m)
#pragma unroll
        for (int r = 0; r < 4; ++r) {
            const int n = n0 + m * 16 + lg * 4 + r;
            if (n < NN) {
#pragma unroll
                for (int nt = 0; nt < 2; ++nt)
                    Y[(size_t)n * BC + j0 + w * 32 + nt * 16 + lr] = f2bf(acc[m][nt][r]);
            }
        }
}

// factored-MFMA NAPL body (round-11 v4: LDS-staged + av-hoist over d). smem = NSEGS*8 KB.
template <int NSEGS, int CO, bool GATE, bool HASX>
__device__ __forceinline__ void napl_body(
    int bid, char* smem,
    const ushort_t* __restrict__ Bt, const float* __restrict__ bp,
    const float* __restrict__ emb, const float* __restrict__ WxPool,
    const ushort_t* __restrict__ s0p, const ushort_t* __restrict__ s1p,
    const ushort_t* __restrict__ s2p, const ushort_t* __restrict__ s3p,
    const float* __restrict__ xv, const float* __restrict__ axv,
    const float* hf, float* __restrict__ zf,
    ushort_t* __restrict__ outb, float* outf, int t) {
    constexpr int K = NSEGS * 64;
    constexpr int NT = (CO == 128) ? 2 : 1;
    constexpr int NHALF = NSEGS / 2;
    ushort_t* As = (ushort_t*)smem;
    const int tid = threadIdx.x;
    const int w = tid >> 6, l = tid & 63, lr = l & 15, lg = l >> 4;
    const int n0 = bid * 2;
    const int ob = w * (16 * NT);
    const ushort_t* segs[4] = {s0p, s1p, s2p, s3p};

#pragma unroll
    for (int s = 0; s < NSEGS; ++s) {
        const ushort_t* sp = segs[s];
#pragma unroll
        for (int p = 0; p < 2; ++p) {
            const int idx = p * 256 + tid;
            const int row = idx >> 3, c16 = idx & 7;
            glld16(sp + (size_t)(n0 + (row >> 5)) * BC + (row & 31) * 64 +
                       ((c16 ^ (row & 7)) << 3),
                   (ushort_t*)((char*)As + s * 8192 + idx * 16));
        }
    }
    __syncthreads();

    f32x4 OUT[4][NT] = {};
#pragma unroll 1
    for (int hf2 = 0; hf2 < NHALF; ++hf2) {
        bf16x8 av[4][4];  // [c][m], c = s_local*2 + h2
#pragma unroll
        for (int c = 0; c < 4; ++c) {
            const int s = hf2 * 2 + (c >> 1);
            const int kin = (c & 1) * 32 + lg * 8;
#pragma unroll
            for (int m = 0; m < 4; ++m) {
                const int rr = m * 16 + lr;
                av[c][m] = *(const bf16x8*)&As[s * 4096 + rr * 64 + (kin ^ ((rr & 7) << 3))];
            }
        }
#pragma unroll 1
        for (int d = 0; d < DD; ++d) {
            const ushort_t* btd = Bt + (size_t)d * CO * K;
            const float ea = emb[n0 * DD + d];
            const float eb = emb[(n0 + 1) * DD + d];
            f32x4 P[4][NT] = {};
#pragma unroll
            for (int c = 0; c < 4; ++c) {
                const int kg = (hf2 * 2 + (c >> 1)) * 64 + (c & 1) * 32 + lg * 8;
                bf16x8 bv[NT];
#pragma unroll
                for (int nt = 0; nt < NT; ++nt)
                    bv[nt] = *(const bf16x8*)&btd[(size_t)(ob + nt * 16 + lr) * K + kg];
#pragma unroll
                for (int m = 0; m < 4; ++m)
#pragma unroll
                    for (int nt = 0; nt < NT; ++nt)
                        P[m][nt] = __builtin_amdgcn_mfma_f32_16x16x32_bf16(av[c][m], bv[nt], P[m][nt], 0, 0, 0);
            }
#pragma unroll
            for (int m = 0; m < 4; ++m) {
                const float e = (m < 2) ? ea : eb;
#pragma unroll
                for (int nt = 0; nt < NT; ++nt)
#pragma unroll
                    for (int r = 0; r < 4; ++r)
                        OUT[m][nt][r] += e * P[m][nt][r];
            }
        }
    }

    float bias[2][NT];
#pragma unroll
    for (int nd = 0; nd < 2; ++nd)
#pragma unroll
        for (int nt = 0; nt < NT; ++nt) {
            float s_ = 0.f;
#pragma unroll
            for (int d = 0; d < DD; ++d)
                s_ += emb[(n0 + nd) * DD + d] * bp[d * CO + ob + nt * 16 + lr];
            bias[nd][nt] = s_;
        }
    float wx[2][2][NT] = {};
    if (HASX) {
#pragma unroll
        for (int kk = 0; kk < 2; ++kk)
#pragma unroll
            for (int nd = 0; nd < 2; ++nd)
#pragma unroll
                for (int nt = 0; nt < NT; ++nt) {
                    float s_ = 0.f;
#pragma unroll
                    for (int d = 0; d < DD; ++d)
                        s_ += emb[(n0 + nd) * DD + d] *
                              WxPool[(size_t)(d * 2 + kk) * 65 * CO + ob + nt * 16 + lr];
                    wx[kk][nd][nt] = s_;
                }
    }

#pragma unroll
    for (int m = 0; m < 4; ++m) {
        const int nd = m >> 1;
        const int n = n0 + nd;
#pragma unroll
        for (int r = 0; r < 4; ++r) {
            const int row = m * 16 + lg * 4 + r;
            const int b = row & 31;
            const size_t nb = (size_t)n * BC + b * 64;
            float xt = 0.f, axt = 0.f;
            if (HASX) {
                xt = xv[((size_t)b * TT + t) * NN + n];
                axt = axv[((size_t)b * TT + t) * NN + n];
            }
#pragma unroll
            for (int nt = 0; nt < NT; ++nt) {
                const int o = ob + nt * 16 + lr;
                float val = OUT[m][nt][r] + bias[nd][nt];
                if (HASX) val += xt * wx[0][nd][nt] + axt * wx[1][nd][nt];
                if (GATE) {
                    const float sg = sigmoidf_(val);
                    if (ob < 64) {
                        zf[nb + o] = sg;
                    } else {
                        outb[nb + (o - 64)] = f2bf(sg * hf[nb + (o - 64)]);
                    }
                } else {
                    const float hc = tanhf(val);
                    const float z = zf[nb + o];
                    const float hn = z * hf[nb + o] + (1.f - z) * hc;
                    outf[nb + o] = hn;
                    outb[nb + o] = f2bf(hn);
                }
            }
        }
    }
}

// ================== kernels ==================

__global__ __launch_bounds__(256) void gemm_trb(const ushort_t* __restrict__ Ab,
                                                const ushort_t* __restrict__ H0,
                                                ushort_t* __restrict__ Y0,
                                                const ushort_t* __restrict__ H1,
                                                ushort_t* __restrict__ Y1) {
    __shared__ __align__(16) char smem[24576];
    gemm_body(blockIdx.x, blockIdx.y, Ab,
              (blockIdx.z == 0) ? H0 : H1, (blockIdx.z == 0) ? Y0 : Y1, smem);
}

template <int NSEGS, int CO, bool GATE, bool HASX>
__global__ __launch_bounds__(256) void napl2(
    const ushort_t* __restrict__ Bt, const float* __restrict__ bp,
    const float* __restrict__ emb, const float* __restrict__ WxPool,
    const ushort_t* __restrict__ s0p, const ushort_t* __restrict__ s1p,
    const ushort_t* __restrict__ s2p, const ushort_t* __restrict__ s3p,
    const float* __restrict__ xv, const float* __restrict__ axv,
    const float* hf, float* __restrict__ zf,
    ushort_t* __restrict__ outb, float* outf, int t) {
    __shared__ __align__(16) char smem[NSEGS * 8192];
    napl_body<NSEGS, CO, GATE, HASX>(blockIdx.x, smem, Bt, bp, emb, WxPool,
                                     s0p, s1p, s2p, s3p, xv, axv, hf, zf, outb, outf, t);
}

// mergeA: blocks [0,512) = gemm (A@Hg -> Yg); blocks [512,1512) = layer0 GATE (t+1)
__global__ __launch_bounds__(256) void mergeA_k(
    const ushort_t* __restrict__ Abf, const ushort_t* __restrict__ Hg,
    ushort_t* __restrict__ Yg,
    const ushort_t* __restrict__ Bt, const float* __restrict__ bp,
    const float* __restrict__ emb, const float* __restrict__ Wx,
    const ushort_t* __restrict__ s0, const ushort_t* __restrict__ s1,
    const float* __restrict__ xv, const float* __restrict__ axv,
    const float* hf, float* __restrict__ zf, ushort_t* __restrict__ outb, int t) {
    __shared__ __align__(16) char smem[24576];
    const int g = blockIdx.x;
    if (g < 512)
        gemm_body(g & 31, g >> 5, Abf, Hg, Yg, smem);
    else
        napl_body<2, 128, true, true>(g - 512, smem, Bt, bp, emb, Wx,
                                      s0, s1, s0, s0, xv, axv, hf, zf, outb, nullptr, t);
}

// mergeB: blocks [0,512) = gemm (A@Hg -> Yg); blocks [512,1512) = layer1 CAND (t)
__global__ __launch_bounds__(256) void mergeB_k(
    const ushort_t* __restrict__ Abf, const ushort_t* __restrict__ Hg,
    ushort_t* __restrict__ Yg,
    const ushort_t* __restrict__ Bt, const float* __restrict__ bp,
    const float* __restrict__ emb,
    const ushort_t* __restrict__ s0, const ushort_t* __restrict__ s1,
    const ushort_t* __restrict__ s2, const ushort_t* __restrict__ s3,
    const float* hf, float* __restrict__ zf,
    ushort_t* __restrict__ outb, float* outf, int t) {
    __shared__ __align__(16) char smem[32768];
    const int g = blockIdx.x;
    if (g < 512)
        gemm_body(g & 31, g >> 5, Abf, Hg, Yg, smem);
    else
        napl_body<4, 64, false, false>(g - 512, smem, Bt, bp, emb, nullptr,
                                       s0, s1, s2, s3, nullptr, nullptr, hf, zf, outb, outf, t);
}

// ---------------- prep: Bt[d][o][K] bf16 from pool (B^T form for MFMA) ----------------
template <int CI, int CO, bool L0>
__global__ __launch_bounds__(256) void prepW(const float* __restrict__ Wp,
                                             ushort_t* __restrict__ Bt) {
    constexpr int K = L0 ? 128 : 256;
    const int idx = blockIdx.x * 256 + threadIdx.x;
    if (idx >= DD * CO * K) return;
    const int d = idx / (CO * K);
    const int rem = idx - d * CO * K;
    const int o = rem / K;
    const int k = rem - o * K;
    const int s = k >> 6, c = k & 63;
    const int kk = L0 ? s : (s & 1);
    const int i = L0 ? (1 + c) : ((s >> 1) * 64 + c);
    Bt[idx] = f2bf(Wp[((size_t)(d * 2 + kk) * CI + i) * CO + o]);
}

// ---------------- head ----------------
__global__ __launch_bounds__(256) void head_kernel(const float* __restrict__ h1,
                                                   const float* __restrict__ hw,
                                                   const float* __restrict__ hb,
                                                   float* __restrict__ y) {
    __shared__ float wl[T_OUT * HH];
    const int tid = threadIdx.x;
    for (int idx = tid; idx < T_OUT * HH; idx += 256) wl[idx] = hw[idx];
    __syncthreads();
    const int gi = blockIdx.x * 256 + tid;
    if (gi >= BB * NN) return;
    const int b = gi / NN, n = gi % NN;
    float acc[T_OUT];
#pragma unroll
    for (int ot = 0; ot < T_OUT; ++ot) acc[ot] = hb[ot];
    for (int h = 0; h < HH; ++h) {
        float v = h1[(size_t)n * BC + b * 64 + h];
#pragma unroll
        for (int ot = 0; ot < T_OUT; ++ot) acc[ot] += v * wl[ot * HH + h];
    }
#pragma unroll
    for (int ot = 0; ot < T_OUT; ++ot)
        y[((size_t)b * T_OUT + ot) * NN + n] = acc[ot];
}

extern "C" void kernel_launch(void* const* d_in, const int* in_sizes, int n_in,
                              void* d_out, int out_size, void* d_ws, size_t ws_size,
                              hipStream_t stream) {
    const float* x = (const float*)d_in[0];
    const float* node_emb = (const float*)d_in[1];
    const float* adapt_emb = (const float*)d_in[2];
    const float* Wg0 = (const float*)d_in[3];
    const float* bg0 = (const float*)d_in[4];
    const float* Wc0 = (const float*)d_in[5];
    const float* bc0 = (const float*)d_in[6];
    const float* Wg1 = (const float*)d_in[7];
    const float* bg1 = (const float*)d_in[8];
    const float* Wc1 = (const float*)d_in[9];
    const float* bc1 = (const float*)d_in[10];
    const float* head_w = (const float*)d_in[11];
    const float* head_b = (const float*)d_in[12];
    float* y = (float*)d_out;

    char* ws = (char*)d_ws;
    ushort_t* Abf  = (ushort_t*)(ws + ABF_OFF);
    float* h0f = (float*)(ws + H0F_OFF);
    float* h1f = (float*)(ws + H1F_OFF);
    float* zf  = (float*)(ws + ZF_OFF);
    ushort_t* h0b = (ushort_t*)(ws + H0B_OFF);
    ushort_t* h1b = (ushort_t*)(ws + H1B_OFF);
    ushort_t* rhb = (ushort_t*)(ws + RHB_OFF);
    ushort_t* Ah0 = (ushort_t*)(ws + AH0_OFF);
    ushort_t* AhX = (ushort_t*)(ws + AHX_OFF);
    float* Axf = (float*)(ws + AXF_OFF);
    ushort_t* Btg0 = (ushort_t*)(ws + BTG0_OFF);
    ushort_t* Btc0 = (ushort_t*)(ws + BTC0_OFF);
    ushort_t* Btg1 = (ushort_t*)(ws + BTG1_OFF);
    ushort_t* Btc1 = (ushort_t*)(ws + BTC1_OFF);
    float* Af32 = zf;  // overlay: consumed before first gate writes z

    const bool pipe = (ws_size >= TOP_PIPE);

    hipMemsetAsync(h0f, 0, SZ_ST4, stream);
    hipMemsetAsync(h1f, 0, SZ_ST4, stream);
    hipMemsetAsync(h0b, 0, SZ_NPB2, stream);
    hipMemsetAsync(h1b, 0, SZ_NPB2, stream);
    hipMemsetAsync(rhb, 0, SZ_NPB2, stream);
    hipMemsetAsync(Ah0, 0, SZ_NPB2, stream);
    hipMemsetAsync(AhX, 0, SZ_NPB2, stream);

    compute_A_kernel<<<NN, 256, 0, stream>>>(adapt_emb, Af32);
    ax2_kernel<<<dim3(32, 8), 256, 0, stream>>>(Af32, x, Axf);
    convert_A<<<(NP * NP) / 256, 256, 0, stream>>>(Af32, Abf);
    prepW<65, 128, true><<<(DD * 128 * 128 + 255) / 256, 256, 0, stream>>>(Wg0, Btg0);
    prepW<65, 64, true><<<(DD * 64 * 128 + 255) / 256, 256, 0, stream>>>(Wc0, Btc0);
    prepW<128, 128, false><<<(DD * 128 * 256 + 255) / 256, 256, 0, stream>>>(Wg1, Btg1);
    prepW<128, 64, false><<<(DD * 64 * 256 + 255) / 256, 256, 0, stream>>>(Wc1, Btc1);

    const dim3 gG1(NP / 64, NP / 128, 1);  // 512 blocks
    const dim3 gG2(NP / 64, NP / 128, 2);  // fused dual GEMM
    const int gN = NN * BB / 64;           // 1000 blocks

    if (pipe) {
        float* zf0 = zf;
        ushort_t* rhb0 = rhb;
        float* zf1 = (float*)(ws + ZF1_OFF);
        ushort_t* rhb1 = (ushort_t*)(ws + RHB1_OFF);
        ushort_t* AhY = (ushort_t*)(ws + AHY_OFF);
        hipMemsetAsync(rhb1, 0, SZ_NPB2, stream);

        // prologue t=0: G0, R0, C0, G2, G1
        napl2<2, 128, true, true><<<gN, 256, 0, stream>>>(
            Btg0, bg0, node_emb, Wg0, h0b, Ah0, h0b, h0b, x, Axf, h0f, zf0, rhb0, nullptr, 0);
        gemm_trb<<<gG1, 256, 0, stream>>>(Abf, rhb0, AhY, rhb0, AhY);
        napl2<2, 64, false, true><<<gN, 256, 0, stream>>>(
            Btc0, bc0, node_emb, Wc0, rhb0, AhY, rhb0, rhb0, x, Axf, h0f, zf0, h0b, h0f, 0);
        gemm_trb<<<gG2, 256, 0, stream>>>(Abf, h0b, Ah0, h1b, AhX);
        napl2<4, 128, true, false><<<gN, 256, 0, stream>>>(
            Btg1, bg1, node_emb, nullptr, h0b, Ah0, h1b, AhX, nullptr, nullptr, h1f, zf1, rhb1, nullptr, 0);

        for (int t = 0; t < TT - 1; ++t) {
            // M_A: R1(t): AhX <- A@rhb1  ||  gate0(t+1): zf0, rhb0
            mergeA_k<<<1512, 256, 0, stream>>>(Abf, rhb1, AhX,
                Btg0, bg0, node_emb, Wg0, h0b, Ah0, x, Axf, h0f, zf0, rhb0, t + 1);
            // M_B: cand1(t): h1f,h1b  ||  R0(t+1): AhY <- A@rhb0
            mergeB_k<<<1512, 256, 0, stream>>>(Abf, rhb0, AhY,
                Btc1, bc1, node_emb, h0b, Ah0, rhb1, AhX, h1f, zf1, h1b, h1f, t);
            // C0(t+1)
            napl2<2, 64, false, true><<<gN, 256, 0, stream>>>(
                Btc0, bc0, node_emb, Wc0, rhb0, AhY, rhb0, rhb0, x, Axf, h0f, zf0, h0b, h0f, t + 1);
            // G2(t+1)
            gemm_trb<<<gG2, 256, 0, stream>>>(Abf, h0b, Ah0, h1b, AhX);
            // G1(t+1)
            napl2<4, 128, true, false><<<gN, 256, 0, stream>>>(
                Btg1, bg1, node_emb, nullptr, h0b, Ah0, h1b, AhX, nullptr, nullptr, h1f, zf1, rhb1, nullptr, t + 1);
        }
        // epilogue t=TT-1: R1, C1
        gemm_trb<<<gG1, 256, 0, stream>>>(Abf, rhb1, AhX, rhb1, AhX);
        napl2<4, 64, false, false><<<gN, 256, 0, stream>>>(
            Btc1, bc1, node_emb, nullptr, h0b, Ah0, rhb1, AhX, nullptr, nullptr, h1f, zf1, h1b, h1f, TT - 1);
    } else {
        // fallback: round-11 proven schedule (single zf/rhb/AhX)
        for (int t = 0; t < TT; ++t) {
            napl2<2, 128, true, true><<<gN, 256, 0, stream>>>(
                Btg0, bg0, node_emb, Wg0, h0b, Ah0, h0b, h0b, x, Axf, h0f, zf, rhb, nullptr, t);
            gemm_trb<<<gG1, 256, 0, stream>>>(Abf, rhb, AhX, rhb, AhX);
            napl2<2, 64, false, true><<<gN, 256, 0, stream>>>(
                Btc0, bc0, node_emb, Wc0, rhb, AhX, rhb, rhb, x, Axf, h0f, zf, h0b, h0f, t);
            gemm_trb<<<gG2, 256, 0, stream>>>(Abf, h0b, Ah0, h1b, AhX);
            napl2<4, 128, true, false><<<gN, 256, 0, stream>>>(
                Btg1, bg1, node_emb, nullptr, h0b, Ah0, h1b, AhX, nullptr, nullptr, h1f, zf, rhb, nullptr, t);
            gemm_trb<<<gG1, 256, 0, stream>>>(Abf, rhb, AhX, rhb, AhX);
            napl2<4, 64, false, false><<<gN, 256, 0, stream>>>(
                Btc1, bc1, node_emb, nullptr, h0b, Ah0, rhb, AhX, nullptr, nullptr, h1f, zf, h1b, h1f, t);
        }
    }

    head_kernel<<<(BB * NN + 255) / 256, 256, 0, stream>>>(h1f, head_w, head_b, y);
}

// Round 13
// 8671.124 us; speedup vs baseline: 1.3134x; 1.0152x over previous
//
#include <hip/hip_runtime.h>
#include <math.h>

#define NN 2000
#define BB 32
#define TT 24
#define T_OUT 12
#define HH 64
#define DD 10
#define NP 2048   // padded node dim
#define BC 2048   // B*H columns (j = b*64 + c)

typedef unsigned short ushort_t;
typedef __bf16 bf16x8 __attribute__((ext_vector_type(8)));
typedef float f32x4 __attribute__((ext_vector_type(4)));

__device__ __forceinline__ float sigmoidf_(float x) { return 1.f / (1.f + expf(-x)); }

__device__ __forceinline__ ushort_t f2bf(float f) {
    unsigned int u = __float_as_uint(f);
    unsigned int r = (u + 0x7FFFu + ((u >> 16) & 1u)) >> 16;
    return (ushort_t)r;
}
__device__ __forceinline__ float bf2f(ushort_t s) {
    return __uint_as_float(((unsigned int)s) << 16);
}

__device__ __forceinline__ void glld16(const ushort_t* g, ushort_t* lds) {
    __builtin_amdgcn_global_load_lds(
        (const __attribute__((address_space(1))) char*)g,
        (__attribute__((address_space(3))) char*)lds, 16, 0, 0);
}

__device__ __forceinline__ unsigned lds_off(const void* p) {
    return (unsigned)(size_t)(__attribute__((address_space(3))) const char*)p;
}

// ---------------- workspace layout (bytes) ----------------
constexpr size_t SZ_NPNP2 = (size_t)NP * NP * 2;   // 8,388,608
constexpr size_t SZ_ST4   = (size_t)NN * BC * 4;   // 16,384,000
constexpr size_t SZ_NPB2  = (size_t)NP * BC * 2;   // 8,388,608 (padded bf16 state)

constexpr size_t ABF_OFF  = 0;
constexpr size_t H0F_OFF  = ABF_OFF + SZ_NPNP2;
constexpr size_t H1F_OFF  = H0F_OFF + SZ_ST4;
constexpr size_t ZF_OFF   = H1F_OFF + SZ_ST4;       // f32; overlaid with A_f32 in setup
constexpr size_t H0B_OFF  = ZF_OFF + SZ_ST4;
constexpr size_t H1B_OFF  = H0B_OFF + SZ_NPB2;
constexpr size_t RHB_OFF  = H1B_OFF + SZ_NPB2;
constexpr size_t AH0_OFF  = RHB_OFF + SZ_NPB2;
constexpr size_t AHX_OFF  = AH0_OFF + SZ_NPB2;
constexpr size_t AXF_OFF  = AHX_OFF + SZ_NPB2;      // [B][T][N] f32
constexpr size_t BTG0_OFF = AXF_OFF + (size_t)BB * TT * NN * 4;
constexpr size_t BTC0_OFF = BTG0_OFF + (size_t)DD * 128 * 128 * 2;  // 327,680
constexpr size_t BTG1_OFF = BTC0_OFF + (size_t)DD * 64 * 128 * 2;   // 163,840
constexpr size_t BTC1_OFF = BTG1_OFF + (size_t)DD * 128 * 256 * 2;  // 655,360
constexpr size_t WS_TOP   = BTC1_OFF + (size_t)DD * 64 * 256 * 2;   // 107,102,208
// pipelined-path extension
constexpr size_t ZF1_OFF  = WS_TOP;                      // f32 16,384,000
constexpr size_t RHB1_OFF = ZF1_OFF + SZ_ST4;            // bf16 8,388,608
constexpr size_t AHY_OFF  = RHB1_OFF + SZ_NPB2;          // bf16 8,388,608
constexpr size_t TOP_PIPE = AHY_OFF + SZ_NPB2;           // 140,263,424

// ---------------- A_f32 = row_softmax(relu(E E^T)) ----------------
__global__ __launch_bounds__(256) void compute_A_kernel(const float* __restrict__ E,
                                                        float* __restrict__ A) {
    const int row = blockIdx.x;
    const int tid = threadIdx.x;
    float er[DD];
#pragma unroll
    for (int d = 0; d < DD; ++d) er[d] = E[row * DD + d];
    __shared__ float red[8];

    float lmax = -1e30f;
    for (int c = tid; c < NN; c += 256) {
        float s = 0.f;
#pragma unroll
        for (int d = 0; d < DD; ++d) s += er[d] * E[c * DD + d];
        s = fmaxf(s, 0.f);
        A[(size_t)row * NN + c] = s;
        lmax = fmaxf(lmax, s);
    }
#pragma unroll
    for (int o = 32; o > 0; o >>= 1) lmax = fmaxf(lmax, __shfl_down(lmax, o, 64));
    if ((tid & 63) == 0) red[tid >> 6] = lmax;
    __syncthreads();
    const float rmax = fmaxf(fmaxf(red[0], red[1]), fmaxf(red[2], red[3]));
    __syncthreads();

    float lsum = 0.f;
    for (int c = tid; c < NN; c += 256) {
        float v = expf(A[(size_t)row * NN + c] - rmax);
        A[(size_t)row * NN + c] = v;
        lsum += v;
    }
#pragma unroll
    for (int o = 32; o > 0; o >>= 1) lsum += __shfl_down(lsum, o, 64);
    if ((tid & 63) == 0) red[4 + (tid >> 6)] = lsum;
    __syncthreads();
    const float inv = 1.f / (red[4] + red[5] + red[6] + red[7]);
    for (int c = tid; c < NN; c += 256) A[(size_t)row * NN + c] *= inv;
}

// ---------------- A_f32 -> A_bf [2048][2048] with zero pad ----------------
__global__ __launch_bounds__(256) void convert_A(const float* __restrict__ Af,
                                                 ushort_t* __restrict__ Ab) {
    size_t idx = (size_t)blockIdx.x * 256 + threadIdx.x;
    int r = (int)(idx >> 11), c = (int)(idx & 2047);
    float v = (r < NN && c < NN) ? Af[(size_t)r * NN + c] : 0.f;
    Ab[idx] = f2bf(v);
}

// ---------------- Ax[b,t,n] = sum_m A[n,m] x[b,t,m]  (f32, one-time) ----------------
// v4: grid (32,16), 2 batches x 24 t = 48 cols/block; LDS 29.7 KB -> ~2x occupancy.
// Same per-output summation order as v1..v3 (bit-identical Ax).
__global__ __launch_bounds__(256) void ax2_kernel(const float* __restrict__ A,
                                                  const float* __restrict__ x,
                                                  float* __restrict__ Ax) {
    __shared__ float As[64][66];  // [mm][r]
    __shared__ float xs[64][50];  // [mm][col], col = bl*24 + t, 48 used
    const int n0 = blockIdx.x * 64;
    const int b0 = blockIdx.y * 2;
    const int tid = threadIdx.x;
    const int tr = tid >> 4, tc = tid & 15;
    float acc[4][3] = {};

    for (int m0 = 0; m0 < NN; m0 += 64) {
#pragma unroll
        for (int l = 0; l < 16; ++l) {
            int idx = tid + l * 256;
            int mm = idx & 63, r = idx >> 6;
            int n = n0 + r, m = m0 + mm;
            As[mm][r] = (n < NN && m < NN) ? A[(size_t)n * NN + m] : 0.f;
        }
#pragma unroll
        for (int l = 0; l < 12; ++l) {
            int idx = tid + l * 256;
            int mm = idx & 63, col = idx >> 6;
            int m = m0 + mm;
            int bl = col / 24, t = col - bl * 24;
            xs[mm][col] = (m < NN) ? x[((size_t)(b0 + bl) * TT + t) * NN + m] : 0.f;
        }
        __syncthreads();
#pragma unroll 4
        for (int mm = 0; mm < 64; ++mm) {
            float2 a01 = *(const float2*)&As[mm][tr * 4];
            float2 a23 = *(const float2*)&As[mm][tr * 4 + 2];
            float xv[3];
            xv[0] = xs[mm][tc * 3];
            xv[1] = xs[mm][tc * 3 + 1];
            xv[2] = xs[mm][tc * 3 + 2];
            float av[4] = {a01.x, a01.y, a23.x, a23.y};
#pragma unroll
            for (int i = 0; i < 4; ++i)
#pragma unroll
                for (int j = 0; j < 3; ++j) acc[i][j] += av[i] * xv[j];
        }
        __syncthreads();
    }
#pragma unroll
    for (int i = 0; i < 4; ++i) {
        const int n = n0 + tr * 4 + i;
        if (n < NN) {
#pragma unroll
            for (int j = 0; j < 3; ++j) {
                int col = tc * 3 + j;
                int bl = col / 24, t = col - bl * 24;
                Ax[((size_t)(b0 + bl) * TT + t) * NN + n] = acc[i][j];
            }
        }
    }
}

// ================== device bodies (shared by standalone + merged kernels) ==================

// MFMA GEMM body: Y[n][j] = sum_m A[n][m] * H[m][j]; BK=64, 24 KB smem.
__device__ __forceinline__ void gemm_body(int bx, int by,
                                          const ushort_t* __restrict__ Ab,
                                          const ushort_t* __restrict__ H,
                                          ushort_t* __restrict__ Y, char* smem) {
    ushort_t* As = (ushort_t*)smem;            // 8 KB
    ushort_t* Bs = (ushort_t*)(smem + 8192);   // 16 KB (two 8 KB halves)
    const int tid = threadIdx.x;
    const int w = tid >> 6, l = tid & 63, lr = l & 15, lg = l >> 4;
    const int n0 = bx * 64, j0 = by * 128;
    f32x4 acc[4][2] = {};

    const unsigned bs0 = lds_off(Bs);
    const unsigned btr_b[2] = {
        bs0 + 2u * ((unsigned)(w * 2 + 0) * 512 + (unsigned)lg * 128 + (unsigned)lr),
        bs0 + 2u * ((unsigned)(w * 2 + 1) * 512 + (unsigned)lg * 128 + (unsigned)lr)};

    for (int ks = 0; ks < NP / 64; ++ks) {
        const int k0 = ks * 64;
#pragma unroll
        for (int p = 0; p < 2; ++p) {  // A: 64x64, XOR-swizzled
            const int idx = p * 256 + tid;
            const int row = idx >> 3, sl = idx & 7;
            glld16(Ab + (size_t)(n0 + row) * NP + k0 + ((sl ^ (row & 7)) << 3),
                   (ushort_t*)((char*)As + idx * 16));
        }
#pragma unroll
        for (int p = 0; p < 4; ++p) {  // B: two 32-row halves in tr-read subtile order
            const int idx = p * 256 + tid;
            const int g = idx >> 9, li = idx & 511;
            const int row = k0 + g * 32 + ((li >> 3) & 7) * 4 + ((li >> 1) & 3);
            const int col = j0 + (li >> 6) * 16 + (li & 1) * 8;
            glld16(H + (size_t)row * BC + col,
                   (ushort_t*)((char*)Bs + g * 8192 + li * 16));
        }
        __syncthreads();

        bf16x8 av[2][4];
#pragma unroll
        for (int kk = 0; kk < 2; ++kk)
#pragma unroll
            for (int m = 0; m < 4; ++m) {
                const int rr = m * 16 + lr;
                av[kk][m] = *(const bf16x8*)&As[rr * 64 + (((kk * 4 + lg) ^ (rr & 7)) << 3)];
            }
        unsigned long long bq[2][2][2];  // [kk][nt][half]
        asm volatile(
            "ds_read_b64_tr_b16 %0, %8 offset:0\n\t"
            "ds_read_b64_tr_b16 %1, %8 offset:128\n\t"
            "ds_read_b64_tr_b16 %2, %9 offset:0\n\t"
            "ds_read_b64_tr_b16 %3, %9 offset:128\n\t"
            "ds_read_b64_tr_b16 %4, %8 offset:8192\n\t"
            "ds_read_b64_tr_b16 %5, %8 offset:8320\n\t"
            "ds_read_b64_tr_b16 %6, %9 offset:8192\n\t"
            "ds_read_b64_tr_b16 %7, %9 offset:8320"
            : "=v"(bq[0][0][0]), "=v"(bq[0][0][1]), "=v"(bq[0][1][0]), "=v"(bq[0][1][1]),
              "=v"(bq[1][0][0]), "=v"(bq[1][0][1]), "=v"(bq[1][1][0]), "=v"(bq[1][1][1])
            : "v"(btr_b[0]), "v"(btr_b[1]));
        asm volatile("s_waitcnt lgkmcnt(0)" ::: "memory");
        __builtin_amdgcn_sched_barrier(0);
        bf16x8 bv[2][2];
#pragma unroll
        for (int kk = 0; kk < 2; ++kk)
#pragma unroll
            for (int nt = 0; nt < 2; ++nt) {
                union { unsigned long long q[2]; bf16x8 f; } u;
                u.q[0] = bq[kk][nt][0];
                u.q[1] = bq[kk][nt][1];
                bv[kk][nt] = u.f;
            }

#pragma unroll
        for (int kk = 0; kk < 2; ++kk)
#pragma unroll
            for (int m = 0; m < 4; ++m)
#pragma unroll
                for (int nt = 0; nt < 2; ++nt)
                    acc[m][nt] = __builtin_amdgcn_mfma_f32_16x16x32_bf16(av[kk][m], bv[kk][nt], acc[m][nt], 0, 0, 0);
        __syncthreads();
    }

#pragma unroll
    for (int m = 0; m < 4; ++m)
#pragma unroll
        for (int r = 0; r < 4; ++r) {
            const int n = n0 + m * 16 + lg * 4 + r;
            if (n < NN) {
#pragma unroll
                for (int nt = 0; nt < 2; ++nt)
                    Y[(size_t)n * BC + j0 + w * 32 + nt * 16 + lr] = f2bf(acc[m][nt][r]);
            }
        }
}

// factored-MFMA NAPL body (LDS-staged + av-hoist over d). smem = NSEGS*8 KB.
template <int NSEGS, int CO, bool GATE, bool HASX>
__device__ __forceinline__ void napl_body(
    int bid, char* smem,
    const ushort_t* __restrict__ Bt, const float* __restrict__ bp,
    const float* __restrict__ emb, const float* __restrict__ WxPool,
    const ushort_t* __restrict__ s0p, const ushort_t* __restrict__ s1p,
    const ushort_t* __restrict__ s2p, const ushort_t* __restrict__ s3p,
    const float* __restrict__ xv, const float* __restrict__ axv,
    const float* hf, float* __restrict__ zf,
    ushort_t* __restrict__ outb, float* outf, int t) {
    constexpr int K = NSEGS * 64;
    constexpr int NT = (CO == 128) ? 2 : 1;
    constexpr int NHALF = NSEGS / 2;
    ushort_t* As = (ushort_t*)smem;
    const int tid = threadIdx.x;
    const int w = tid >> 6, l = tid & 63, lr = l & 15, lg = l >> 4;
    const int n0 = bid * 2;
    const int ob = w * (16 * NT);
    const ushort_t* segs[4] = {s0p, s1p, s2p, s3p};

#pragma unroll
    for (int s = 0; s < NSEGS; ++s) {
        const ushort_t* sp = segs[s];
#pragma unroll
        for (int p = 0; p < 2; ++p) {
            const int idx = p * 256 + tid;
            const int row = idx >> 3, c16 = idx & 7;
            glld16(sp + (size_t)(n0 + (row >> 5)) * BC + (row & 31) * 64 +
                       ((c16 ^ (row & 7)) << 3),
                   (ushort_t*)((char*)As + s * 8192 + idx * 16));
        }
    }
    __syncthreads();

    f32x4 OUT[4][NT] = {};
#pragma unroll 1
    for (int hf2 = 0; hf2 < NHALF; ++hf2) {
        bf16x8 av[4][4];  // [c][m], c = s_local*2 + h2
#pragma unroll
        for (int c = 0; c < 4; ++c) {
            const int s = hf2 * 2 + (c >> 1);
            const int kin = (c & 1) * 32 + lg * 8;
#pragma unroll
            for (int m = 0; m < 4; ++m) {
                const int rr = m * 16 + lr;
                av[c][m] = *(const bf16x8*)&As[s * 4096 + rr * 64 + (kin ^ ((rr & 7) << 3))];
            }
        }
#pragma unroll 1
        for (int d = 0; d < DD; ++d) {
            const ushort_t* btd = Bt + (size_t)d * CO * K;
            const float ea = emb[n0 * DD + d];
            const float eb = emb[(n0 + 1) * DD + d];
            f32x4 P[4][NT] = {};
#pragma unroll
            for (int c = 0; c < 4; ++c) {
                const int kg = (hf2 * 2 + (c >> 1)) * 64 + (c & 1) * 32 + lg * 8;
                bf16x8 bv[NT];
#pragma unroll
                for (int nt = 0; nt < NT; ++nt)
                    bv[nt] = *(const bf16x8*)&btd[(size_t)(ob + nt * 16 + lr) * K + kg];
#pragma unroll
                for (int m = 0; m < 4; ++m)
#pragma unroll
                    for (int nt = 0; nt < NT; ++nt)
                        P[m][nt] = __builtin_amdgcn_mfma_f32_16x16x32_bf16(av[c][m], bv[nt], P[m][nt], 0, 0, 0);
            }
#pragma unroll
            for (int m = 0; m < 4; ++m) {
                const float e = (m < 2) ? ea : eb;
#pragma unroll
                for (int nt = 0; nt < NT; ++nt)
#pragma unroll
                    for (int r = 0; r < 4; ++r)
                        OUT[m][nt][r] += e * P[m][nt][r];
            }
        }
    }

    float bias[2][NT];
#pragma unroll
    for (int nd = 0; nd < 2; ++nd)
#pragma unroll
        for (int nt = 0; nt < NT; ++nt) {
            float s_ = 0.f;
#pragma unroll
            for (int d = 0; d < DD; ++d)
                s_ += emb[(n0 + nd) * DD + d] * bp[d * CO + ob + nt * 16 + lr];
            bias[nd][nt] = s_;
        }
    float wx[2][2][NT] = {};
    if (HASX) {
#pragma unroll
        for (int kk = 0; kk < 2; ++kk)
#pragma unroll
            for (int nd = 0; nd < 2; ++nd)
#pragma unroll
                for (int nt = 0; nt < NT; ++nt) {
                    float s_ = 0.f;
#pragma unroll
                    for (int d = 0; d < DD; ++d)
                        s_ += emb[(n0 + nd) * DD + d] *
                              WxPool[(size_t)(d * 2 + kk) * 65 * CO + ob + nt * 16 + lr];
                    wx[kk][nd][nt] = s_;
                }
    }

#pragma unroll
    for (int m = 0; m < 4; ++m) {
        const int nd = m >> 1;
        const int n = n0 + nd;
#pragma unroll
        for (int r = 0; r < 4; ++r) {
            const int row = m * 16 + lg * 4 + r;
            const int b = row & 31;
            const size_t nb = (size_t)n * BC + b * 64;
            float xt = 0.f, axt = 0.f;
            if (HASX) {
                xt = xv[((size_t)b * TT + t) * NN + n];
                axt = axv[((size_t)b * TT + t) * NN + n];
            }
#pragma unroll
            for (int nt = 0; nt < NT; ++nt) {
                const int o = ob + nt * 16 + lr;
                float val = OUT[m][nt][r] + bias[nd][nt];
                if (HASX) val += xt * wx[0][nd][nt] + axt * wx[1][nd][nt];
                if (GATE) {
                    const float sg = sigmoidf_(val);
                    if (ob < 64) {
                        zf[nb + o] = sg;
                    } else {
                        outb[nb + (o - 64)] = f2bf(sg * hf[nb + (o - 64)]);
                    }
                } else {
                    const float hc = tanhf(val);
                    const float z = zf[nb + o];
                    const float hn = z * hf[nb + o] + (1.f - z) * hc;
                    outf[nb + o] = hn;
                    outb[nb + o] = f2bf(hn);
                }
            }
        }
    }
}

// ================== kernels ==================

__global__ __launch_bounds__(256) void gemm_trb(const ushort_t* __restrict__ Ab,
                                                const ushort_t* __restrict__ H0,
                                                ushort_t* __restrict__ Y0,
                                                const ushort_t* __restrict__ H1,
                                                ushort_t* __restrict__ Y1) {
    __shared__ __align__(16) char smem[24576];
    gemm_body(blockIdx.x, blockIdx.y, Ab,
              (blockIdx.z == 0) ? H0 : H1, (blockIdx.z == 0) ? Y0 : Y1, smem);
}

template <int NSEGS, int CO, bool GATE, bool HASX>
__global__ __launch_bounds__(256) void napl2(
    const ushort_t* __restrict__ Bt, const float* __restrict__ bp,
    const float* __restrict__ emb, const float* __restrict__ WxPool,
    const ushort_t* __restrict__ s0p, const ushort_t* __restrict__ s1p,
    const ushort_t* __restrict__ s2p, const ushort_t* __restrict__ s3p,
    const float* __restrict__ xv, const float* __restrict__ axv,
    const float* hf, float* __restrict__ zf,
    ushort_t* __restrict__ outb, float* outf, int t) {
    __shared__ __align__(16) char smem[NSEGS * 8192];
    napl_body<NSEGS, CO, GATE, HASX>(blockIdx.x, smem, Bt, bp, emb, WxPool,
                                     s0p, s1p, s2p, s3p, xv, axv, hf, zf, outb, outf, t);
}

// mergeA: blocks [0,512) = gemm (A@Hg -> Yg); blocks [512,1512) = layer0 GATE (t+1)
__global__ __launch_bounds__(256) void mergeA_k(
    const ushort_t* __restrict__ Abf, const ushort_t* __restrict__ Hg,
    ushort_t* __restrict__ Yg,
    const ushort_t* __restrict__ Bt, const float* __restrict__ bp,
    const float* __restrict__ emb, const float* __restrict__ Wx,
    const ushort_t* __restrict__ s0, const ushort_t* __restrict__ s1,
    const float* __restrict__ xv, const float* __restrict__ axv,
    const float* hf, float* __restrict__ zf, ushort_t* __restrict__ outb, int t) {
    __shared__ __align__(16) char smem[24576];
    const int g = blockIdx.x;
    if (g < 512)
        gemm_body(g & 31, g >> 5, Abf, Hg, Yg, smem);
    else
        napl_body<2, 128, true, true>(g - 512, smem, Bt, bp, emb, Wx,
                                      s0, s1, s0, s0, xv, axv, hf, zf, outb, nullptr, t);
}

// mergeB: blocks [0,512) = gemm (A@Hg -> Yg); blocks [512,1512) = layer1 CAND (t)
__global__ __launch_bounds__(256) void mergeB_k(
    const ushort_t* __restrict__ Abf, const ushort_t* __restrict__ Hg,
    ushort_t* __restrict__ Yg,
    const ushort_t* __restrict__ Bt, const float* __restrict__ bp,
    const float* __restrict__ emb,
    const ushort_t* __restrict__ s0, const ushort_t* __restrict__ s1,
    const ushort_t* __restrict__ s2, const ushort_t* __restrict__ s3,
    const float* hf, float* __restrict__ zf,
    ushort_t* __restrict__ outb, float* outf, int t) {
    __shared__ __align__(16) char smem[32768];
    const int g = blockIdx.x;
    if (g < 512)
        gemm_body(g & 31, g >> 5, Abf, Hg, Yg, smem);
    else
        napl_body<4, 64, false, false>(g - 512, smem, Bt, bp, emb, nullptr,
                                       s0, s1, s2, s3, nullptr, nullptr, hf, zf, outb, outf, t);
}

// mergeC: blocks [0,512) = gemm (A@Hg -> Yg); blocks [512,1512) = layer0 CAND (t+1)
__global__ __launch_bounds__(256) void mergeC_k(
    const ushort_t* __restrict__ Abf, const ushort_t* __restrict__ Hg,
    ushort_t* __restrict__ Yg,
    const ushort_t* __restrict__ Bt, const float* __restrict__ bp,
    const float* __restrict__ emb, const float* __restrict__ Wx,
    const ushort_t* __restrict__ s0, const ushort_t* __restrict__ s1,
    const float* __restrict__ xv, const float* __restrict__ axv,
    const float* hf, float* __restrict__ zf,
    ushort_t* __restrict__ outb, float* outf, int t) {
    __shared__ __align__(16) char smem[24576];
    const int g = blockIdx.x;
    if (g < 512)
        gemm_body(g & 31, g >> 5, Abf, Hg, Yg, smem);
    else
        napl_body<2, 64, false, true>(g - 512, smem, Bt, bp, emb, Wx,
                                      s0, s1, s0, s0, xv, axv, hf, zf, outb, outf, t);
}

// ---------------- prep: Bt[d][o][K] bf16 from pool (B^T form for MFMA) ----------------
template <int CI, int CO, bool L0>
__global__ __launch_bounds__(256) void prepW(const float* __restrict__ Wp,
                                             ushort_t* __restrict__ Bt) {
    constexpr int K = L0 ? 128 : 256;
    const int idx = blockIdx.x * 256 + threadIdx.x;
    if (idx >= DD * CO * K) return;
    const int d = idx / (CO * K);
    const int rem = idx - d * CO * K;
    const int o = rem / K;
    const int k = rem - o * K;
    const int s = k >> 6, c = k & 63;
    const int kk = L0 ? s : (s & 1);
    const int i = L0 ? (1 + c) : ((s >> 1) * 64 + c);
    Bt[idx] = f2bf(Wp[((size_t)(d * 2 + kk) * CI + i) * CO + o]);
}

// ---------------- head ----------------
__global__ __launch_bounds__(256) void head_kernel(const float* __restrict__ h1,
                                                   const float* __restrict__ hw,
                                                   const float* __restrict__ hb,
                                                   float* __restrict__ y) {
    __shared__ float wl[T_OUT * HH];
    const int tid = threadIdx.x;
    for (int idx = tid; idx < T_OUT * HH; idx += 256) wl[idx] = hw[idx];
    __syncthreads();
    const int gi = blockIdx.x * 256 + tid;
    if (gi >= BB * NN) return;
    const int b = gi / NN, n = gi % NN;
    float acc[T_OUT];
#pragma unroll
    for (int ot = 0; ot < T_OUT; ++ot) acc[ot] = hb[ot];
    for (int h = 0; h < HH; ++h) {
        float v = h1[(size_t)n * BC + b * 64 + h];
#pragma unroll
        for (int ot = 0; ot < T_OUT; ++ot) acc[ot] += v * wl[ot * HH + h];
    }
#pragma unroll
    for (int ot = 0; ot < T_OUT; ++ot)
        y[((size_t)b * T_OUT + ot) * NN + n] = acc[ot];
}

extern "C" void kernel_launch(void* const* d_in, const int* in_sizes, int n_in,
                              void* d_out, int out_size, void* d_ws, size_t ws_size,
                              hipStream_t stream) {
    const float* x = (const float*)d_in[0];
    const float* node_emb = (const float*)d_in[1];
    const float* adapt_emb = (const float*)d_in[2];
    const float* Wg0 = (const float*)d_in[3];
    const float* bg0 = (const float*)d_in[4];
    const float* Wc0 = (const float*)d_in[5];
    const float* bc0 = (const float*)d_in[6];
    const float* Wg1 = (const float*)d_in[7];
    const float* bg1 = (const float*)d_in[8];
    const float* Wc1 = (const float*)d_in[9];
    const float* bc1 = (const float*)d_in[10];
    const float* head_w = (const float*)d_in[11];
    const float* head_b = (const float*)d_in[12];
    float* y = (float*)d_out;

    char* ws = (char*)d_ws;
    ushort_t* Abf  = (ushort_t*)(ws + ABF_OFF);
    float* h0f = (float*)(ws + H0F_OFF);
    float* h1f = (float*)(ws + H1F_OFF);
    float* zf  = (float*)(ws + ZF_OFF);
    ushort_t* h0b = (ushort_t*)(ws + H0B_OFF);
    ushort_t* h1b = (ushort_t*)(ws + H1B_OFF);
    ushort_t* rhb = (ushort_t*)(ws + RHB_OFF);
    ushort_t* Ah0 = (ushort_t*)(ws + AH0_OFF);
    ushort_t* AhX = (ushort_t*)(ws + AHX_OFF);
    float* Axf = (float*)(ws + AXF_OFF);
    ushort_t* Btg0 = (ushort_t*)(ws + BTG0_OFF);
    ushort_t* Btc0 = (ushort_t*)(ws + BTC0_OFF);
    ushort_t* Btg1 = (ushort_t*)(ws + BTG1_OFF);
    ushort_t* Btc1 = (ushort_t*)(ws + BTC1_OFF);
    float* Af32 = zf;  // overlay: consumed before first gate writes z

    const bool pipe = (ws_size >= TOP_PIPE);

    hipMemsetAsync(h0f, 0, SZ_ST4, stream);
    hipMemsetAsync(h1f, 0, SZ_ST4, stream);
    hipMemsetAsync(h0b, 0, SZ_NPB2, stream);
    hipMemsetAsync(h1b, 0, SZ_NPB2, stream);
    hipMemsetAsync(rhb, 0, SZ_NPB2, stream);
    hipMemsetAsync(Ah0, 0, SZ_NPB2, stream);
    hipMemsetAsync(AhX, 0, SZ_NPB2, stream);

    compute_A_kernel<<<NN, 256, 0, stream>>>(adapt_emb, Af32);
    ax2_kernel<<<dim3(32, 16), 256, 0, stream>>>(Af32, x, Axf);
    convert_A<<<(NP * NP) / 256, 256, 0, stream>>>(Af32, Abf);
    prepW<65, 128, true><<<(DD * 128 * 128 + 255) / 256, 256, 0, stream>>>(Wg0, Btg0);
    prepW<65, 64, true><<<(DD * 64 * 128 + 255) / 256, 256, 0, stream>>>(Wc0, Btc0);
    prepW<128, 128, false><<<(DD * 128 * 256 + 255) / 256, 256, 0, stream>>>(Wg1, Btg1);
    prepW<128, 64, false><<<(DD * 64 * 256 + 255) / 256, 256, 0, stream>>>(Wc1, Btc1);

    const dim3 gG1(NP / 64, NP / 128, 1);  // 512 blocks
    const dim3 gG2(NP / 64, NP / 128, 2);  // fused dual GEMM
    const int gN = NN * BB / 64;           // 1000 blocks

    if (pipe) {
        float* zf0 = zf;
        ushort_t* rhb0 = rhb;
        float* zf1 = (float*)(ws + ZF1_OFF);
        ushort_t* rhb1 = (ushort_t*)(ws + RHB1_OFF);
        ushort_t* AhY = (ushort_t*)(ws + AHY_OFF);
        hipMemsetAsync(rhb1, 0, SZ_NPB2, stream);

        // prologue t=0: G0, R0, C0, G2(dual), G1
        napl2<2, 128, true, true><<<gN, 256, 0, stream>>>(
            Btg0, bg0, node_emb, Wg0, h0b, Ah0, h0b, h0b, x, Axf, h0f, zf0, rhb0, nullptr, 0);
        gemm_trb<<<gG1, 256, 0, stream>>>(Abf, rhb0, AhY, rhb0, AhY);
        napl2<2, 64, false, true><<<gN, 256, 0, stream>>>(
            Btc0, bc0, node_emb, Wc0, rhb0, AhY, rhb0, rhb0, x, Axf, h0f, zf0, h0b, h0f, 0);
        gemm_trb<<<gG2, 256, 0, stream>>>(Abf, h0b, Ah0, h1b, AhX);
        napl2<4, 128, true, false><<<gN, 256, 0, stream>>>(
            Btg1, bg1, node_emb, nullptr, h0b, Ah0, h1b, AhX, nullptr, nullptr, h1f, zf1, rhb1, nullptr, 0);

        for (int t = 0; t < TT - 1; ++t) {
            // M_A: R1(t): AhX <- A@rhb1  ||  gate0(t+1): zf0, rhb0
            mergeA_k<<<1512, 256, 0, stream>>>(Abf, rhb1, AhX,
                Btg0, bg0, node_emb, Wg0, h0b, Ah0, x, Axf, h0f, zf0, rhb0, t + 1);
            // M_B: cand1(t): h1f,h1b  ||  R0(t+1): AhY <- A@rhb0
            mergeB_k<<<1512, 256, 0, stream>>>(Abf, rhb0, AhY,
                Btc1, bc1, node_emb, h0b, Ah0, rhb1, AhX, h1f, zf1, h1b, h1f, t);
            // M_C: cand0(t+1): h0f,h0b  ||  AhX <- A@h1b (h1b from M_B)
            mergeC_k<<<1512, 256, 0, stream>>>(Abf, h1b, AhX,
                Btc0, bc0, node_emb, Wc0, rhb0, AhY, x, Axf, h0f, zf0, h0b, h0f, t + 1);
            // G2b: Ah0 <- A@h0b
            gemm_trb<<<gG1, 256, 0, stream>>>(Abf, h0b, Ah0, h0b, Ah0);
            // G1(t+1): reads h0b, Ah0, h1b, AhX
            napl2<4, 128, true, false><<<gN, 256, 0, stream>>>(
                Btg1, bg1, node_emb, nullptr, h0b, Ah0, h1b, AhX, nullptr, nullptr, h1f, zf1, rhb1, nullptr, t + 1);
        }
        // epilogue t=TT-1: R1, C1
        gemm_trb<<<gG1, 256, 0, stream>>>(Abf, rhb1, AhX, rhb1, AhX);
        napl2<4, 64, false, false><<<gN, 256, 0, stream>>>(
            Btc1, bc1, node_emb, nullptr, h0b, Ah0, rhb1, AhX, nullptr, nullptr, h1f, zf1, h1b, h1f, TT - 1);
    } else {
        // fallback: round-11 proven schedule (single zf/rhb/AhX)
        for (int t = 0; t < TT; ++t) {
            napl2<2, 128, true, true><<<gN, 256, 0, stream>>>(
                Btg0, bg0, node_emb, Wg0, h0b, Ah0, h0b, h0b, x, Axf, h0f, zf, rhb, nullptr, t);
            gemm_trb<<<gG1, 256, 0, stream>>>(Abf, rhb, AhX, rhb, AhX);
            napl2<2, 64, false, true><<<gN, 256, 0, stream>>>(
                Btc0, bc0, node_emb, Wc0, rhb, AhX, rhb, rhb, x, Axf, h0f, zf, h0b, h0f, t);
            gemm_trb<<<gG2, 256, 0, stream>>>(Abf, h0b, Ah0, h1b, AhX);
            napl2<4, 128, true, false><<<gN, 256, 0, stream>>>(
                Btg1, bg1, node_emb, nullptr, h0b, Ah0, h1b, AhX, nullptr, nullptr, h1f, zf, rhb, nullptr, t);
            gemm_trb<<<gG1, 256, 0, stream>>>(Abf, rhb, AhX, rhb, AhX);
            napl2<4, 64, false, false><<<gN, 256, 0, stream>>>(
                Btc1, bc1, node_emb, nullptr, h0b, Ah0, rhb, AhX, nullptr, nullptr, h1f, zf, h1b, h1f, t);
        }
    }

    head_kernel<<<(BB * NN + 255) / 256, 256, 0, stream>>>(h1f, head_w, head_b, y);
}

// Round 14
// 8600.661 us; speedup vs baseline: 1.3241x; 1.0082x over previous
//
#include <hip/hip_runtime.h>
#include <math.h>

#define NN 2000
#define BB 32
#define TT 24
#define T_OUT 12
#define HH 64
#define DD 10
#define NP 2048   // padded node dim
#define BC 2048   // B*H columns (j = b*64 + c)

typedef unsigned short ushort_t;
typedef __bf16 bf16x8 __attribute__((ext_vector_type(8)));
typedef float f32x4 __attribute__((ext_vector_type(4)));

__device__ __forceinline__ float sigmoidf_(float x) { return 1.f / (1.f + expf(-x)); }

__device__ __forceinline__ ushort_t f2bf(float f) {
    unsigned int u = __float_as_uint(f);
    unsigned int r = (u + 0x7FFFu + ((u >> 16) & 1u)) >> 16;
    return (ushort_t)r;
}
__device__ __forceinline__ float bf2f(ushort_t s) {
    return __uint_as_float(((unsigned int)s) << 16);
}

__device__ __forceinline__ void glld16(const ushort_t* g, ushort_t* lds) {
    __builtin_amdgcn_global_load_lds(
        (const __attribute__((address_space(1))) char*)g,
        (__attribute__((address_space(3))) char*)lds, 16, 0, 0);
}

__device__ __forceinline__ unsigned lds_off(const void* p) {
    return (unsigned)(size_t)(__attribute__((address_space(3))) const char*)p;
}

// ---------------- workspace layout (bytes) ----------------
constexpr size_t SZ_NPNP2 = (size_t)NP * NP * 2;   // 8,388,608
constexpr size_t SZ_ST4   = (size_t)NN * BC * 4;   // 16,384,000
constexpr size_t SZ_NPB2  = (size_t)NP * BC * 2;   // 8,388,608 (padded bf16 state)

constexpr size_t ABF_OFF  = 0;
constexpr size_t H0F_OFF  = ABF_OFF + SZ_NPNP2;
constexpr size_t H1F_OFF  = H0F_OFF + SZ_ST4;
constexpr size_t ZF_OFF   = H1F_OFF + SZ_ST4;       // f32; overlaid with A_f32 in setup
constexpr size_t H0B_OFF  = ZF_OFF + SZ_ST4;
constexpr size_t H1B_OFF  = H0B_OFF + SZ_NPB2;
constexpr size_t RHB_OFF  = H1B_OFF + SZ_NPB2;
constexpr size_t AH0_OFF  = RHB_OFF + SZ_NPB2;
constexpr size_t AHX_OFF  = AH0_OFF + SZ_NPB2;
constexpr size_t AXF_OFF  = AHX_OFF + SZ_NPB2;      // [B][T][N] f32
constexpr size_t BTG0_OFF = AXF_OFF + (size_t)BB * TT * NN * 4;
constexpr size_t BTC0_OFF = BTG0_OFF + (size_t)DD * 128 * 128 * 2;  // 327,680
constexpr size_t BTG1_OFF = BTC0_OFF + (size_t)DD * 64 * 128 * 2;   // 163,840
constexpr size_t BTC1_OFF = BTG1_OFF + (size_t)DD * 128 * 256 * 2;  // 655,360
constexpr size_t WS_TOP   = BTC1_OFF + (size_t)DD * 64 * 256 * 2;   // 107,102,208
// pipelined-path extension (r12/r13)
constexpr size_t ZF1_OFF  = WS_TOP;                      // f32 16,384,000
constexpr size_t RHB1_OFF = ZF1_OFF + SZ_ST4;            // bf16 8,388,608
constexpr size_t AHY_OFF  = RHB1_OFF + SZ_NPB2;          // bf16 8,388,608
constexpr size_t TOP_PIPE = AHY_OFF + SZ_NPB2;           // 140,263,424
// pipe2 extension: parity copy of h0b
constexpr size_t H0B2_OFF = TOP_PIPE;                    // bf16 8,388,608
constexpr size_t TOP_PIPE2 = H0B2_OFF + SZ_NPB2;         // 148,652,032

// ---------------- A_f32 = row_softmax(relu(E E^T)) ----------------
__global__ __launch_bounds__(256) void compute_A_kernel(const float* __restrict__ E,
                                                        float* __restrict__ A) {
    const int row = blockIdx.x;
    const int tid = threadIdx.x;
    float er[DD];
#pragma unroll
    for (int d = 0; d < DD; ++d) er[d] = E[row * DD + d];
    __shared__ float red[8];

    float lmax = -1e30f;
    for (int c = tid; c < NN; c += 256) {
        float s = 0.f;
#pragma unroll
        for (int d = 0; d < DD; ++d) s += er[d] * E[c * DD + d];
        s = fmaxf(s, 0.f);
        A[(size_t)row * NN + c] = s;
        lmax = fmaxf(lmax, s);
    }
#pragma unroll
    for (int o = 32; o > 0; o >>= 1) lmax = fmaxf(lmax, __shfl_down(lmax, o, 64));
    if ((tid & 63) == 0) red[tid >> 6] = lmax;
    __syncthreads();
    const float rmax = fmaxf(fmaxf(red[0], red[1]), fmaxf(red[2], red[3]));
    __syncthreads();

    float lsum = 0.f;
    for (int c = tid; c < NN; c += 256) {
        float v = expf(A[(size_t)row * NN + c] - rmax);
        A[(size_t)row * NN + c] = v;
        lsum += v;
    }
#pragma unroll
    for (int o = 32; o > 0; o >>= 1) lsum += __shfl_down(lsum, o, 64);
    if ((tid & 63) == 0) red[4 + (tid >> 6)] = lsum;
    __syncthreads();
    const float inv = 1.f / (red[4] + red[5] + red[6] + red[7]);
    for (int c = tid; c < NN; c += 256) A[(size_t)row * NN + c] *= inv;
}

// ---------------- A_f32 -> A_bf [2048][2048] with zero pad ----------------
__global__ __launch_bounds__(256) void convert_A(const float* __restrict__ Af,
                                                 ushort_t* __restrict__ Ab) {
    size_t idx = (size_t)blockIdx.x * 256 + threadIdx.x;
    int r = (int)(idx >> 11), c = (int)(idx & 2047);
    float v = (r < NN && c < NN) ? Af[(size_t)r * NN + c] : 0.f;
    Ab[idx] = f2bf(v);
}

// ---------------- Ax[b,t,n] = sum_m A[n,m] x[b,t,m]  (f32, one-time) ----------------
__global__ __launch_bounds__(256) void ax2_kernel(const float* __restrict__ A,
                                                  const float* __restrict__ x,
                                                  float* __restrict__ Ax) {
    __shared__ float As[64][66];  // [mm][r]
    __shared__ float xs[64][50];  // [mm][col], col = bl*24 + t, 48 used
    const int n0 = blockIdx.x * 64;
    const int b0 = blockIdx.y * 2;
    const int tid = threadIdx.x;
    const int tr = tid >> 4, tc = tid & 15;
    float acc[4][3] = {};

    for (int m0 = 0; m0 < NN; m0 += 64) {
#pragma unroll
        for (int l = 0; l < 16; ++l) {
            int idx = tid + l * 256;
            int mm = idx & 63, r = idx >> 6;
            int n = n0 + r, m = m0 + mm;
            As[mm][r] = (n < NN && m < NN) ? A[(size_t)n * NN + m] : 0.f;
        }
#pragma unroll
        for (int l = 0; l < 12; ++l) {
            int idx = tid + l * 256;
            int mm = idx & 63, col = idx >> 6;
            int m = m0 + mm;
            int bl = col / 24, t = col - bl * 24;
            xs[mm][col] = (m < NN) ? x[((size_t)(b0 + bl) * TT + t) * NN + m] : 0.f;
        }
        __syncthreads();
#pragma unroll 4
        for (int mm = 0; mm < 64; ++mm) {
            float2 a01 = *(const float2*)&As[mm][tr * 4];
            float2 a23 = *(const float2*)&As[mm][tr * 4 + 2];
            float xv[3];
            xv[0] = xs[mm][tc * 3];
            xv[1] = xs[mm][tc * 3 + 1];
            xv[2] = xs[mm][tc * 3 + 2];
            float av[4] = {a01.x, a01.y, a23.x, a23.y};
#pragma unroll
            for (int i = 0; i < 4; ++i)
#pragma unroll
                for (int j = 0; j < 3; ++j) acc[i][j] += av[i] * xv[j];
        }
        __syncthreads();
    }
#pragma unroll
    for (int i = 0; i < 4; ++i) {
        const int n = n0 + tr * 4 + i;
        if (n < NN) {
#pragma unroll
            for (int j = 0; j < 3; ++j) {
                int col = tc * 3 + j;
                int bl = col / 24, t = col - bl * 24;
                Ax[((size_t)(b0 + bl) * TT + t) * NN + n] = acc[i][j];
            }
        }
    }
}

// ================== device bodies ==================

// MFMA GEMM body: Y[n][j] = sum_m A[n][m] * H[m][j]; BK=64, 24 KB smem.
__device__ __forceinline__ void gemm_body(int bx, int by,
                                          const ushort_t* __restrict__ Ab,
                                          const ushort_t* __restrict__ H,
                                          ushort_t* __restrict__ Y, char* smem) {
    ushort_t* As = (ushort_t*)smem;            // 8 KB
    ushort_t* Bs = (ushort_t*)(smem + 8192);   // 16 KB (two 8 KB halves)
    const int tid = threadIdx.x;
    const int w = tid >> 6, l = tid & 63, lr = l & 15, lg = l >> 4;
    const int n0 = bx * 64, j0 = by * 128;
    f32x4 acc[4][2] = {};

    const unsigned bs0 = lds_off(Bs);
    const unsigned btr_b[2] = {
        bs0 + 2u * ((unsigned)(w * 2 + 0) * 512 + (unsigned)lg * 128 + (unsigned)lr),
        bs0 + 2u * ((unsigned)(w * 2 + 1) * 512 + (unsigned)lg * 128 + (unsigned)lr)};

    for (int ks = 0; ks < NP / 64; ++ks) {
        const int k0 = ks * 64;
#pragma unroll
        for (int p = 0; p < 2; ++p) {  // A: 64x64, XOR-swizzled
            const int idx = p * 256 + tid;
            const int row = idx >> 3, sl = idx & 7;
            glld16(Ab + (size_t)(n0 + row) * NP + k0 + ((sl ^ (row & 7)) << 3),
                   (ushort_t*)((char*)As + idx * 16));
        }
#pragma unroll
        for (int p = 0; p < 4; ++p) {  // B: two 32-row halves in tr-read subtile order
            const int idx = p * 256 + tid;
            const int g = idx >> 9, li = idx & 511;
            const int row = k0 + g * 32 + ((li >> 3) & 7) * 4 + ((li >> 1) & 3);
            const int col = j0 + (li >> 6) * 16 + (li & 1) * 8;
            glld16(H + (size_t)row * BC + col,
                   (ushort_t*)((char*)Bs + g * 8192 + li * 16));
        }
        __syncthreads();

        bf16x8 av[2][4];
#pragma unroll
        for (int kk = 0; kk < 2; ++kk)
#pragma unroll
            for (int m = 0; m < 4; ++m) {
                const int rr = m * 16 + lr;
                av[kk][m] = *(const bf16x8*)&As[rr * 64 + (((kk * 4 + lg) ^ (rr & 7)) << 3)];
            }
        unsigned long long bq[2][2][2];  // [kk][nt][half]
        asm volatile(
            "ds_read_b64_tr_b16 %0, %8 offset:0\n\t"
            "ds_read_b64_tr_b16 %1, %8 offset:128\n\t"
            "ds_read_b64_tr_b16 %2, %9 offset:0\n\t"
            "ds_read_b64_tr_b16 %3, %9 offset:128\n\t"
            "ds_read_b64_tr_b16 %4, %8 offset:8192\n\t"
            "ds_read_b64_tr_b16 %5, %8 offset:8320\n\t"
            "ds_read_b64_tr_b16 %6, %9 offset:8192\n\t"
            "ds_read_b64_tr_b16 %7, %9 offset:8320"
            : "=v"(bq[0][0][0]), "=v"(bq[0][0][1]), "=v"(bq[0][1][0]), "=v"(bq[0][1][1]),
              "=v"(bq[1][0][0]), "=v"(bq[1][0][1]), "=v"(bq[1][1][0]), "=v"(bq[1][1][1])
            : "v"(btr_b[0]), "v"(btr_b[1]));
        asm volatile("s_waitcnt lgkmcnt(0)" ::: "memory");
        __builtin_amdgcn_sched_barrier(0);
        bf16x8 bv[2][2];
#pragma unroll
        for (int kk = 0; kk < 2; ++kk)
#pragma unroll
            for (int nt = 0; nt < 2; ++nt) {
                union { unsigned long long q[2]; bf16x8 f; } u;
                u.q[0] = bq[kk][nt][0];
                u.q[1] = bq[kk][nt][1];
                bv[kk][nt] = u.f;
            }

#pragma unroll
        for (int kk = 0; kk < 2; ++kk)
#pragma unroll
            for (int m = 0; m < 4; ++m)
#pragma unroll
                for (int nt = 0; nt < 2; ++nt)
                    acc[m][nt] = __builtin_amdgcn_mfma_f32_16x16x32_bf16(av[kk][m], bv[kk][nt], acc[m][nt], 0, 0, 0);
        __syncthreads();
    }

#pragma unroll
    for (int m = 0; m < 4; ++m)
#pragma unroll
        for (int r = 0; r < 4; ++r) {
            const int n = n0 + m * 16 + lg * 4 + r;
            if (n < NN) {
#pragma unroll
                for (int nt = 0; nt < 2; ++nt)
                    Y[(size_t)n * BC + j0 + w * 32 + nt * 16 + lr] = f2bf(acc[m][nt][r]);
            }
        }
}

// factored-MFMA NAPL body (LDS-staged + av-hoist over d). smem = NSEGS*8 KB.
template <int NSEGS, int CO, bool GATE, bool HASX>
__device__ __forceinline__ void napl_body(
    int bid, char* smem,
    const ushort_t* __restrict__ Bt, const float* __restrict__ bp,
    const float* __restrict__ emb, const float* __restrict__ WxPool,
    const ushort_t* __restrict__ s0p, const ushort_t* __restrict__ s1p,
    const ushort_t* __restrict__ s2p, const ushort_t* __restrict__ s3p,
    const float* __restrict__ xv, const float* __restrict__ axv,
    const float* hf, float* __restrict__ zf,
    ushort_t* __restrict__ outb, float* outf, int t) {
    constexpr int K = NSEGS * 64;
    constexpr int NT = (CO == 128) ? 2 : 1;
    constexpr int NHALF = NSEGS / 2;
    ushort_t* As = (ushort_t*)smem;
    const int tid = threadIdx.x;
    const int w = tid >> 6, l = tid & 63, lr = l & 15, lg = l >> 4;
    const int n0 = bid * 2;
    const int ob = w * (16 * NT);
    const ushort_t* segs[4] = {s0p, s1p, s2p, s3p};

#pragma unroll
    for (int s = 0; s < NSEGS; ++s) {
        const ushort_t* sp = segs[s];
#pragma unroll
        for (int p = 0; p < 2; ++p) {
            const int idx = p * 256 + tid;
            const int row = idx >> 3, c16 = idx & 7;
            glld16(sp + (size_t)(n0 + (row >> 5)) * BC + (row & 31) * 64 +
                       ((c16 ^ (row & 7)) << 3),
                   (ushort_t*)((char*)As + s * 8192 + idx * 16));
        }
    }
    __syncthreads();

    f32x4 OUT[4][NT] = {};
#pragma unroll 1
    for (int hf2 = 0; hf2 < NHALF; ++hf2) {
        bf16x8 av[4][4];  // [c][m], c = s_local*2 + h2
#pragma unroll
        for (int c = 0; c < 4; ++c) {
            const int s = hf2 * 2 + (c >> 1);
            const int kin = (c & 1) * 32 + lg * 8;
#pragma unroll
            for (int m = 0; m < 4; ++m) {
                const int rr = m * 16 + lr;
                av[c][m] = *(const bf16x8*)&As[s * 4096 + rr * 64 + (kin ^ ((rr & 7) << 3))];
            }
        }
#pragma unroll 1
        for (int d = 0; d < DD; ++d) {
            const ushort_t* btd = Bt + (size_t)d * CO * K;
            const float ea = emb[n0 * DD + d];
            const float eb = emb[(n0 + 1) * DD + d];
            f32x4 P[4][NT] = {};
#pragma unroll
            for (int c = 0; c < 4; ++c) {
                const int kg = (hf2 * 2 + (c >> 1)) * 64 + (c & 1) * 32 + lg * 8;
                bf16x8 bv[NT];
#pragma unroll
                for (int nt = 0; nt < NT; ++nt)
                    bv[nt] = *(const bf16x8*)&btd[(size_t)(ob + nt * 16 + lr) * K + kg];
#pragma unroll
                for (int m = 0; m < 4; ++m)
#pragma unroll
                    for (int nt = 0; nt < NT; ++nt)
                        P[m][nt] = __builtin_amdgcn_mfma_f32_16x16x32_bf16(av[c][m], bv[nt], P[m][nt], 0, 0, 0);
            }
#pragma unroll
            for (int m = 0; m < 4; ++m) {
                const float e = (m < 2) ? ea : eb;
#pragma unroll
                for (int nt = 0; nt < NT; ++nt)
#pragma unroll
                    for (int r = 0; r < 4; ++r)
                        OUT[m][nt][r] += e * P[m][nt][r];
            }
        }
    }

    float bias[2][NT];
#pragma unroll
    for (int nd = 0; nd < 2; ++nd)
#pragma unroll
        for (int nt = 0; nt < NT; ++nt) {
            float s_ = 0.f;
#pragma unroll
            for (int d = 0; d < DD; ++d)
                s_ += emb[(n0 + nd) * DD + d] * bp[d * CO + ob + nt * 16 + lr];
            bias[nd][nt] = s_;
        }
    float wx[2][2][NT] = {};
    if (HASX) {
#pragma unroll
        for (int kk = 0; kk < 2; ++kk)
#pragma unroll
            for (int nd = 0; nd < 2; ++nd)
#pragma unroll
                for (int nt = 0; nt < NT; ++nt) {
                    float s_ = 0.f;
#pragma unroll
                    for (int d = 0; d < DD; ++d)
                        s_ += emb[(n0 + nd) * DD + d] *
                              WxPool[(size_t)(d * 2 + kk) * 65 * CO + ob + nt * 16 + lr];
                    wx[kk][nd][nt] = s_;
                }
    }

#pragma unroll
    for (int m = 0; m < 4; ++m) {
        const int nd = m >> 1;
        const int n = n0 + nd;
#pragma unroll
        for (int r = 0; r < 4; ++r) {
            const int row = m * 16 + lg * 4 + r;
            const int b = row & 31;
            const size_t nb = (size_t)n * BC + b * 64;
            float xt = 0.f, axt = 0.f;
            if (HASX) {
                xt = xv[((size_t)b * TT + t) * NN + n];
                axt = axv[((size_t)b * TT + t) * NN + n];
            }
#pragma unroll
            for (int nt = 0; nt < NT; ++nt) {
                const int o = ob + nt * 16 + lr;
                float val = OUT[m][nt][r] + bias[nd][nt];
                if (HASX) val += xt * wx[0][nd][nt] + axt * wx[1][nd][nt];
                if (GATE) {
                    const float sg = sigmoidf_(val);
                    if (ob < 64) {
                        zf[nb + o] = sg;
                    } else {
                        outb[nb + (o - 64)] = f2bf(sg * hf[nb + (o - 64)]);
                    }
                } else {
                    const float hc = tanhf(val);
                    const float z = zf[nb + o];
                    const float hn = z * hf[nb + o] + (1.f - z) * hc;
                    outf[nb + o] = hn;
                    outb[nb + o] = f2bf(hn);
                }
            }
        }
    }
}

// ================== kernels ==================

__global__ __launch_bounds__(256) void gemm_trb(const ushort_t* __restrict__ Ab,
                                                const ushort_t* __restrict__ H0,
                                                ushort_t* __restrict__ Y0,
                                                const ushort_t* __restrict__ H1,
                                                ushort_t* __restrict__ Y1) {
    __shared__ __align__(16) char smem[24576];
    gemm_body(blockIdx.x, blockIdx.y, Ab,
              (blockIdx.z == 0) ? H0 : H1, (blockIdx.z == 0) ? Y0 : Y1, smem);
}

template <int NSEGS, int CO, bool GATE, bool HASX>
__global__ __launch_bounds__(256) void napl2(
    const ushort_t* __restrict__ Bt, const float* __restrict__ bp,
    const float* __restrict__ emb, const float* __restrict__ WxPool,
    const ushort_t* __restrict__ s0p, const ushort_t* __restrict__ s1p,
    const ushort_t* __restrict__ s2p, const ushort_t* __restrict__ s3p,
    const float* __restrict__ xv, const float* __restrict__ axv,
    const float* hf, float* __restrict__ zf,
    ushort_t* __restrict__ outb, float* outf, int t) {
    __shared__ __align__(16) char smem[NSEGS * 8192];
    napl_body<NSEGS, CO, GATE, HASX>(blockIdx.x, smem, Bt, bp, emb, WxPool,
                                     s0p, s1p, s2p, s3p, xv, axv, hf, zf, outb, outf, t);
}

// ---- r13-path merged kernels ----
__global__ __launch_bounds__(256) void mergeA_k(
    const ushort_t* __restrict__ Abf, const ushort_t* __restrict__ Hg,
    ushort_t* __restrict__ Yg,
    const ushort_t* __restrict__ Bt, const float* __restrict__ bp,
    const float* __restrict__ emb, const float* __restrict__ Wx,
    const ushort_t* __restrict__ s0, const ushort_t* __restrict__ s1,
    const float* __restrict__ xv, const float* __restrict__ axv,
    const float* hf, float* __restrict__ zf, ushort_t* __restrict__ outb, int t) {
    __shared__ __align__(16) char smem[24576];
    const int g = blockIdx.x;
    if (g < 512)
        gemm_body(g & 31, g >> 5, Abf, Hg, Yg, smem);
    else
        napl_body<2, 128, true, true>(g - 512, smem, Bt, bp, emb, Wx,
                                      s0, s1, s0, s0, xv, axv, hf, zf, outb, nullptr, t);
}

__global__ __launch_bounds__(256) void mergeB_k(
    const ushort_t* __restrict__ Abf, const ushort_t* __restrict__ Hg,
    ushort_t* __restrict__ Yg,
    const ushort_t* __restrict__ Bt, const float* __restrict__ bp,
    const float* __restrict__ emb,
    const ushort_t* __restrict__ s0, const ushort_t* __restrict__ s1,
    const ushort_t* __restrict__ s2, const ushort_t* __restrict__ s3,
    const float* hf, float* __restrict__ zf,
    ushort_t* __restrict__ outb, float* outf, int t) {
    __shared__ __align__(16) char smem[32768];
    const int g = blockIdx.x;
    if (g < 512)
        gemm_body(g & 31, g >> 5, Abf, Hg, Yg, smem);
    else
        napl_body<4, 64, false, false>(g - 512, smem, Bt, bp, emb, nullptr,
                                       s0, s1, s2, s3, nullptr, nullptr, hf, zf, outb, outf, t);
}

__global__ __launch_bounds__(256) void mergeC_k(
    const ushort_t* __restrict__ Abf, const ushort_t* __restrict__ Hg,
    ushort_t* __restrict__ Yg,
    const ushort_t* __restrict__ Bt, const float* __restrict__ bp,
    const float* __restrict__ emb, const float* __restrict__ Wx,
    const ushort_t* __restrict__ s0, const ushort_t* __restrict__ s1,
    const float* __restrict__ xv, const float* __restrict__ axv,
    const float* hf, float* __restrict__ zf,
    ushort_t* __restrict__ outb, float* outf, int t) {
    __shared__ __align__(16) char smem[24576];
    const int g = blockIdx.x;
    if (g < 512)
        gemm_body(g & 31, g >> 5, Abf, Hg, Yg, smem);
    else
        napl_body<2, 64, false, true>(g - 512, smem, Bt, bp, emb, Wx,
                                      s0, s1, s0, s0, xv, axv, hf, zf, outb, outf, t);
}

// ---- pipe2 merged kernels ----
// mergeG: blocks [0,1000) = layer1 GATE (t); [1000,2000) = layer0 GATE (t+1)
__global__ __launch_bounds__(256) void mergeG_k(
    const ushort_t* __restrict__ Btg1, const float* __restrict__ bg1,
    const ushort_t* __restrict__ Btg0, const float* __restrict__ bg0,
    const float* __restrict__ emb, const float* __restrict__ Wg0,
    const ushort_t* __restrict__ hbt, const ushort_t* __restrict__ Ah0,
    const ushort_t* __restrict__ h1b, const ushort_t* __restrict__ AhX,
    const float* __restrict__ xv, const float* __restrict__ axv,
    const float* h0f, const float* h1f,
    float* __restrict__ zf0, float* __restrict__ zf1,
    ushort_t* __restrict__ rhb0, ushort_t* __restrict__ rhb1, int t) {
    __shared__ __align__(16) char smem[32768];
    const int g = blockIdx.x;
    if (g < 1000)
        napl_body<4, 128, true, false>(g, smem, Btg1, bg1, emb, nullptr,
                                       hbt, Ah0, h1b, AhX, nullptr, nullptr,
                                       h1f, zf1, rhb1, nullptr, t);
    else
        napl_body<2, 128, true, true>(g - 1000, smem, Btg0, bg0, emb, Wg0,
                                      hbt, Ah0, hbt, hbt, xv, axv,
                                      h0f, zf0, rhb0, nullptr, t + 1);
}

// mergeCC: blocks [0,1000) = layer1 CAND (t); [1000,2000) = layer0 CAND (t+1)
__global__ __launch_bounds__(256) void mergeCC_k(
    const ushort_t* __restrict__ Btc1, const float* __restrict__ bc1,
    const ushort_t* __restrict__ Btc0, const float* __restrict__ bc0,
    const float* __restrict__ emb, const float* __restrict__ Wc0,
    const ushort_t* __restrict__ hbt, ushort_t* __restrict__ hbt1,
    const ushort_t* __restrict__ Ah0, const ushort_t* __restrict__ rhb1,
    const ushort_t* __restrict__ AhX, const ushort_t* __restrict__ AhY,
    const ushort_t* __restrict__ rhb0,
    const float* __restrict__ xv, const float* __restrict__ axv,
    float* h0f, float* h1f,
    float* __restrict__ zf0, float* __restrict__ zf1,
    ushort_t* __restrict__ h1b, int t) {
    __shared__ __align__(16) char smem[32768];
    const int g = blockIdx.x;
    if (g < 1000)
        napl_body<4, 64, false, false>(g, smem, Btc1, bc1, emb, nullptr,
                                       hbt, Ah0, rhb1, AhX, nullptr, nullptr,
                                       h1f, zf1, h1b, h1f, t);
    else
        napl_body<2, 64, false, true>(g - 1000, smem, Btc0, bc0, emb, Wc0,
                                      rhb0, AhY, rhb0, rhb0, xv, axv,
                                      h0f, zf0, hbt1, h0f, t + 1);
}

// ---------------- prep: Bt[d][o][K] bf16 from pool (B^T form for MFMA) ----------------
template <int CI, int CO, bool L0>
__global__ __launch_bounds__(256) void prepW(const float* __restrict__ Wp,
                                             ushort_t* __restrict__ Bt) {
    constexpr int K = L0 ? 128 : 256;
    const int idx = blockIdx.x * 256 + threadIdx.x;
    if (idx >= DD * CO * K) return;
    const int d = idx / (CO * K);
    const int rem = idx - d * CO * K;
    const int o = rem / K;
    const int k = rem - o * K;
    const int s = k >> 6, c = k & 63;
    const int kk = L0 ? s : (s & 1);
    const int i = L0 ? (1 + c) : ((s >> 1) * 64 + c);
    Bt[idx] = f2bf(Wp[((size_t)(d * 2 + kk) * CI + i) * CO + o]);
}

// ---------------- head ----------------
__global__ __launch_bounds__(256) void head_kernel(const float* __restrict__ h1,
                                                   const float* __restrict__ hw,
                                                   const float* __restrict__ hb,
                                                   float* __restrict__ y) {
    __shared__ float wl[T_OUT * HH];
    const int tid = threadIdx.x;
    for (int idx = tid; idx < T_OUT * HH; idx += 256) wl[idx] = hw[idx];
    __syncthreads();
    const int gi = blockIdx.x * 256 + tid;
    if (gi >= BB * NN) return;
    const int b = gi / NN, n = gi % NN;
    float acc[T_OUT];
#pragma unroll
    for (int ot = 0; ot < T_OUT; ++ot) acc[ot] = hb[ot];
    for (int h = 0; h < HH; ++h) {
        float v = h1[(size_t)n * BC + b * 64 + h];
#pragma unroll
        for (int ot = 0; ot < T_OUT; ++ot) acc[ot] += v * wl[ot * HH + h];
    }
#pragma unroll
    for (int ot = 0; ot < T_OUT; ++ot)
        y[((size_t)b * T_OUT + ot) * NN + n] = acc[ot];
}

extern "C" void kernel_launch(void* const* d_in, const int* in_sizes, int n_in,
                              void* d_out, int out_size, void* d_ws, size_t ws_size,
                              hipStream_t stream) {
    const float* x = (const float*)d_in[0];
    const float* node_emb = (const float*)d_in[1];
    const float* adapt_emb = (const float*)d_in[2];
    const float* Wg0 = (const float*)d_in[3];
    const float* bg0 = (const float*)d_in[4];
    const float* Wc0 = (const float*)d_in[5];
    const float* bc0 = (const float*)d_in[6];
    const float* Wg1 = (const float*)d_in[7];
    const float* bg1 = (const float*)d_in[8];
    const float* Wc1 = (const float*)d_in[9];
    const float* bc1 = (const float*)d_in[10];
    const float* head_w = (const float*)d_in[11];
    const float* head_b = (const float*)d_in[12];
    float* y = (float*)d_out;

    char* ws = (char*)d_ws;
    ushort_t* Abf  = (ushort_t*)(ws + ABF_OFF);
    float* h0f = (float*)(ws + H0F_OFF);
    float* h1f = (float*)(ws + H1F_OFF);
    float* zf  = (float*)(ws + ZF_OFF);
    ushort_t* h0b = (ushort_t*)(ws + H0B_OFF);
    ushort_t* h1b = (ushort_t*)(ws + H1B_OFF);
    ushort_t* rhb = (ushort_t*)(ws + RHB_OFF);
    ushort_t* Ah0 = (ushort_t*)(ws + AH0_OFF);
    ushort_t* AhX = (ushort_t*)(ws + AHX_OFF);
    float* Axf = (float*)(ws + AXF_OFF);
    ushort_t* Btg0 = (ushort_t*)(ws + BTG0_OFF);
    ushort_t* Btc0 = (ushort_t*)(ws + BTC0_OFF);
    ushort_t* Btg1 = (ushort_t*)(ws + BTG1_OFF);
    ushort_t* Btc1 = (ushort_t*)(ws + BTC1_OFF);
    float* Af32 = zf;  // overlay: consumed before first gate writes z

    const bool pipe2 = (ws_size >= TOP_PIPE2);
    const bool pipe = (ws_size >= TOP_PIPE);

    hipMemsetAsync(h0f, 0, SZ_ST4, stream);
    hipMemsetAsync(h1f, 0, SZ_ST4, stream);
    hipMemsetAsync(h0b, 0, SZ_NPB2, stream);
    hipMemsetAsync(h1b, 0, SZ_NPB2, stream);
    hipMemsetAsync(rhb, 0, SZ_NPB2, stream);
    hipMemsetAsync(Ah0, 0, SZ_NPB2, stream);
    hipMemsetAsync(AhX, 0, SZ_NPB2, stream);

    compute_A_kernel<<<NN, 256, 0, stream>>>(adapt_emb, Af32);
    ax2_kernel<<<dim3(32, 16), 256, 0, stream>>>(Af32, x, Axf);
    convert_A<<<(NP * NP) / 256, 256, 0, stream>>>(Af32, Abf);
    prepW<65, 128, true><<<(DD * 128 * 128 + 255) / 256, 256, 0, stream>>>(Wg0, Btg0);
    prepW<65, 64, true><<<(DD * 64 * 128 + 255) / 256, 256, 0, stream>>>(Wc0, Btc0);
    prepW<128, 128, false><<<(DD * 128 * 256 + 255) / 256, 256, 0, stream>>>(Wg1, Btg1);
    prepW<128, 64, false><<<(DD * 64 * 256 + 255) / 256, 256, 0, stream>>>(Wc1, Btc1);

    const dim3 gG1(NP / 64, NP / 128, 1);  // 512 blocks
    const dim3 gG2(NP / 64, NP / 128, 2);  // dual GEMM: 1024 blocks
    const int gN = NN * BB / 64;           // 1000 blocks

    if (pipe2) {
        float* zf0 = zf;
        ushort_t* rhb0 = rhb;
        float* zf1 = (float*)(ws + ZF1_OFF);
        ushort_t* rhb1 = (ushort_t*)(ws + RHB1_OFF);
        ushort_t* AhY = (ushort_t*)(ws + AHY_OFF);
        ushort_t* h0b2 = (ushort_t*)(ws + H0B2_OFF);
        hipMemsetAsync(rhb1, 0, SZ_NPB2, stream);
        hipMemsetAsync(h0b2, 0, SZ_NPB2, stream);
        ushort_t* hb[2] = {h0b, h0b2};  // C0(t) writes hb[t&1]

        // prologue: G0(0), R0(0), C0(0) -> hb[0], G2(0) -> Ah0
        napl2<2, 128, true, true><<<gN, 256, 0, stream>>>(
            Btg0, bg0, node_emb, Wg0, h0b, Ah0, h0b, h0b, x, Axf, h0f, zf0, rhb0, nullptr, 0);
        gemm_trb<<<gG1, 256, 0, stream>>>(Abf, rhb0, AhY, rhb0, AhY);
        napl2<2, 64, false, true><<<gN, 256, 0, stream>>>(
            Btc0, bc0, node_emb, Wc0, rhb0, AhY, rhb0, rhb0, x, Axf, h0f, zf0, hb[0], h0f, 0);
        gemm_trb<<<gG1, 256, 0, stream>>>(Abf, hb[0], Ah0, hb[0], Ah0);

        for (int t = 0; t < TT - 1; ++t) {
            ushort_t* hbt = hb[t & 1];
            ushort_t* hbt1 = hb[(t + 1) & 1];
            // D1: G1(t) || G0(t+1)
            mergeG_k<<<2000, 256, 0, stream>>>(Btg1, bg1, Btg0, bg0, node_emb, Wg0,
                hbt, Ah0, h1b, AhX, x, Axf, h0f, h1f, zf0, zf1, rhb0, rhb1, t);
            // D2: R1(t): AhX <- A@rhb1 || R0(t+1): AhY <- A@rhb0
            gemm_trb<<<gG2, 256, 0, stream>>>(Abf, rhb1, AhX, rhb0, AhY);
            // D3: C1(t) -> h1f,h1b || C0(t+1) -> h0f,hbt1
            mergeCC_k<<<2000, 256, 0, stream>>>(Btc1, bc1, Btc0, bc0, node_emb, Wc0,
                hbt, hbt1, Ah0, rhb1, AhX, AhY, rhb0, x, Axf, h0f, h1f, zf0, zf1, h1b, t);
            // D4: AhX <- A@h1b || Ah0 <- A@hbt1
            gemm_trb<<<gG2, 256, 0, stream>>>(Abf, h1b, AhX, hbt1, Ah0);
        }
        // epilogue t=TT-1
        {
            ushort_t* hbT = hb[(TT - 1) & 1];
            napl2<4, 128, true, false><<<gN, 256, 0, stream>>>(
                Btg1, bg1, node_emb, nullptr, hbT, Ah0, h1b, AhX, nullptr, nullptr, h1f, zf1, rhb1, nullptr, TT - 1);
            gemm_trb<<<gG1, 256, 0, stream>>>(Abf, rhb1, AhX, rhb1, AhX);
            napl2<4, 64, false, false><<<gN, 256, 0, stream>>>(
                Btc1, bc1, node_emb, nullptr, hbT, Ah0, rhb1, AhX, nullptr, nullptr, h1f, zf1, h1b, h1f, TT - 1);
        }
    } else if (pipe) {
        float* zf0 = zf;
        ushort_t* rhb0 = rhb;
        float* zf1 = (float*)(ws + ZF1_OFF);
        ushort_t* rhb1 = (ushort_t*)(ws + RHB1_OFF);
        ushort_t* AhY = (ushort_t*)(ws + AHY_OFF);
        hipMemsetAsync(rhb1, 0, SZ_NPB2, stream);

        napl2<2, 128, true, true><<<gN, 256, 0, stream>>>(
            Btg0, bg0, node_emb, Wg0, h0b, Ah0, h0b, h0b, x, Axf, h0f, zf0, rhb0, nullptr, 0);
        gemm_trb<<<gG1, 256, 0, stream>>>(Abf, rhb0, AhY, rhb0, AhY);
        napl2<2, 64, false, true><<<gN, 256, 0, stream>>>(
            Btc0, bc0, node_emb, Wc0, rhb0, AhY, rhb0, rhb0, x, Axf, h0f, zf0, h0b, h0f, 0);
        gemm_trb<<<gG2, 256, 0, stream>>>(Abf, h0b, Ah0, h1b, AhX);
        napl2<4, 128, true, false><<<gN, 256, 0, stream>>>(
            Btg1, bg1, node_emb, nullptr, h0b, Ah0, h1b, AhX, nullptr, nullptr, h1f, zf1, rhb1, nullptr, 0);

        for (int t = 0; t < TT - 1; ++t) {
            mergeA_k<<<1512, 256, 0, stream>>>(Abf, rhb1, AhX,
                Btg0, bg0, node_emb, Wg0, h0b, Ah0, x, Axf, h0f, zf0, rhb0, t + 1);
            mergeB_k<<<1512, 256, 0, stream>>>(Abf, rhb0, AhY,
                Btc1, bc1, node_emb, h0b, Ah0, rhb1, AhX, h1f, zf1, h1b, h1f, t);
            mergeC_k<<<1512, 256, 0, stream>>>(Abf, h1b, AhX,
                Btc0, bc0, node_emb, Wc0, rhb0, AhY, x, Axf, h0f, zf0, h0b, h0f, t + 1);
            gemm_trb<<<gG1, 256, 0, stream>>>(Abf, h0b, Ah0, h0b, Ah0);
            napl2<4, 128, true, false><<<gN, 256, 0, stream>>>(
                Btg1, bg1, node_emb, nullptr, h0b, Ah0, h1b, AhX, nullptr, nullptr, h1f, zf1, rhb1, nullptr, t + 1);
        }
        gemm_trb<<<gG1, 256, 0, stream>>>(Abf, rhb1, AhX, rhb1, AhX);
        napl2<4, 64, false, false><<<gN, 256, 0, stream>>>(
            Btc1, bc1, node_emb, nullptr, h0b, Ah0, rhb1, AhX, nullptr, nullptr, h1f, zf1, h1b, h1f, TT - 1);
    } else {
        for (int t = 0; t < TT; ++t) {
            napl2<2, 128, true, true><<<gN, 256, 0, stream>>>(
                Btg0, bg0, node_emb, Wg0, h0b, Ah0, h0b, h0b, x, Axf, h0f, zf, rhb, nullptr, t);
            gemm_trb<<<gG1, 256, 0, stream>>>(Abf, rhb, AhX, rhb, AhX);
            napl2<2, 64, false, true><<<gN, 256, 0, stream>>>(
                Btc0, bc0, node_emb, Wc0, rhb, AhX, rhb, rhb, x, Axf, h0f, zf, h0b, h0f, t);
            gemm_trb<<<gG2, 256, 0, stream>>>(Abf, h0b, Ah0, h1b, AhX);
            napl2<4, 128, true, false><<<gN, 256, 0, stream>>>(
                Btg1, bg1, node_emb, nullptr, h0b, Ah0, h1b, AhX, nullptr, nullptr, h1f, zf, rhb, nullptr, t);
            gemm_trb<<<gG1, 256, 0, stream>>>(Abf, rhb, AhX, rhb, AhX);
            napl2<4, 64, false, false><<<gN, 256, 0, stream>>>(
                Btc1, bc1, node_emb, nullptr, h0b, Ah0, rhb, AhX, nullptr, nullptr, h1f, zf, h1b, h1f, t);
        }
    }

    head_kernel<<<(BB * NN + 255) / 256, 256, 0, stream>>>(h1f, head_w, head_b, y);
}

// Round 15
// 8222.559 us; speedup vs baseline: 1.3850x; 1.0460x over previous
//
#include <hip/hip_runtime.h>
#include <math.h>

#define NN 2000
#define BB 32
#define TT 24
#define T_OUT 12
#define HH 64
#define DD 10
#define NP 2048   // padded node dim
#define BC 2048   // B*H columns (j = b*64 + c)

typedef unsigned short ushort_t;
typedef __bf16 bf16x8 __attribute__((ext_vector_type(8)));
typedef float f32x4 __attribute__((ext_vector_type(4)));

__device__ __forceinline__ float sigmoidf_(float x) { return 1.f / (1.f + expf(-x)); }

__device__ __forceinline__ ushort_t f2bf(float f) {
    unsigned int u = __float_as_uint(f);
    unsigned int r = (u + 0x7FFFu + ((u >> 16) & 1u)) >> 16;
    return (ushort_t)r;
}
__device__ __forceinline__ float bf2f(ushort_t s) {
    return __uint_as_float(((unsigned int)s) << 16);
}

__device__ __forceinline__ void glld16(const ushort_t* g, ushort_t* lds) {
    __builtin_amdgcn_global_load_lds(
        (const __attribute__((address_space(1))) char*)g,
        (__attribute__((address_space(3))) char*)lds, 16, 0, 0);
}

__device__ __forceinline__ unsigned lds_off(const void* p) {
    return (unsigned)(size_t)(__attribute__((address_space(3))) const char*)p;
}

// ---------------- workspace layout (bytes) ----------------
constexpr size_t SZ_NPNP2 = (size_t)NP * NP * 2;   // 8,388,608
constexpr size_t SZ_ST4   = (size_t)NN * BC * 4;   // 16,384,000
constexpr size_t SZ_NPB2  = (size_t)NP * BC * 2;   // 8,388,608 (padded bf16 state)

constexpr size_t ABF_OFF  = 0;
constexpr size_t H0F_OFF  = ABF_OFF + SZ_NPNP2;
constexpr size_t H1F_OFF  = H0F_OFF + SZ_ST4;
constexpr size_t ZF_OFF   = H1F_OFF + SZ_ST4;       // f32; overlaid with A_f32 in setup
constexpr size_t H0B_OFF  = ZF_OFF + SZ_ST4;
constexpr size_t H1B_OFF  = H0B_OFF + SZ_NPB2;
constexpr size_t RHB_OFF  = H1B_OFF + SZ_NPB2;
constexpr size_t AH0_OFF  = RHB_OFF + SZ_NPB2;
constexpr size_t AHX_OFF  = AH0_OFF + SZ_NPB2;
constexpr size_t AXF_OFF  = AHX_OFF + SZ_NPB2;      // [B][T][N] f32
constexpr size_t BTG0_OFF = AXF_OFF + (size_t)BB * TT * NN * 4;
constexpr size_t BTC0_OFF = BTG0_OFF + (size_t)DD * 128 * 128 * 2;  // 327,680
constexpr size_t BTG1_OFF = BTC0_OFF + (size_t)DD * 64 * 128 * 2;   // 163,840
constexpr size_t BTC1_OFF = BTG1_OFF + (size_t)DD * 128 * 256 * 2;  // 655,360
constexpr size_t WS_TOP   = BTC1_OFF + (size_t)DD * 64 * 256 * 2;   // 107,102,208
// pipelined-path extension (r12/r13)
constexpr size_t ZF1_OFF  = WS_TOP;                      // f32 16,384,000
constexpr size_t RHB1_OFF = ZF1_OFF + SZ_ST4;            // bf16 8,388,608
constexpr size_t AHY_OFF  = RHB1_OFF + SZ_NPB2;          // bf16 8,388,608
constexpr size_t TOP_PIPE = AHY_OFF + SZ_NPB2;           // 140,263,424
// pipe2 extension: parity copy of h0b
constexpr size_t H0B2_OFF = TOP_PIPE;                    // bf16 8,388,608
constexpr size_t TOP_PIPE2 = H0B2_OFF + SZ_NPB2;         // 148,652,032

// ---------------- A_f32 = row_softmax(relu(E E^T)) ----------------
__global__ __launch_bounds__(256) void compute_A_kernel(const float* __restrict__ E,
                                                        float* __restrict__ A) {
    const int row = blockIdx.x;
    const int tid = threadIdx.x;
    float er[DD];
#pragma unroll
    for (int d = 0; d < DD; ++d) er[d] = E[row * DD + d];
    __shared__ float red[8];

    float lmax = -1e30f;
    for (int c = tid; c < NN; c += 256) {
        float s = 0.f;
#pragma unroll
        for (int d = 0; d < DD; ++d) s += er[d] * E[c * DD + d];
        s = fmaxf(s, 0.f);
        A[(size_t)row * NN + c] = s;
        lmax = fmaxf(lmax, s);
    }
#pragma unroll
    for (int o = 32; o > 0; o >>= 1) lmax = fmaxf(lmax, __shfl_down(lmax, o, 64));
    if ((tid & 63) == 0) red[tid >> 6] = lmax;
    __syncthreads();
    const float rmax = fmaxf(fmaxf(red[0], red[1]), fmaxf(red[2], red[3]));
    __syncthreads();

    float lsum = 0.f;
    for (int c = tid; c < NN; c += 256) {
        float v = expf(A[(size_t)row * NN + c] - rmax);
        A[(size_t)row * NN + c] = v;
        lsum += v;
    }
#pragma unroll
    for (int o = 32; o > 0; o >>= 1) lsum += __shfl_down(lsum, o, 64);
    if ((tid & 63) == 0) red[4 + (tid >> 6)] = lsum;
    __syncthreads();
    const float inv = 1.f / (red[4] + red[5] + red[6] + red[7]);
    for (int c = tid; c < NN; c += 256) A[(size_t)row * NN + c] *= inv;
}

// ---------------- A_f32 -> A_bf [2048][2048] with zero pad ----------------
__global__ __launch_bounds__(256) void convert_A(const float* __restrict__ Af,
                                                 ushort_t* __restrict__ Ab) {
    size_t idx = (size_t)blockIdx.x * 256 + threadIdx.x;
    int r = (int)(idx >> 11), c = (int)(idx & 2047);
    float v = (r < NN && c < NN) ? Af[(size_t)r * NN + c] : 0.f;
    Ab[idx] = f2bf(v);
}

// ---------------- Ax[b,t,n] = sum_m A[n,m] x[b,t,m]  (f32, one-time) ----------------
__global__ __launch_bounds__(256) void ax2_kernel(const float* __restrict__ A,
                                                  const float* __restrict__ x,
                                                  float* __restrict__ Ax) {
    __shared__ float As[64][66];  // [mm][r]
    __shared__ float xs[64][50];  // [mm][col], col = bl*24 + t, 48 used
    const int n0 = blockIdx.x * 64;
    const int b0 = blockIdx.y * 2;
    const int tid = threadIdx.x;
    const int tr = tid >> 4, tc = tid & 15;
    float acc[4][3] = {};

    for (int m0 = 0; m0 < NN; m0 += 64) {
#pragma unroll
        for (int l = 0; l < 16; ++l) {
            int idx = tid + l * 256;
            int mm = idx & 63, r = idx >> 6;
            int n = n0 + r, m = m0 + mm;
            As[mm][r] = (n < NN && m < NN) ? A[(size_t)n * NN + m] : 0.f;
        }
#pragma unroll
        for (int l = 0; l < 12; ++l) {
            int idx = tid + l * 256;
            int mm = idx & 63, col = idx >> 6;
            int m = m0 + mm;
            int bl = col / 24, t = col - bl * 24;
            xs[mm][col] = (m < NN) ? x[((size_t)(b0 + bl) * TT + t) * NN + m] : 0.f;
        }
        __syncthreads();
#pragma unroll 4
        for (int mm = 0; mm < 64; ++mm) {
            float2 a01 = *(const float2*)&As[mm][tr * 4];
            float2 a23 = *(const float2*)&As[mm][tr * 4 + 2];
            float xv[3];
            xv[0] = xs[mm][tc * 3];
            xv[1] = xs[mm][tc * 3 + 1];
            xv[2] = xs[mm][tc * 3 + 2];
            float av[4] = {a01.x, a01.y, a23.x, a23.y};
#pragma unroll
            for (int i = 0; i < 4; ++i)
#pragma unroll
                for (int j = 0; j < 3; ++j) acc[i][j] += av[i] * xv[j];
        }
        __syncthreads();
    }
#pragma unroll
    for (int i = 0; i < 4; ++i) {
        const int n = n0 + tr * 4 + i;
        if (n < NN) {
#pragma unroll
            for (int j = 0; j < 3; ++j) {
                int col = tc * 3 + j;
                int bl = col / 24, t = col - bl * 24;
                Ax[((size_t)(b0 + bl) * TT + t) * NN + n] = acc[i][j];
            }
        }
    }
}

// ================== device bodies ==================

// MFMA GEMM body v3: 128x128 tile, BK=64, 32 KB smem, 32 MFMA : 8 staging issues
// per barrier-pair. B-side identical tr-read subtile layout; A-side 128 rows.
// Per-output K-order (ks asc, kk asc) identical to 64x128 body -> bit-identical.
__device__ __forceinline__ void gemm_body(int bx, int by,
                                          const ushort_t* __restrict__ Ab,
                                          const ushort_t* __restrict__ H,
                                          ushort_t* __restrict__ Y, char* smem) {
    ushort_t* As = (ushort_t*)smem;             // 16 KB (128 rows x 64 k)
    ushort_t* Bs = (ushort_t*)(smem + 16384);   // 16 KB (two 8 KB halves)
    const int tid = threadIdx.x;
    const int w = tid >> 6, l = tid & 63, lr = l & 15, lg = l >> 4;
    const int n0 = bx * 128, j0 = by * 128;
    f32x4 acc[8][2] = {};

    const unsigned bs0 = lds_off(Bs);
    const unsigned btr_b[2] = {
        bs0 + 2u * ((unsigned)(w * 2 + 0) * 512 + (unsigned)lg * 128 + (unsigned)lr),
        bs0 + 2u * ((unsigned)(w * 2 + 1) * 512 + (unsigned)lg * 128 + (unsigned)lr)};

    for (int ks = 0; ks < NP / 64; ++ks) {
        const int k0 = ks * 64;
#pragma unroll
        for (int p = 0; p < 4; ++p) {  // A: 128x64, XOR-swizzled
            const int idx = p * 256 + tid;
            const int row = idx >> 3, sl = idx & 7;
            glld16(Ab + (size_t)(n0 + row) * NP + k0 + ((sl ^ (row & 7)) << 3),
                   (ushort_t*)((char*)As + idx * 16));
        }
#pragma unroll
        for (int p = 0; p < 4; ++p) {  // B: two 32-row halves in tr-read subtile order
            const int idx = p * 256 + tid;
            const int g = idx >> 9, li = idx & 511;
            const int row = k0 + g * 32 + ((li >> 3) & 7) * 4 + ((li >> 1) & 3);
            const int col = j0 + (li >> 6) * 16 + (li & 1) * 8;
            glld16(H + (size_t)row * BC + col,
                   (ushort_t*)((char*)Bs + g * 8192 + li * 16));
        }
        __syncthreads();

        unsigned long long bq[2][2][2];  // [kk][nt][half]
        asm volatile(
            "ds_read_b64_tr_b16 %0, %8 offset:0\n\t"
            "ds_read_b64_tr_b16 %1, %8 offset:128\n\t"
            "ds_read_b64_tr_b16 %2, %9 offset:0\n\t"
            "ds_read_b64_tr_b16 %3, %9 offset:128\n\t"
            "ds_read_b64_tr_b16 %4, %8 offset:8192\n\t"
            "ds_read_b64_tr_b16 %5, %8 offset:8320\n\t"
            "ds_read_b64_tr_b16 %6, %9 offset:8192\n\t"
            "ds_read_b64_tr_b16 %7, %9 offset:8320"
            : "=v"(bq[0][0][0]), "=v"(bq[0][0][1]), "=v"(bq[0][1][0]), "=v"(bq[0][1][1]),
              "=v"(bq[1][0][0]), "=v"(bq[1][0][1]), "=v"(bq[1][1][0]), "=v"(bq[1][1][1])
            : "v"(btr_b[0]), "v"(btr_b[1]));
        asm volatile("s_waitcnt lgkmcnt(0)" ::: "memory");
        __builtin_amdgcn_sched_barrier(0);
        bf16x8 bv[2][2];
#pragma unroll
        for (int kk = 0; kk < 2; ++kk)
#pragma unroll
            for (int nt = 0; nt < 2; ++nt) {
                union { unsigned long long q[2]; bf16x8 f; } u;
                u.q[0] = bq[kk][nt][0];
                u.q[1] = bq[kk][nt][1];
                bv[kk][nt] = u.f;
            }

#pragma unroll
        for (int kk = 0; kk < 2; ++kk)
#pragma unroll
            for (int m = 0; m < 8; ++m) {
                const int rr = m * 16 + lr;
                const bf16x8 av = *(const bf16x8*)&As[rr * 64 + (((kk * 4 + lg) ^ (rr & 7)) << 3)];
#pragma unroll
                for (int nt = 0; nt < 2; ++nt)
                    acc[m][nt] = __builtin_amdgcn_mfma_f32_16x16x32_bf16(av, bv[kk][nt], acc[m][nt], 0, 0, 0);
            }
        __syncthreads();
    }

#pragma unroll
    for (int m = 0; m < 8; ++m)
#pragma unroll
        for (int r = 0; r < 4; ++r) {
            const int n = n0 + m * 16 + lg * 4 + r;
            if (n < NN) {
#pragma unroll
                for (int nt = 0; nt < 2; ++nt)
                    Y[(size_t)n * BC + j0 + w * 32 + nt * 16 + lr] = f2bf(acc[m][nt][r]);
            }
        }
}

// factored-MFMA NAPL body (LDS-staged + av-hoist over d). smem = NSEGS*8 KB.
template <int NSEGS, int CO, bool GATE, bool HASX>
__device__ __forceinline__ void napl_body(
    int bid, char* smem,
    const ushort_t* __restrict__ Bt, const float* __restrict__ bp,
    const float* __restrict__ emb, const float* __restrict__ WxPool,
    const ushort_t* __restrict__ s0p, const ushort_t* __restrict__ s1p,
    const ushort_t* __restrict__ s2p, const ushort_t* __restrict__ s3p,
    const float* __restrict__ xv, const float* __restrict__ axv,
    const float* hf, float* __restrict__ zf,
    ushort_t* __restrict__ outb, float* outf, int t) {
    constexpr int K = NSEGS * 64;
    constexpr int NT = (CO == 128) ? 2 : 1;
    constexpr int NHALF = NSEGS / 2;
    ushort_t* As = (ushort_t*)smem;
    const int tid = threadIdx.x;
    const int w = tid >> 6, l = tid & 63, lr = l & 15, lg = l >> 4;
    const int n0 = bid * 2;
    const int ob = w * (16 * NT);
    const ushort_t* segs[4] = {s0p, s1p, s2p, s3p};

#pragma unroll
    for (int s = 0; s < NSEGS; ++s) {
        const ushort_t* sp = segs[s];
#pragma unroll
        for (int p = 0; p < 2; ++p) {
            const int idx = p * 256 + tid;
            const int row = idx >> 3, c16 = idx & 7;
            glld16(sp + (size_t)(n0 + (row >> 5)) * BC + (row & 31) * 64 +
                       ((c16 ^ (row & 7)) << 3),
                   (ushort_t*)((char*)As + s * 8192 + idx * 16));
        }
    }
    __syncthreads();

    f32x4 OUT[4][NT] = {};
#pragma unroll 1
    for (int hf2 = 0; hf2 < NHALF; ++hf2) {
        bf16x8 av[4][4];  // [c][m], c = s_local*2 + h2
#pragma unroll
        for (int c = 0; c < 4; ++c) {
            const int s = hf2 * 2 + (c >> 1);
            const int kin = (c & 1) * 32 + lg * 8;
#pragma unroll
            for (int m = 0; m < 4; ++m) {
                const int rr = m * 16 + lr;
                av[c][m] = *(const bf16x8*)&As[s * 4096 + rr * 64 + (kin ^ ((rr & 7) << 3))];
            }
        }
#pragma unroll 1
        for (int d = 0; d < DD; ++d) {
            const ushort_t* btd = Bt + (size_t)d * CO * K;
            const float ea = emb[n0 * DD + d];
            const float eb = emb[(n0 + 1) * DD + d];
            f32x4 P[4][NT] = {};
#pragma unroll
            for (int c = 0; c < 4; ++c) {
                const int kg = (hf2 * 2 + (c >> 1)) * 64 + (c & 1) * 32 + lg * 8;
                bf16x8 bv[NT];
#pragma unroll
                for (int nt = 0; nt < NT; ++nt)
                    bv[nt] = *(const bf16x8*)&btd[(size_t)(ob + nt * 16 + lr) * K + kg];
#pragma unroll
                for (int m = 0; m < 4; ++m)
#pragma unroll
                    for (int nt = 0; nt < NT; ++nt)
                        P[m][nt] = __builtin_amdgcn_mfma_f32_16x16x32_bf16(av[c][m], bv[nt], P[m][nt], 0, 0, 0);
            }
#pragma unroll
            for (int m = 0; m < 4; ++m) {
                const float e = (m < 2) ? ea : eb;
#pragma unroll
                for (int nt = 0; nt < NT; ++nt)
#pragma unroll
                    for (int r = 0; r < 4; ++r)
                        OUT[m][nt][r] += e * P[m][nt][r];
            }
        }
    }

    float bias[2][NT];
#pragma unroll
    for (int nd = 0; nd < 2; ++nd)
#pragma unroll
        for (int nt = 0; nt < NT; ++nt) {
            float s_ = 0.f;
#pragma unroll
            for (int d = 0; d < DD; ++d)
                s_ += emb[(n0 + nd) * DD + d] * bp[d * CO + ob + nt * 16 + lr];
            bias[nd][nt] = s_;
        }
    float wx[2][2][NT] = {};
    if (HASX) {
#pragma unroll
        for (int kk = 0; kk < 2; ++kk)
#pragma unroll
            for (int nd = 0; nd < 2; ++nd)
#pragma unroll
                for (int nt = 0; nt < NT; ++nt) {
                    float s_ = 0.f;
#pragma unroll
                    for (int d = 0; d < DD; ++d)
                        s_ += emb[(n0 + nd) * DD + d] *
                              WxPool[(size_t)(d * 2 + kk) * 65 * CO + ob + nt * 16 + lr];
                    wx[kk][nd][nt] = s_;
                }
    }

#pragma unroll
    for (int m = 0; m < 4; ++m) {
        const int nd = m >> 1;
        const int n = n0 + nd;
#pragma unroll
        for (int r = 0; r < 4; ++r) {
            const int row = m * 16 + lg * 4 + r;
            const int b = row & 31;
            const size_t nb = (size_t)n * BC + b * 64;
            float xt = 0.f, axt = 0.f;
            if (HASX) {
                xt = xv[((size_t)b * TT + t) * NN + n];
                axt = axv[((size_t)b * TT + t) * NN + n];
            }
#pragma unroll
            for (int nt = 0; nt < NT; ++nt) {
                const int o = ob + nt * 16 + lr;
                float val = OUT[m][nt][r] + bias[nd][nt];
                if (HASX) val += xt * wx[0][nd][nt] + axt * wx[1][nd][nt];
                if (GATE) {
                    const float sg = sigmoidf_(val);
                    if (ob < 64) {
                        zf[nb + o] = sg;
                    } else {
                        outb[nb + (o - 64)] = f2bf(sg * hf[nb + (o - 64)]);
                    }
                } else {
                    const float hc = tanhf(val);
                    const float z = zf[nb + o];
                    const float hn = z * hf[nb + o] + (1.f - z) * hc;
                    outf[nb + o] = hn;
                    outb[nb + o] = f2bf(hn);
                }
            }
        }
    }
}

// ================== kernels ==================

__global__ __launch_bounds__(256) void gemm_trb(const ushort_t* __restrict__ Ab,
                                                const ushort_t* __restrict__ H0,
                                                ushort_t* __restrict__ Y0,
                                                const ushort_t* __restrict__ H1,
                                                ushort_t* __restrict__ Y1) {
    __shared__ __align__(16) char smem[32768];
    gemm_body(blockIdx.x, blockIdx.y, Ab,
              (blockIdx.z == 0) ? H0 : H1, (blockIdx.z == 0) ? Y0 : Y1, smem);
}

template <int NSEGS, int CO, bool GATE, bool HASX>
__global__ __launch_bounds__(256) void napl2(
    const ushort_t* __restrict__ Bt, const float* __restrict__ bp,
    const float* __restrict__ emb, const float* __restrict__ WxPool,
    const ushort_t* __restrict__ s0p, const ushort_t* __restrict__ s1p,
    const ushort_t* __restrict__ s2p, const ushort_t* __restrict__ s3p,
    const float* __restrict__ xv, const float* __restrict__ axv,
    const float* hf, float* __restrict__ zf,
    ushort_t* __restrict__ outb, float* outf, int t) {
    __shared__ __align__(16) char smem[NSEGS * 8192];
    napl_body<NSEGS, CO, GATE, HASX>(blockIdx.x, smem, Bt, bp, emb, WxPool,
                                     s0p, s1p, s2p, s3p, xv, axv, hf, zf, outb, outf, t);
}

// ---- r13-path merged kernels (gemm part: 256 blocks now) ----
__global__ __launch_bounds__(256) void mergeA_k(
    const ushort_t* __restrict__ Abf, const ushort_t* __restrict__ Hg,
    ushort_t* __restrict__ Yg,
    const ushort_t* __restrict__ Bt, const float* __restrict__ bp,
    const float* __restrict__ emb, const float* __restrict__ Wx,
    const ushort_t* __restrict__ s0, const ushort_t* __restrict__ s1,
    const float* __restrict__ xv, const float* __restrict__ axv,
    const float* hf, float* __restrict__ zf, ushort_t* __restrict__ outb, int t) {
    __shared__ __align__(16) char smem[32768];
    const int g = blockIdx.x;
    if (g < 256)
        gemm_body(g & 15, g >> 4, Abf, Hg, Yg, smem);
    else
        napl_body<2, 128, true, true>(g - 256, smem, Bt, bp, emb, Wx,
                                      s0, s1, s0, s0, xv, axv, hf, zf, outb, nullptr, t);
}

__global__ __launch_bounds__(256) void mergeB_k(
    const ushort_t* __restrict__ Abf, const ushort_t* __restrict__ Hg,
    ushort_t* __restrict__ Yg,
    const ushort_t* __restrict__ Bt, const float* __restrict__ bp,
    const float* __restrict__ emb,
    const ushort_t* __restrict__ s0, const ushort_t* __restrict__ s1,
    const ushort_t* __restrict__ s2, const ushort_t* __restrict__ s3,
    const float* hf, float* __restrict__ zf,
    ushort_t* __restrict__ outb, float* outf, int t) {
    __shared__ __align__(16) char smem[32768];
    const int g = blockIdx.x;
    if (g < 256)
        gemm_body(g & 15, g >> 4, Abf, Hg, Yg, smem);
    else
        napl_body<4, 64, false, false>(g - 256, smem, Bt, bp, emb, nullptr,
                                       s0, s1, s2, s3, nullptr, nullptr, hf, zf, outb, outf, t);
}

__global__ __launch_bounds__(256) void mergeC_k(
    const ushort_t* __restrict__ Abf, const ushort_t* __restrict__ Hg,
    ushort_t* __restrict__ Yg,
    const ushort_t* __restrict__ Bt, const float* __restrict__ bp,
    const float* __restrict__ emb, const float* __restrict__ Wx,
    const ushort_t* __restrict__ s0, const ushort_t* __restrict__ s1,
    const float* __restrict__ xv, const float* __restrict__ axv,
    const float* hf, float* __restrict__ zf,
    ushort_t* __restrict__ outb, float* outf, int t) {
    __shared__ __align__(16) char smem[32768];
    const int g = blockIdx.x;
    if (g < 256)
        gemm_body(g & 15, g >> 4, Abf, Hg, Yg, smem);
    else
        napl_body<2, 64, false, true>(g - 256, smem, Bt, bp, emb, Wx,
                                      s0, s1, s0, s0, xv, axv, hf, zf, outb, outf, t);
}

// ---- pipe2 merged kernels ----
// mergeG: blocks [0,1000) = layer1 GATE (t); [1000,2000) = layer0 GATE (t+1)
__global__ __launch_bounds__(256) void mergeG_k(
    const ushort_t* __restrict__ Btg1, const float* __restrict__ bg1,
    const ushort_t* __restrict__ Btg0, const float* __restrict__ bg0,
    const float* __restrict__ emb, const float* __restrict__ Wg0,
    const ushort_t* __restrict__ hbt, const ushort_t* __restrict__ Ah0,
    const ushort_t* __restrict__ h1b, const ushort_t* __restrict__ AhX,
    const float* __restrict__ xv, const float* __restrict__ axv,
    const float* h0f, const float* h1f,
    float* __restrict__ zf0, float* __restrict__ zf1,
    ushort_t* __restrict__ rhb0, ushort_t* __restrict__ rhb1, int t) {
    __shared__ __align__(16) char smem[32768];
    const int g = blockIdx.x;
    if (g < 1000)
        napl_body<4, 128, true, false>(g, smem, Btg1, bg1, emb, nullptr,
                                       hbt, Ah0, h1b, AhX, nullptr, nullptr,
                                       h1f, zf1, rhb1, nullptr, t);
    else
        napl_body<2, 128, true, true>(g - 1000, smem, Btg0, bg0, emb, Wg0,
                                      hbt, Ah0, hbt, hbt, xv, axv,
                                      h0f, zf0, rhb0, nullptr, t + 1);
}

// mergeCC: blocks [0,1000) = layer1 CAND (t); [1000,2000) = layer0 CAND (t+1)
__global__ __launch_bounds__(256) void mergeCC_k(
    const ushort_t* __restrict__ Btc1, const float* __restrict__ bc1,
    const ushort_t* __restrict__ Btc0, const float* __restrict__ bc0,
    const float* __restrict__ emb, const float* __restrict__ Wc0,
    const ushort_t* __restrict__ hbt, ushort_t* __restrict__ hbt1,
    const ushort_t* __restrict__ Ah0, const ushort_t* __restrict__ rhb1,
    const ushort_t* __restrict__ AhX, const ushort_t* __restrict__ AhY,
    const ushort_t* __restrict__ rhb0,
    const float* __restrict__ xv, const float* __restrict__ axv,
    float* h0f, float* h1f,
    float* __restrict__ zf0, float* __restrict__ zf1,
    ushort_t* __restrict__ h1b, int t) {
    __shared__ __align__(16) char smem[32768];
    const int g = blockIdx.x;
    if (g < 1000)
        napl_body<4, 64, false, false>(g, smem, Btc1, bc1, emb, nullptr,
                                       hbt, Ah0, rhb1, AhX, nullptr, nullptr,
                                       h1f, zf1, h1b, h1f, t);
    else
        napl_body<2, 64, false, true>(g - 1000, smem, Btc0, bc0, emb, Wc0,
                                      rhb0, AhY, rhb0, rhb0, xv, axv,
                                      h0f, zf0, hbt1, h0f, t + 1);
}

// ---------------- prep: Bt[d][o][K] bf16 from pool (B^T form for MFMA) ----------------
template <int CI, int CO, bool L0>
__global__ __launch_bounds__(256) void prepW(const float* __restrict__ Wp,
                                             ushort_t* __restrict__ Bt) {
    constexpr int K = L0 ? 128 : 256;
    const int idx = blockIdx.x * 256 + threadIdx.x;
    if (idx >= DD * CO * K) return;
    const int d = idx / (CO * K);
    const int rem = idx - d * CO * K;
    const int o = rem / K;
    const int k = rem - o * K;
    const int s = k >> 6, c = k & 63;
    const int kk = L0 ? s : (s & 1);
    const int i = L0 ? (1 + c) : ((s >> 1) * 64 + c);
    Bt[idx] = f2bf(Wp[((size_t)(d * 2 + kk) * CI + i) * CO + o]);
}

// ---------------- head ----------------
__global__ __launch_bounds__(256) void head_kernel(const float* __restrict__ h1,
                                                   const float* __restrict__ hw,
                                                   const float* __restrict__ hb,
                                                   float* __restrict__ y) {
    __shared__ float wl[T_OUT * HH];
    const int tid = threadIdx.x;
    for (int idx = tid; idx < T_OUT * HH; idx += 256) wl[idx] = hw[idx];
    __syncthreads();
    const int gi = blockIdx.x * 256 + tid;
    if (gi >= BB * NN) return;
    const int b = gi / NN, n = gi % NN;
    float acc[T_OUT];
#pragma unroll
    for (int ot = 0; ot < T_OUT; ++ot) acc[ot] = hb[ot];
    for (int h = 0; h < HH; ++h) {
        float v = h1[(size_t)n * BC + b * 64 + h];
#pragma unroll
        for (int ot = 0; ot < T_OUT; ++ot) acc[ot] += v * wl[ot * HH + h];
    }
#pragma unroll
    for (int ot = 0; ot < T_OUT; ++ot)
        y[((size_t)b * T_OUT + ot) * NN + n] = acc[ot];
}

extern "C" void kernel_launch(void* const* d_in, const int* in_sizes, int n_in,
                              void* d_out, int out_size, void* d_ws, size_t ws_size,
                              hipStream_t stream) {
    const float* x = (const float*)d_in[0];
    const float* node_emb = (const float*)d_in[1];
    const float* adapt_emb = (const float*)d_in[2];
    const float* Wg0 = (const float*)d_in[3];
    const float* bg0 = (const float*)d_in[4];
    const float* Wc0 = (const float*)d_in[5];
    const float* bc0 = (const float*)d_in[6];
    const float* Wg1 = (const float*)d_in[7];
    const float* bg1 = (const float*)d_in[8];
    const float* Wc1 = (const float*)d_in[9];
    const float* bc1 = (const float*)d_in[10];
    const float* head_w = (const float*)d_in[11];
    const float* head_b = (const float*)d_in[12];
    float* y = (float*)d_out;

    char* ws = (char*)d_ws;
    ushort_t* Abf  = (ushort_t*)(ws + ABF_OFF);
    float* h0f = (float*)(ws + H0F_OFF);
    float* h1f = (float*)(ws + H1F_OFF);
    float* zf  = (float*)(ws + ZF_OFF);
    ushort_t* h0b = (ushort_t*)(ws + H0B_OFF);
    ushort_t* h1b = (ushort_t*)(ws + H1B_OFF);
    ushort_t* rhb = (ushort_t*)(ws + RHB_OFF);
    ushort_t* Ah0 = (ushort_t*)(ws + AH0_OFF);
    ushort_t* AhX = (ushort_t*)(ws + AHX_OFF);
    float* Axf = (float*)(ws + AXF_OFF);
    ushort_t* Btg0 = (ushort_t*)(ws + BTG0_OFF);
    ushort_t* Btc0 = (ushort_t*)(ws + BTC0_OFF);
    ushort_t* Btg1 = (ushort_t*)(ws + BTG1_OFF);
    ushort_t* Btc1 = (ushort_t*)(ws + BTC1_OFF);
    float* Af32 = zf;  // overlay: consumed before first gate writes z

    const bool pipe2 = (ws_size >= TOP_PIPE2);
    const bool pipe = (ws_size >= TOP_PIPE);

    hipMemsetAsync(h0f, 0, SZ_ST4, stream);
    hipMemsetAsync(h1f, 0, SZ_ST4, stream);
    hipMemsetAsync(h0b, 0, SZ_NPB2, stream);
    hipMemsetAsync(h1b, 0, SZ_NPB2, stream);
    hipMemsetAsync(rhb, 0, SZ_NPB2, stream);
    hipMemsetAsync(Ah0, 0, SZ_NPB2, stream);
    hipMemsetAsync(AhX, 0, SZ_NPB2, stream);

    compute_A_kernel<<<NN, 256, 0, stream>>>(adapt_emb, Af32);
    ax2_kernel<<<dim3(32, 16), 256, 0, stream>>>(Af32, x, Axf);
    convert_A<<<(NP * NP) / 256, 256, 0, stream>>>(Af32, Abf);
    prepW<65, 128, true><<<(DD * 128 * 128 + 255) / 256, 256, 0, stream>>>(Wg0, Btg0);
    prepW<65, 64, true><<<(DD * 64 * 128 + 255) / 256, 256, 0, stream>>>(Wc0, Btc0);
    prepW<128, 128, false><<<(DD * 128 * 256 + 255) / 256, 256, 0, stream>>>(Wg1, Btg1);
    prepW<128, 64, false><<<(DD * 64 * 256 + 255) / 256, 256, 0, stream>>>(Wc1, Btc1);

    const dim3 gG1(NP / 128, NP / 128, 1);  // 256 blocks
    const dim3 gG2(NP / 128, NP / 128, 2);  // dual GEMM: 512 blocks
    const int gN = NN * BB / 64;            // 1000 blocks

    if (pipe2) {
        float* zf0 = zf;
        ushort_t* rhb0 = rhb;
        float* zf1 = (float*)(ws + ZF1_OFF);
        ushort_t* rhb1 = (ushort_t*)(ws + RHB1_OFF);
        ushort_t* AhY = (ushort_t*)(ws + AHY_OFF);
        ushort_t* h0b2 = (ushort_t*)(ws + H0B2_OFF);
        hipMemsetAsync(rhb1, 0, SZ_NPB2, stream);
        hipMemsetAsync(h0b2, 0, SZ_NPB2, stream);
        ushort_t* hb[2] = {h0b, h0b2};  // C0(t) writes hb[t&1]

        // prologue: G0(0), R0(0), C0(0) -> hb[0], G2(0) -> Ah0
        napl2<2, 128, true, true><<<gN, 256, 0, stream>>>(
            Btg0, bg0, node_emb, Wg0, h0b, Ah0, h0b, h0b, x, Axf, h0f, zf0, rhb0, nullptr, 0);
        gemm_trb<<<gG1, 256, 0, stream>>>(Abf, rhb0, AhY, rhb0, AhY);
        napl2<2, 64, false, true><<<gN, 256, 0, stream>>>(
            Btc0, bc0, node_emb, Wc0, rhb0, AhY, rhb0, rhb0, x, Axf, h0f, zf0, hb[0], h0f, 0);
        gemm_trb<<<gG1, 256, 0, stream>>>(Abf, hb[0], Ah0, hb[0], Ah0);

        for (int t = 0; t < TT - 1; ++t) {
            ushort_t* hbt = hb[t & 1];
            ushort_t* hbt1 = hb[(t + 1) & 1];
            // D1: G1(t) || G0(t+1)
            mergeG_k<<<2000, 256, 0, stream>>>(Btg1, bg1, Btg0, bg0, node_emb, Wg0,
                hbt, Ah0, h1b, AhX, x, Axf, h0f, h1f, zf0, zf1, rhb0, rhb1, t);
            // D2: R1(t): AhX <- A@rhb1 || R0(t+1): AhY <- A@rhb0
            gemm_trb<<<gG2, 256, 0, stream>>>(Abf, rhb1, AhX, rhb0, AhY);
            // D3: C1(t) -> h1f,h1b || C0(t+1) -> h0f,hbt1
            mergeCC_k<<<2000, 256, 0, stream>>>(Btc1, bc1, Btc0, bc0, node_emb, Wc0,
                hbt, hbt1, Ah0, rhb1, AhX, AhY, rhb0, x, Axf, h0f, h1f, zf0, zf1, h1b, t);
            // D4: AhX <- A@h1b || Ah0 <- A@hbt1
            gemm_trb<<<gG2, 256, 0, stream>>>(Abf, h1b, AhX, hbt1, Ah0);
        }
        // epilogue t=TT-1
        {
            ushort_t* hbT = hb[(TT - 1) & 1];
            napl2<4, 128, true, false><<<gN, 256, 0, stream>>>(
                Btg1, bg1, node_emb, nullptr, hbT, Ah0, h1b, AhX, nullptr, nullptr, h1f, zf1, rhb1, nullptr, TT - 1);
            gemm_trb<<<gG1, 256, 0, stream>>>(Abf, rhb1, AhX, rhb1, AhX);
            napl2<4, 64, false, false><<<gN, 256, 0, stream>>>(
                Btc1, bc1, node_emb, nullptr, hbT, Ah0, rhb1, AhX, nullptr, nullptr, h1f, zf1, h1b, h1f, TT - 1);
        }
    } else if (pipe) {
        float* zf0 = zf;
        ushort_t* rhb0 = rhb;
        float* zf1 = (float*)(ws + ZF1_OFF);
        ushort_t* rhb1 = (ushort_t*)(ws + RHB1_OFF);
        ushort_t* AhY = (ushort_t*)(ws + AHY_OFF);
        hipMemsetAsync(rhb1, 0, SZ_NPB2, stream);

        napl2<2, 128, true, true><<<gN, 256, 0, stream>>>(
            Btg0, bg0, node_emb, Wg0, h0b, Ah0, h0b, h0b, x, Axf, h0f, zf0, rhb0, nullptr, 0);
        gemm_trb<<<gG1, 256, 0, stream>>>(Abf, rhb0, AhY, rhb0, AhY);
        napl2<2, 64, false, true><<<gN, 256, 0, stream>>>(
            Btc0, bc0, node_emb, Wc0, rhb0, AhY, rhb0, rhb0, x, Axf, h0f, zf0, h0b, h0f, 0);
        gemm_trb<<<gG2, 256, 0, stream>>>(Abf, h0b, Ah0, h1b, AhX);
        napl2<4, 128, true, false><<<gN, 256, 0, stream>>>(
            Btg1, bg1, node_emb, nullptr, h0b, Ah0, h1b, AhX, nullptr, nullptr, h1f, zf1, rhb1, nullptr, 0);

        for (int t = 0; t < TT - 1; ++t) {
            mergeA_k<<<1256, 256, 0, stream>>>(Abf, rhb1, AhX,
                Btg0, bg0, node_emb, Wg0, h0b, Ah0, x, Axf, h0f, zf0, rhb0, t + 1);
            mergeB_k<<<1256, 256, 0, stream>>>(Abf, rhb0, AhY,
                Btc1, bc1, node_emb, h0b, Ah0, rhb1, AhX, h1f, zf1, h1b, h1f, t);
            mergeC_k<<<1256, 256, 0, stream>>>(Abf, h1b, AhX,
                Btc0, bc0, node_emb, Wc0, rhb0, AhY, x, Axf, h0f, zf0, h0b, h0f, t + 1);
            gemm_trb<<<gG1, 256, 0, stream>>>(Abf, h0b, Ah0, h0b, Ah0);
            napl2<4, 128, true, false><<<gN, 256, 0, stream>>>(
                Btg1, bg1, node_emb, nullptr, h0b, Ah0, h1b, AhX, nullptr, nullptr, h1f, zf1, rhb1, nullptr, t + 1);
        }
        gemm_trb<<<gG1, 256, 0, stream>>>(Abf, rhb1, AhX, rhb1, AhX);
        napl2<4, 64, false, false><<<gN, 256, 0, stream>>>(
            Btc1, bc1, node_emb, nullptr, h0b, Ah0, rhb1, AhX, nullptr, nullptr, h1f, zf1, h1b, h1f, TT - 1);
    } else {
        for (int t = 0; t < TT; ++t) {
            napl2<2, 128, true, true><<<gN, 256, 0, stream>>>(
                Btg0, bg0, node_emb, Wg0, h0b, Ah0, h0b, h0b, x, Axf, h0f, zf, rhb, nullptr, t);
            gemm_trb<<<gG1, 256, 0, stream>>>(Abf, rhb, AhX, rhb, AhX);
            napl2<2, 64, false, true><<<gN, 256, 0, stream>>>(
                Btc0, bc0, node_emb, Wc0, rhb, AhX, rhb, rhb, x, Axf, h0f, zf, h0b, h0f, t);
            gemm_trb<<<gG2, 256, 0, stream>>>(Abf, h0b, Ah0, h1b, AhX);
            napl2<4, 128, true, false><<<gN, 256, 0, stream>>>(
                Btg1, bg1, node_emb, nullptr, h0b, Ah0, h1b, AhX, nullptr, nullptr, h1f, zf, rhb, nullptr, t);
            gemm_trb<<<gG1, 256, 0, stream>>>(Abf, rhb, AhX, rhb, AhX);
            napl2<4, 64, false, false><<<gN, 256, 0, stream>>>(
                Btc1, bc1, node_emb, nullptr, h0b, Ah0, rhb, AhX, nullptr, nullptr, h1f, zf, h1b, h1f, t);
        }
    }

    head_kernel<<<(BB * NN + 255) / 256, 256, 0, stream>>>(h1f, head_w, head_b, y);
}

// Round 16
// 8110.310 us; speedup vs baseline: 1.4042x; 1.0138x over previous
//
#include <hip/hip_runtime.h>
#include <math.h>

#define NN 2000
#define BB 32
#define TT 24
#define T_OUT 12
#define HH 64
#define DD 10
#define NP 2048   // padded node dim
#define BC 2048   // B*H columns (j = b*64 + c)

typedef unsigned short ushort_t;
typedef __bf16 bf16x8 __attribute__((ext_vector_type(8)));
typedef float f32x4 __attribute__((ext_vector_type(4)));

__device__ __forceinline__ float sigmoidf_(float x) { return 1.f / (1.f + expf(-x)); }

__device__ __forceinline__ ushort_t f2bf(float f) {
    unsigned int u = __float_as_uint(f);
    unsigned int r = (u + 0x7FFFu + ((u >> 16) & 1u)) >> 16;
    return (ushort_t)r;
}
__device__ __forceinline__ float bf2f(ushort_t s) {
    return __uint_as_float(((unsigned int)s) << 16);
}

__device__ __forceinline__ void glld16(const ushort_t* g, ushort_t* lds) {
    __builtin_amdgcn_global_load_lds(
        (const __attribute__((address_space(1))) char*)g,
        (__attribute__((address_space(3))) char*)lds, 16, 0, 0);
}

__device__ __forceinline__ unsigned lds_off(const void* p) {
    return (unsigned)(size_t)(__attribute__((address_space(3))) const char*)p;
}

// ---------------- workspace layout (bytes) ----------------
constexpr size_t SZ_NPNP2 = (size_t)NP * NP * 2;   // 8,388,608
constexpr size_t SZ_ST4   = (size_t)NN * BC * 4;   // 16,384,000
constexpr size_t SZ_NPB2  = (size_t)NP * BC * 2;   // 8,388,608 (padded bf16 state)

constexpr size_t ABF_OFF  = 0;
constexpr size_t H0F_OFF  = ABF_OFF + SZ_NPNP2;
constexpr size_t H1F_OFF  = H0F_OFF + SZ_ST4;
constexpr size_t ZF_OFF   = H1F_OFF + SZ_ST4;       // f32; overlaid with A_f32 in setup
constexpr size_t H0B_OFF  = ZF_OFF + SZ_ST4;
constexpr size_t H1B_OFF  = H0B_OFF + SZ_NPB2;
constexpr size_t RHB_OFF  = H1B_OFF + SZ_NPB2;
constexpr size_t AH0_OFF  = RHB_OFF + SZ_NPB2;
constexpr size_t AHX_OFF  = AH0_OFF + SZ_NPB2;
constexpr size_t AXF_OFF  = AHX_OFF + SZ_NPB2;      // [B][T][N] f32
constexpr size_t BTG0_OFF = AXF_OFF + (size_t)BB * TT * NN * 4;
constexpr size_t BTC0_OFF = BTG0_OFF + (size_t)DD * 128 * 128 * 2;  // 327,680
constexpr size_t BTG1_OFF = BTC0_OFF + (size_t)DD * 64 * 128 * 2;   // 163,840
constexpr size_t BTC1_OFF = BTG1_OFF + (size_t)DD * 128 * 256 * 2;  // 655,360
constexpr size_t WS_TOP   = BTC1_OFF + (size_t)DD * 64 * 256 * 2;   // 107,102,208
// pipelined-path extension (r12/r13)
constexpr size_t ZF1_OFF  = WS_TOP;                      // f32 16,384,000
constexpr size_t RHB1_OFF = ZF1_OFF + SZ_ST4;            // bf16 8,388,608
constexpr size_t AHY_OFF  = RHB1_OFF + SZ_NPB2;          // bf16 8,388,608
constexpr size_t TOP_PIPE = AHY_OFF + SZ_NPB2;           // 140,263,424
// pipe2 extension: parity copy of h0b
constexpr size_t H0B2_OFF = TOP_PIPE;                    // bf16 8,388,608
constexpr size_t TOP_PIPE2 = H0B2_OFF + SZ_NPB2;         // 148,652,032

// ---------------- A_f32 = row_softmax(relu(E E^T)) ----------------
__global__ __launch_bounds__(256) void compute_A_kernel(const float* __restrict__ E,
                                                        float* __restrict__ A) {
    const int row = blockIdx.x;
    const int tid = threadIdx.x;
    float er[DD];
#pragma unroll
    for (int d = 0; d < DD; ++d) er[d] = E[row * DD + d];
    __shared__ float red[8];

    float lmax = -1e30f;
    for (int c = tid; c < NN; c += 256) {
        float s = 0.f;
#pragma unroll
        for (int d = 0; d < DD; ++d) s += er[d] * E[c * DD + d];
        s = fmaxf(s, 0.f);
        A[(size_t)row * NN + c] = s;
        lmax = fmaxf(lmax, s);
    }
#pragma unroll
    for (int o = 32; o > 0; o >>= 1) lmax = fmaxf(lmax, __shfl_down(lmax, o, 64));
    if ((tid & 63) == 0) red[tid >> 6] = lmax;
    __syncthreads();
    const float rmax = fmaxf(fmaxf(red[0], red[1]), fmaxf(red[2], red[3]));
    __syncthreads();

    float lsum = 0.f;
    for (int c = tid; c < NN; c += 256) {
        float v = expf(A[(size_t)row * NN + c] - rmax);
        A[(size_t)row * NN + c] = v;
        lsum += v;
    }
#pragma unroll
    for (int o = 32; o > 0; o >>= 1) lsum += __shfl_down(lsum, o, 64);
    if ((tid & 63) == 0) red[4 + (tid >> 6)] = lsum;
    __syncthreads();
    const float inv = 1.f / (red[4] + red[5] + red[6] + red[7]);
    for (int c = tid; c < NN; c += 256) A[(size_t)row * NN + c] *= inv;
}

// ---------------- A_f32 -> A_bf [2048][2048] with zero pad ----------------
__global__ __launch_bounds__(256) void convert_A(const float* __restrict__ Af,
                                                 ushort_t* __restrict__ Ab) {
    size_t idx = (size_t)blockIdx.x * 256 + threadIdx.x;
    int r = (int)(idx >> 11), c = (int)(idx & 2047);
    float v = (r < NN && c < NN) ? Af[(size_t)r * NN + c] : 0.f;
    Ab[idx] = f2bf(v);
}

// ---------------- Ax[b,t,n] = sum_m A[n,m] x[b,t,m]  (f32, one-time) ----------------
// v5: grid (32,32), 1 batch x 24 t per block; lane = n-row (conflict-free As reads,
// coalesced stores), wave = col-group (xs reads wave-uniform). 1024 blocks = 4/CU.
// Same per-output summation order as v1..v4 (bit-identical Ax).
__global__ __launch_bounds__(256) void ax2_kernel(const float* __restrict__ A,
                                                  const float* __restrict__ x,
                                                  float* __restrict__ Ax) {
    __shared__ float As[64][66];  // [mm][r]
    __shared__ float xs[64][26];  // [mm][t], 24 used
    const int n0 = blockIdx.x * 64;
    const int b = blockIdx.y;
    const int tid = threadIdx.x;
    const int lane = tid & 63, cq = tid >> 6;  // cq = wave id, cols cq*6..cq*6+5
    float acc[6] = {};

    for (int m0 = 0; m0 < NN; m0 += 64) {
#pragma unroll
        for (int l = 0; l < 16; ++l) {
            int idx = tid + l * 256;
            int mm = idx & 63, r = idx >> 6;
            int n = n0 + r, m = m0 + mm;
            As[mm][r] = (n < NN && m < NN) ? A[(size_t)n * NN + m] : 0.f;
        }
#pragma unroll
        for (int l = 0; l < 6; ++l) {
            int idx = tid + l * 256;
            int mm = idx & 63, t = idx >> 6;
            int m = m0 + mm;
            xs[mm][t] = (m < NN) ? x[((size_t)b * TT + t) * NN + m] : 0.f;
        }
        __syncthreads();
#pragma unroll 4
        for (int mm = 0; mm < 64; ++mm) {
            const float a = As[mm][lane];
            float2 x01 = *(const float2*)&xs[mm][cq * 6];
            float2 x23 = *(const float2*)&xs[mm][cq * 6 + 2];
            float2 x45 = *(const float2*)&xs[mm][cq * 6 + 4];
            acc[0] += a * x01.x;
            acc[1] += a * x01.y;
            acc[2] += a * x23.x;
            acc[3] += a * x23.y;
            acc[4] += a * x45.x;
            acc[5] += a * x45.y;
        }
        __syncthreads();
    }
    const int n = n0 + lane;
    if (n < NN) {
#pragma unroll
        for (int j = 0; j < 6; ++j) {
            const int t = cq * 6 + j;
            Ax[((size_t)b * TT + t) * NN + n] = acc[j];
        }
    }
}

// ================== device bodies ==================

// MFMA GEMM body: 128x128 tile, BK=64, 32 KB smem. NW = waves/block (4 or 8).
// NW=8: each wave owns one 16-col j-subtile (SPW=1) -> 2x resident waves hide the
// barrier drain. Per-output K-order identical for both NW -> bit-identical results.
template <int NW>
__device__ __forceinline__ void gemm_body(int bx, int by,
                                          const ushort_t* __restrict__ Ab,
                                          const ushort_t* __restrict__ H,
                                          ushort_t* __restrict__ Y, char* smem) {
    constexpr int TH = NW * 64;
    constexpr int SPW = 8 / NW;  // j-subtiles per wave
    ushort_t* As = (ushort_t*)smem;             // 16 KB (128 rows x 64 k)
    ushort_t* Bs = (ushort_t*)(smem + 16384);   // 16 KB (two 8 KB halves)
    const int tid = threadIdx.x;
    const int w = tid >> 6, l = tid & 63, lr = l & 15, lg = l >> 4;
    const int n0 = bx * 128, j0 = by * 128;
    f32x4 acc[8][SPW] = {};

    const unsigned bs0 = lds_off(Bs);
    unsigned btr_b[SPW];
#pragma unroll
    for (int nt = 0; nt < SPW; ++nt)
        btr_b[nt] = bs0 + 2u * ((unsigned)(w * SPW + nt) * 512 + (unsigned)lg * 128 + (unsigned)lr);

    for (int ks = 0; ks < NP / 64; ++ks) {
        const int k0 = ks * 64;
#pragma unroll
        for (int p = 0; p < 1024 / TH; ++p) {  // A: 128x64, XOR-swizzled
            const int idx = p * TH + tid;
            const int row = idx >> 3, sl = idx & 7;
            glld16(Ab + (size_t)(n0 + row) * NP + k0 + ((sl ^ (row & 7)) << 3),
                   (ushort_t*)((char*)As + idx * 16));
        }
#pragma unroll
        for (int p = 0; p < 1024 / TH; ++p) {  // B: two 32-row halves, tr-read subtile order
            const int idx = p * TH + tid;
            const int g = idx >> 9, li = idx & 511;
            const int row = k0 + g * 32 + ((li >> 3) & 7) * 4 + ((li >> 1) & 3);
            const int col = j0 + (li >> 6) * 16 + (li & 1) * 8;
            glld16(H + (size_t)row * BC + col,
                   (ushort_t*)((char*)Bs + g * 8192 + li * 16));
        }
        __syncthreads();

        unsigned long long bq[2][SPW][2];  // [kk][nt][half]
        if constexpr (SPW == 2) {
            asm volatile(
                "ds_read_b64_tr_b16 %0, %8 offset:0\n\t"
                "ds_read_b64_tr_b16 %1, %8 offset:128\n\t"
                "ds_read_b64_tr_b16 %2, %9 offset:0\n\t"
                "ds_read_b64_tr_b16 %3, %9 offset:128\n\t"
                "ds_read_b64_tr_b16 %4, %8 offset:8192\n\t"
                "ds_read_b64_tr_b16 %5, %8 offset:8320\n\t"
                "ds_read_b64_tr_b16 %6, %9 offset:8192\n\t"
                "ds_read_b64_tr_b16 %7, %9 offset:8320"
                : "=v"(bq[0][0][0]), "=v"(bq[0][0][1]), "=v"(bq[0][1][0]), "=v"(bq[0][1][1]),
                  "=v"(bq[1][0][0]), "=v"(bq[1][0][1]), "=v"(bq[1][1][0]), "=v"(bq[1][1][1])
                : "v"(btr_b[0]), "v"(btr_b[1]));
        } else {
            asm volatile(
                "ds_read_b64_tr_b16 %0, %4 offset:0\n\t"
                "ds_read_b64_tr_b16 %1, %4 offset:128\n\t"
                "ds_read_b64_tr_b16 %2, %4 offset:8192\n\t"
                "ds_read_b64_tr_b16 %3, %4 offset:8320"
                : "=v"(bq[0][0][0]), "=v"(bq[0][0][1]), "=v"(bq[1][0][0]), "=v"(bq[1][0][1])
                : "v"(btr_b[0]));
        }
        asm volatile("s_waitcnt lgkmcnt(0)" ::: "memory");
        __builtin_amdgcn_sched_barrier(0);
        bf16x8 bv[2][SPW];
#pragma unroll
        for (int kk = 0; kk < 2; ++kk)
#pragma unroll
            for (int nt = 0; nt < SPW; ++nt) {
                union { unsigned long long q[2]; bf16x8 f; } u;
                u.q[0] = bq[kk][nt][0];
                u.q[1] = bq[kk][nt][1];
                bv[kk][nt] = u.f;
            }

#pragma unroll
        for (int kk = 0; kk < 2; ++kk)
#pragma unroll
            for (int m = 0; m < 8; ++m) {
                const int rr = m * 16 + lr;
                const bf16x8 av = *(const bf16x8*)&As[rr * 64 + (((kk * 4 + lg) ^ (rr & 7)) << 3)];
#pragma unroll
                for (int nt = 0; nt < SPW; ++nt)
                    acc[m][nt] = __builtin_amdgcn_mfma_f32_16x16x32_bf16(av, bv[kk][nt], acc[m][nt], 0, 0, 0);
            }
        __syncthreads();
    }

#pragma unroll
    for (int m = 0; m < 8; ++m)
#pragma unroll
        for (int r = 0; r < 4; ++r) {
            const int n = n0 + m * 16 + lg * 4 + r;
            if (n < NN) {
#pragma unroll
                for (int nt = 0; nt < SPW; ++nt)
                    Y[(size_t)n * BC + j0 + (w * SPW + nt) * 16 + lr] = f2bf(acc[m][nt][r]);
            }
        }
}

// factored-MFMA NAPL body (LDS-staged + av-hoist over d). smem = NSEGS*8 KB. 4 waves.
template <int NSEGS, int CO, bool GATE, bool HASX>
__device__ __forceinline__ void napl_body(
    int bid, char* smem,
    const ushort_t* __restrict__ Bt, const float* __restrict__ bp,
    const float* __restrict__ emb, const float* __restrict__ WxPool,
    const ushort_t* __restrict__ s0p, const ushort_t* __restrict__ s1p,
    const ushort_t* __restrict__ s2p, const ushort_t* __restrict__ s3p,
    const float* __restrict__ xv, const float* __restrict__ axv,
    const float* hf, float* __restrict__ zf,
    ushort_t* __restrict__ outb, float* outf, int t) {
    constexpr int K = NSEGS * 64;
    constexpr int NT = (CO == 128) ? 2 : 1;
    constexpr int NHALF = NSEGS / 2;
    ushort_t* As = (ushort_t*)smem;
    const int tid = threadIdx.x;
    const int w = tid >> 6, l = tid & 63, lr = l & 15, lg = l >> 4;
    const int n0 = bid * 2;
    const int ob = w * (16 * NT);
    const ushort_t* segs[4] = {s0p, s1p, s2p, s3p};

#pragma unroll
    for (int s = 0; s < NSEGS; ++s) {
        const ushort_t* sp = segs[s];
#pragma unroll
        for (int p = 0; p < 2; ++p) {
            const int idx = p * 256 + tid;
            const int row = idx >> 3, c16 = idx & 7;
            glld16(sp + (size_t)(n0 + (row >> 5)) * BC + (row & 31) * 64 +
                       ((c16 ^ (row & 7)) << 3),
                   (ushort_t*)((char*)As + s * 8192 + idx * 16));
        }
    }
    __syncthreads();

    f32x4 OUT[4][NT] = {};
#pragma unroll 1
    for (int hf2 = 0; hf2 < NHALF; ++hf2) {
        bf16x8 av[4][4];  // [c][m], c = s_local*2 + h2
#pragma unroll
        for (int c = 0; c < 4; ++c) {
            const int s = hf2 * 2 + (c >> 1);
            const int kin = (c & 1) * 32 + lg * 8;
#pragma unroll
            for (int m = 0; m < 4; ++m) {
                const int rr = m * 16 + lr;
                av[c][m] = *(const bf16x8*)&As[s * 4096 + rr * 64 + (kin ^ ((rr & 7) << 3))];
            }
        }
#pragma unroll 1
        for (int d = 0; d < DD; ++d) {
            const ushort_t* btd = Bt + (size_t)d * CO * K;
            const float ea = emb[n0 * DD + d];
            const float eb = emb[(n0 + 1) * DD + d];
            f32x4 P[4][NT] = {};
#pragma unroll
            for (int c = 0; c < 4; ++c) {
                const int kg = (hf2 * 2 + (c >> 1)) * 64 + (c & 1) * 32 + lg * 8;
                bf16x8 bv[NT];
#pragma unroll
                for (int nt = 0; nt < NT; ++nt)
                    bv[nt] = *(const bf16x8*)&btd[(size_t)(ob + nt * 16 + lr) * K + kg];
#pragma unroll
                for (int m = 0; m < 4; ++m)
#pragma unroll
                    for (int nt = 0; nt < NT; ++nt)
                        P[m][nt] = __builtin_amdgcn_mfma_f32_16x16x32_bf16(av[c][m], bv[nt], P[m][nt], 0, 0, 0);
            }
#pragma unroll
            for (int m = 0; m < 4; ++m) {
                const float e = (m < 2) ? ea : eb;
#pragma unroll
                for (int nt = 0; nt < NT; ++nt)
#pragma unroll
                    for (int r = 0; r < 4; ++r)
                        OUT[m][nt][r] += e * P[m][nt][r];
            }
        }
    }

    float bias[2][NT];
#pragma unroll
    for (int nd = 0; nd < 2; ++nd)
#pragma unroll
        for (int nt = 0; nt < NT; ++nt) {
            float s_ = 0.f;
#pragma unroll
            for (int d = 0; d < DD; ++d)
                s_ += emb[(n0 + nd) * DD + d] * bp[d * CO + ob + nt * 16 + lr];
            bias[nd][nt] = s_;
        }
    float wx[2][2][NT] = {};
    if (HASX) {
#pragma unroll
        for (int kk = 0; kk < 2; ++kk)
#pragma unroll
            for (int nd = 0; nd < 2; ++nd)
#pragma unroll
                for (int nt = 0; nt < NT; ++nt) {
                    float s_ = 0.f;
#pragma unroll
                    for (int d = 0; d < DD; ++d)
                        s_ += emb[(n0 + nd) * DD + d] *
                              WxPool[(size_t)(d * 2 + kk) * 65 * CO + ob + nt * 16 + lr];
                    wx[kk][nd][nt] = s_;
                }
    }

#pragma unroll
    for (int m = 0; m < 4; ++m) {
        const int nd = m >> 1;
        const int n = n0 + nd;
#pragma unroll
        for (int r = 0; r < 4; ++r) {
            const int row = m * 16 + lg * 4 + r;
            const int b = row & 31;
            const size_t nb = (size_t)n * BC + b * 64;
            float xt = 0.f, axt = 0.f;
            if (HASX) {
                xt = xv[((size_t)b * TT + t) * NN + n];
                axt = axv[((size_t)b * TT + t) * NN + n];
            }
#pragma unroll
            for (int nt = 0; nt < NT; ++nt) {
                const int o = ob + nt * 16 + lr;
                float val = OUT[m][nt][r] + bias[nd][nt];
                if (HASX) val += xt * wx[0][nd][nt] + axt * wx[1][nd][nt];
                if (GATE) {
                    const float sg = sigmoidf_(val);
                    if (ob < 64) {
                        zf[nb + o] = sg;
                    } else {
                        outb[nb + (o - 64)] = f2bf(sg * hf[nb + (o - 64)]);
                    }
                } else {
                    const float hc = tanhf(val);
                    const float z = zf[nb + o];
                    const float hn = z * hf[nb + o] + (1.f - z) * hc;
                    outf[nb + o] = hn;
                    outb[nb + o] = f2bf(hn);
                }
            }
        }
    }
}

// ================== kernels ==================

__global__ __launch_bounds__(512) void gemm_trb(const ushort_t* __restrict__ Ab,
                                                const ushort_t* __restrict__ H0,
                                                ushort_t* __restrict__ Y0,
                                                const ushort_t* __restrict__ H1,
                                                ushort_t* __restrict__ Y1) {
    __shared__ __align__(16) char smem[32768];
    gemm_body<8>(blockIdx.x, blockIdx.y, Ab,
                 (blockIdx.z == 0) ? H0 : H1, (blockIdx.z == 0) ? Y0 : Y1, smem);
}

template <int NSEGS, int CO, bool GATE, bool HASX>
__global__ __launch_bounds__(256) void napl2(
    const ushort_t* __restrict__ Bt, const float* __restrict__ bp,
    const float* __restrict__ emb, const float* __restrict__ WxPool,
    const ushort_t* __restrict__ s0p, const ushort_t* __restrict__ s1p,
    const ushort_t* __restrict__ s2p, const ushort_t* __restrict__ s3p,
    const float* __restrict__ xv, const float* __restrict__ axv,
    const float* hf, float* __restrict__ zf,
    ushort_t* __restrict__ outb, float* outf, int t) {
    __shared__ __align__(16) char smem[NSEGS * 8192];
    napl_body<NSEGS, CO, GATE, HASX>(blockIdx.x, smem, Bt, bp, emb, WxPool,
                                     s0p, s1p, s2p, s3p, xv, axv, hf, zf, outb, outf, t);
}

// ---- r13-path merged kernels (4-wave gemm body; dead under pipe2, kept for fallback) ----
__global__ __launch_bounds__(256) void mergeA_k(
    const ushort_t* __restrict__ Abf, const ushort_t* __restrict__ Hg,
    ushort_t* __restrict__ Yg,
    const ushort_t* __restrict__ Bt, const float* __restrict__ bp,
    const float* __restrict__ emb, const float* __restrict__ Wx,
    const ushort_t* __restrict__ s0, const ushort_t* __restrict__ s1,
    const float* __restrict__ xv, const float* __restrict__ axv,
    const float* hf, float* __restrict__ zf, ushort_t* __restrict__ outb, int t) {
    __shared__ __align__(16) char smem[32768];
    const int g = blockIdx.x;
    if (g < 256)
        gemm_body<4>(g & 15, g >> 4, Abf, Hg, Yg, smem);
    else
        napl_body<2, 128, true, true>(g - 256, smem, Bt, bp, emb, Wx,
                                      s0, s1, s0, s0, xv, axv, hf, zf, outb, nullptr, t);
}

__global__ __launch_bounds__(256) void mergeB_k(
    const ushort_t* __restrict__ Abf, const ushort_t* __restrict__ Hg,
    ushort_t* __restrict__ Yg,
    const ushort_t* __restrict__ Bt, const float* __restrict__ bp,
    const float* __restrict__ emb,
    const ushort_t* __restrict__ s0, const ushort_t* __restrict__ s1,
    const ushort_t* __restrict__ s2, const ushort_t* __restrict__ s3,
    const float* hf, float* __restrict__ zf,
    ushort_t* __restrict__ outb, float* outf, int t) {
    __shared__ __align__(16) char smem[32768];
    const int g = blockIdx.x;
    if (g < 256)
        gemm_body<4>(g & 15, g >> 4, Abf, Hg, Yg, smem);
    else
        napl_body<4, 64, false, false>(g - 256, smem, Bt, bp, emb, nullptr,
                                       s0, s1, s2, s3, nullptr, nullptr, hf, zf, outb, outf, t);
}

__global__ __launch_bounds__(256) void mergeC_k(
    const ushort_t* __restrict__ Abf, const ushort_t* __restrict__ Hg,
    ushort_t* __restrict__ Yg,
    const ushort_t* __restrict__ Bt, const float* __restrict__ bp,
    const float* __restrict__ emb, const float* __restrict__ Wx,
    const ushort_t* __restrict__ s0, const ushort_t* __restrict__ s1,
    const float* __restrict__ xv, const float* __restrict__ axv,
    const float* hf, float* __restrict__ zf,
    ushort_t* __restrict__ outb, float* outf, int t) {
    __shared__ __align__(16) char smem[32768];
    const int g = blockIdx.x;
    if (g < 256)
        gemm_body<4>(g & 15, g >> 4, Abf, Hg, Yg, smem);
    else
        napl_body<2, 64, false, true>(g - 256, smem, Bt, bp, emb, Wx,
                                      s0, s1, s0, s0, xv, axv, hf, zf, outb, outf, t);
}

// ---- pipe2 merged kernels ----
// mergeG: blocks [0,1000) = layer1 GATE (t); [1000,2000) = layer0 GATE (t+1)
__global__ __launch_bounds__(256) void mergeG_k(
    const ushort_t* __restrict__ Btg1, const float* __restrict__ bg1,
    const ushort_t* __restrict__ Btg0, const float* __restrict__ bg0,
    const float* __restrict__ emb, const float* __restrict__ Wg0,
    const ushort_t* __restrict__ hbt, const ushort_t* __restrict__ Ah0,
    const ushort_t* __restrict__ h1b, const ushort_t* __restrict__ AhX,
    const float* __restrict__ xv, const float* __restrict__ axv,
    const float* h0f, const float* h1f,
    float* __restrict__ zf0, float* __restrict__ zf1,
    ushort_t* __restrict__ rhb0, ushort_t* __restrict__ rhb1, int t) {
    __shared__ __align__(16) char smem[32768];
    const int g = blockIdx.x;
    if (g < 1000)
        napl_body<4, 128, true, false>(g, smem, Btg1, bg1, emb, nullptr,
                                       hbt, Ah0, h1b, AhX, nullptr, nullptr,
                                       h1f, zf1, rhb1, nullptr, t);
    else
        napl_body<2, 128, true, true>(g - 1000, smem, Btg0, bg0, emb, Wg0,
                                      hbt, Ah0, hbt, hbt, xv, axv,
                                      h0f, zf0, rhb0, nullptr, t + 1);
}

// mergeCC: blocks [0,1000) = layer1 CAND (t); [1000,2000) = layer0 CAND (t+1)
__global__ __launch_bounds__(256) void mergeCC_k(
    const ushort_t* __restrict__ Btc1, const float* __restrict__ bc1,
    const ushort_t* __restrict__ Btc0, const float* __restrict__ bc0,
    const float* __restrict__ emb, const float* __restrict__ Wc0,
    const ushort_t* __restrict__ hbt, ushort_t* __restrict__ hbt1,
    const ushort_t* __restrict__ Ah0, const ushort_t* __restrict__ rhb1,
    const ushort_t* __restrict__ AhX, const ushort_t* __restrict__ AhY,
    const ushort_t* __restrict__ rhb0,
    const float* __restrict__ xv, const float* __restrict__ axv,
    float* h0f, float* h1f,
    float* __restrict__ zf0, float* __restrict__ zf1,
    ushort_t* __restrict__ h1b, int t) {
    __shared__ __align__(16) char smem[32768];
    const int g = blockIdx.x;
    if (g < 1000)
        napl_body<4, 64, false, false>(g, smem, Btc1, bc1, emb, nullptr,
                                       hbt, Ah0, rhb1, AhX, nullptr, nullptr,
                                       h1f, zf1, h1b, h1f, t);
    else
        napl_body<2, 64, false, true>(g - 1000, smem, Btc0, bc0, emb, Wc0,
                                      rhb0, AhY, rhb0, rhb0, xv, axv,
                                      h0f, zf0, hbt1, h0f, t + 1);
}

// ---------------- prep: Bt[d][o][K] bf16 from pool (B^T form for MFMA) ----------------
template <int CI, int CO, bool L0>
__global__ __launch_bounds__(256) void prepW(const float* __restrict__ Wp,
                                             ushort_t* __restrict__ Bt) {
    constexpr int K = L0 ? 128 : 256;
    const int idx = blockIdx.x * 256 + threadIdx.x;
    if (idx >= DD * CO * K) return;
    const int d = idx / (CO * K);
    const int rem = idx - d * CO * K;
    const int o = rem / K;
    const int k = rem - o * K;
    const int s = k >> 6, c = k & 63;
    const int kk = L0 ? s : (s & 1);
    const int i = L0 ? (1 + c) : ((s >> 1) * 64 + c);
    Bt[idx] = f2bf(Wp[((size_t)(d * 2 + kk) * CI + i) * CO + o]);
}

// ---------------- head ----------------
__global__ __launch_bounds__(256) void head_kernel(const float* __restrict__ h1,
                                                   const float* __restrict__ hw,
                                                   const float* __restrict__ hb,
                                                   float* __restrict__ y) {
    __shared__ float wl[T_OUT * HH];
    const int tid = threadIdx.x;
    for (int idx = tid; idx < T_OUT * HH; idx += 256) wl[idx] = hw[idx];
    __syncthreads();
    const int gi = blockIdx.x * 256 + tid;
    if (gi >= BB * NN) return;
    const int b = gi / NN, n = gi % NN;
    float acc[T_OUT];
#pragma unroll
    for (int ot = 0; ot < T_OUT; ++ot) acc[ot] = hb[ot];
    for (int h = 0; h < HH; ++h) {
        float v = h1[(size_t)n * BC + b * 64 + h];
#pragma unroll
        for (int ot = 0; ot < T_OUT; ++ot) acc[ot] += v * wl[ot * HH + h];
    }
#pragma unroll
    for (int ot = 0; ot < T_OUT; ++ot)
        y[((size_t)b * T_OUT + ot) * NN + n] = acc[ot];
}

extern "C" void kernel_launch(void* const* d_in, const int* in_sizes, int n_in,
                              void* d_out, int out_size, void* d_ws, size_t ws_size,
                              hipStream_t stream) {
    const float* x = (const float*)d_in[0];
    const float* node_emb = (const float*)d_in[1];
    const float* adapt_emb = (const float*)d_in[2];
    const float* Wg0 = (const float*)d_in[3];
    const float* bg0 = (const float*)d_in[4];
    const float* Wc0 = (const float*)d_in[5];
    const float* bc0 = (const float*)d_in[6];
    const float* Wg1 = (const float*)d_in[7];
    const float* bg1 = (const float*)d_in[8];
    const float* Wc1 = (const float*)d_in[9];
    const float* bc1 = (const float*)d_in[10];
    const float* head_w = (const float*)d_in[11];
    const float* head_b = (const float*)d_in[12];
    float* y = (float*)d_out;

    char* ws = (char*)d_ws;
    ushort_t* Abf  = (ushort_t*)(ws + ABF_OFF);
    float* h0f = (float*)(ws + H0F_OFF);
    float* h1f = (float*)(ws + H1F_OFF);
    float* zf  = (float*)(ws + ZF_OFF);
    ushort_t* h0b = (ushort_t*)(ws + H0B_OFF);
    ushort_t* h1b = (ushort_t*)(ws + H1B_OFF);
    ushort_t* rhb = (ushort_t*)(ws + RHB_OFF);
    ushort_t* Ah0 = (ushort_t*)(ws + AH0_OFF);
    ushort_t* AhX = (ushort_t*)(ws + AHX_OFF);
    float* Axf = (float*)(ws + AXF_OFF);
    ushort_t* Btg0 = (ushort_t*)(ws + BTG0_OFF);
    ushort_t* Btc0 = (ushort_t*)(ws + BTC0_OFF);
    ushort_t* Btg1 = (ushort_t*)(ws + BTG1_OFF);
    ushort_t* Btc1 = (ushort_t*)(ws + BTC1_OFF);
    float* Af32 = zf;  // overlay: consumed before first gate writes z

    const bool pipe2 = (ws_size >= TOP_PIPE2);
    const bool pipe = (ws_size >= TOP_PIPE);

    hipMemsetAsync(h0f, 0, SZ_ST4, stream);
    hipMemsetAsync(h1f, 0, SZ_ST4, stream);
    hipMemsetAsync(h0b, 0, SZ_NPB2, stream);
    hipMemsetAsync(h1b, 0, SZ_NPB2, stream);
    hipMemsetAsync(rhb, 0, SZ_NPB2, stream);
    hipMemsetAsync(Ah0, 0, SZ_NPB2, stream);
    hipMemsetAsync(AhX, 0, SZ_NPB2, stream);

    compute_A_kernel<<<NN, 256, 0, stream>>>(adapt_emb, Af32);
    ax2_kernel<<<dim3(32, 32), 256, 0, stream>>>(Af32, x, Axf);
    convert_A<<<(NP * NP) / 256, 256, 0, stream>>>(Af32, Abf);
    prepW<65, 128, true><<<(DD * 128 * 128 + 255) / 256, 256, 0, stream>>>(Wg0, Btg0);
    prepW<65, 64, true><<<(DD * 64 * 128 + 255) / 256, 256, 0, stream>>>(Wc0, Btc0);
    prepW<128, 128, false><<<(DD * 128 * 256 + 255) / 256, 256, 0, stream>>>(Wg1, Btg1);
    prepW<128, 64, false><<<(DD * 64 * 256 + 255) / 256, 256, 0, stream>>>(Wc1, Btc1);

    const dim3 gG1(NP / 128, NP / 128, 1);  // 256 blocks
    const dim3 gG2(NP / 128, NP / 128, 2);  // dual GEMM: 512 blocks
    const int gN = NN * BB / 64;            // 1000 blocks

    if (pipe2) {
        float* zf0 = zf;
        ushort_t* rhb0 = rhb;
        float* zf1 = (float*)(ws + ZF1_OFF);
        ushort_t* rhb1 = (ushort_t*)(ws + RHB1_OFF);
        ushort_t* AhY = (ushort_t*)(ws + AHY_OFF);
        ushort_t* h0b2 = (ushort_t*)(ws + H0B2_OFF);
        hipMemsetAsync(rhb1, 0, SZ_NPB2, stream);
        hipMemsetAsync(h0b2, 0, SZ_NPB2, stream);
        ushort_t* hb[2] = {h0b, h0b2};  // C0(t) writes hb[t&1]

        // prologue: G0(0), R0(0), C0(0) -> hb[0], G2(0) -> Ah0
        napl2<2, 128, true, true><<<gN, 256, 0, stream>>>(
            Btg0, bg0, node_emb, Wg0, h0b, Ah0, h0b, h0b, x, Axf, h0f, zf0, rhb0, nullptr, 0);
        gemm_trb<<<gG1, 512, 0, stream>>>(Abf, rhb0, AhY, rhb0, AhY);
        napl2<2, 64, false, true><<<gN, 256, 0, stream>>>(
            Btc0, bc0, node_emb, Wc0, rhb0, AhY, rhb0, rhb0, x, Axf, h0f, zf0, hb[0], h0f, 0);
        gemm_trb<<<gG1, 512, 0, stream>>>(Abf, hb[0], Ah0, hb[0], Ah0);

        for (int t = 0; t < TT - 1; ++t) {
            ushort_t* hbt = hb[t & 1];
            ushort_t* hbt1 = hb[(t + 1) & 1];
            // D1: G1(t) || G0(t+1)
            mergeG_k<<<2000, 256, 0, stream>>>(Btg1, bg1, Btg0, bg0, node_emb, Wg0,
                hbt, Ah0, h1b, AhX, x, Axf, h0f, h1f, zf0, zf1, rhb0, rhb1, t);
            // D2: R1(t): AhX <- A@rhb1 || R0(t+1): AhY <- A@rhb0
            gemm_trb<<<gG2, 512, 0, stream>>>(Abf, rhb1, AhX, rhb0, AhY);
            // D3: C1(t) -> h1f,h1b || C0(t+1) -> h0f,hbt1
            mergeCC_k<<<2000, 256, 0, stream>>>(Btc1, bc1, Btc0, bc0, node_emb, Wc0,
                hbt, hbt1, Ah0, rhb1, AhX, AhY, rhb0, x, Axf, h0f, h1f, zf0, zf1, h1b, t);
            // D4: AhX <- A@h1b || Ah0 <- A@hbt1
            gemm_trb<<<gG2, 512, 0, stream>>>(Abf, h1b, AhX, hbt1, Ah0);
        }
        // epilogue t=TT-1
        {
            ushort_t* hbT = hb[(TT - 1) & 1];
            napl2<4, 128, true, false><<<gN, 256, 0, stream>>>(
                Btg1, bg1, node_emb, nullptr, hbT, Ah0, h1b, AhX, nullptr, nullptr, h1f, zf1, rhb1, nullptr, TT - 1);
            gemm_trb<<<gG1, 512, 0, stream>>>(Abf, rhb1, AhX, rhb1, AhX);
            napl2<4, 64, false, false><<<gN, 256, 0, stream>>>(
                Btc1, bc1, node_emb, nullptr, hbT, Ah0, rhb1, AhX, nullptr, nullptr, h1f, zf1, h1b, h1f, TT - 1);
        }
    } else if (pipe) {
        float* zf0 = zf;
        ushort_t* rhb0 = rhb;
        float* zf1 = (float*)(ws + ZF1_OFF);
        ushort_t* rhb1 = (ushort_t*)(ws + RHB1_OFF);
        ushort_t* AhY = (ushort_t*)(ws + AHY_OFF);
        hipMemsetAsync(rhb1, 0, SZ_NPB2, stream);

        napl2<2, 128, true, true><<<gN, 256, 0, stream>>>(
            Btg0, bg0, node_emb, Wg0, h0b, Ah0, h0b, h0b, x, Axf, h0f, zf0, rhb0, nullptr, 0);
        gemm_trb<<<gG1, 512, 0, stream>>>(Abf, rhb0, AhY, rhb0, AhY);
        napl2<2, 64, false, true><<<gN, 256, 0, stream>>>(
            Btc0, bc0, node_emb, Wc0, rhb0, AhY, rhb0, rhb0, x, Axf, h0f, zf0, h0b, h0f, 0);
        gemm_trb<<<gG2, 512, 0, stream>>>(Abf, h0b, Ah0, h1b, AhX);
        napl2<4, 128, true, false><<<gN, 256, 0, stream>>>(
            Btg1, bg1, node_emb, nullptr, h0b, Ah0, h1b, AhX, nullptr, nullptr, h1f, zf1, rhb1, nullptr, 0);

        for (int t = 0; t < TT - 1; ++t) {
            mergeA_k<<<1256, 256, 0, stream>>>(Abf, rhb1, AhX,
                Btg0, bg0, node_emb, Wg0, h0b, Ah0, x, Axf, h0f, zf0, rhb0, t + 1);
            mergeB_k<<<1256, 256, 0, stream>>>(Abf, rhb0, AhY,
                Btc1, bc1, node_emb, h0b, Ah0, rhb1, AhX, h1f, zf1, h1b, h1f, t);
            mergeC_k<<<1256, 256, 0, stream>>>(Abf, h1b, AhX,
                Btc0, bc0, node_emb, Wc0, rhb0, AhY, x, Axf, h0f, zf0, h0b, h0f, t + 1);
            gemm_trb<<<gG1, 512, 0, stream>>>(Abf, h0b, Ah0, h0b, Ah0);
            napl2<4, 128, true, false><<<gN, 256, 0, stream>>>(
                Btg1, bg1, node_emb, nullptr, h0b, Ah0, h1b, AhX, nullptr, nullptr, h1f, zf1, rhb1, nullptr, t + 1);
        }
        gemm_trb<<<gG1, 512, 0, stream>>>(Abf, rhb1, AhX, rhb1, AhX);
        napl2<4, 64, false, false><<<gN, 256, 0, stream>>>(
            Btc1, bc1, node_emb, nullptr, h0b, Ah0, rhb1, AhX, nullptr, nullptr, h1f, zf1, h1b, h1f, TT - 1);
    } else {
        for (int t = 0; t < TT; ++t) {
            napl2<2, 128, true, true><<<gN, 256, 0, stream>>>(
                Btg0, bg0, node_emb, Wg0, h0b, Ah0, h0b, h0b, x, Axf, h0f, zf, rhb, nullptr, t);
            gemm_trb<<<gG1, 512, 0, stream>>>(Abf, rhb, AhX, rhb, AhX);
            napl2<2, 64, false, true><<<gN, 256, 0, stream>>>(
                Btc0, bc0, node_emb, Wc0, rhb, AhX, rhb, rhb, x, Axf, h0f, zf, h0b, h0f, t);
            gemm_trb<<<gG2, 512, 0, stream>>>(Abf, h0b, Ah0, h1b, AhX);
            napl2<4, 128, true, false><<<gN, 256, 0, stream>>>(
                Btg1, bg1, node_emb, nullptr, h0b, Ah0, h1b, AhX, nullptr, nullptr, h1f, zf, rhb, nullptr, t);
            gemm_trb<<<gG1, 512, 0, stream>>>(Abf, rhb, AhX, rhb, AhX);
            napl2<4, 64, false, false><<<gN, 256, 0, stream>>>(
                Btc1, bc1, node_emb, nullptr, h0b, Ah0, rhb, AhX, nullptr, nullptr, h1f, zf, h1b, h1f, t);
        }
    }

    head_kernel<<<(BB * NN + 255) / 256, 256, 0, stream>>>(h1f, head_w, head_b, y);
}